// Round 11
// baseline (1551.921 us; speedup 1.0000x reference)
//
#include <hip/hip_runtime.h>

// TransformerDecoder on MI355X. Round 11:
// - batched weight-transpose prep (13 dispatches -> 4)
// - split-K partials stored bf16 (halves Spart HBM traffic; 4.5x abs headroom)
// - logits GEMM at BN=256 single-buffer (2x MFMA per barrier, 2000 blocks)
// Everything else = Round-10 passing code. Fallback = Round-3 proven.

typedef unsigned short u16;
typedef __bf16 v8bf __attribute__((ext_vector_type(8)));
typedef float v4f __attribute__((ext_vector_type(4)));

namespace {
constexpr int kB = 4, kT = 512, kD = 1024, kH = 16, kDK = 64, kF = 4096, kV = 32000, kL = 4;
constexpr int kM = kB * kT;
constexpr long kTD = (long)kT * kD;
constexpr long kTT = (long)kT * kT;
constexpr long kHTT = (long)kH * kTT;
constexpr long kBHTT = (long)kB * kHTT;
constexpr long kLOG = (long)kM * kV;
constexpr long kPART = (long)kM * kD;
}

__device__ __forceinline__ u16 f2bf(float f) {
  union { float f; unsigned u; } v; v.f = f;
  unsigned r = v.u + 0x7FFFu + ((v.u >> 16) & 1u);
  return (u16)(r >> 16);
}
__device__ __forceinline__ float bf2f(u16 h) {
  union { unsigned u; float f; } v; v.u = ((unsigned)h) << 16;
  return v.f;
}

typedef __attribute__((address_space(3))) void lds_void;
typedef const __attribute__((address_space(1))) void glob_void;
__device__ __forceinline__ void gl2lds16(const void* g, void* l) {
  __builtin_amdgcn_global_load_lds((glob_void*)g, (lds_void*)l, 16, 0, 0);
}

// ---------------------------------------------------------------------------
// bf16 GEMM, BK=64, swizzled LDS. DBUF=1: double-buffered (1 barrier/step).
// DBUF=0: single buffer (2 barriers/step, less LDS -> higher residency).
// C[m][n] = scale*sum A[m][k]*B[n][k] + bias[zh*bstride+n] (zb==0 only).
// VTR: cols>=2048 of a (.,3072) C also written transposed into vt (B,H,dk,T).
// ---------------------------------------------------------------------------
template <int BM, int BN, int OUTBF, int VTR, int DBUF>
__global__ __launch_bounds__(256)
void gemm_bf(const u16* __restrict__ A0, const u16* __restrict__ B0,
             const float* __restrict__ bias, void* __restrict__ Cv,
             u16* __restrict__ vtw,
             const int K, const int lda, const int ldb, const int ldc,
             const int nH, const long sAb, const long sAh,
             const long sBb, const long sBh, const long sCb, const long sCh,
             const float scale, const int relu, const int bstride) {
  static_assert(BM % 32 == 0 && BN % 32 == 0, "tiles");
  __shared__ u16 As[DBUF + 1][BM][64];
  __shared__ u16 Bs[DBUF + 1][BN][64];
  const int tid = threadIdx.x;
  const int lane = tid & 63;
  const int w = tid >> 6;
  const int z = blockIdx.z;
  const int zb = z / nH, zh = z - zb * nH;
  const u16* A = A0 + zb * sAb + zh * sAh + (long)blockIdx.y * BM * lda;
  const u16* B = B0 + zb * sBb + zh * sBh + (long)blockIdx.x * BN * ldb;
  const long offC = zb * sCb + zh * sCh;
  const int wm = w >> 1, wn = w & 1;
  constexpr int FM = BM / 32, FN = BN / 32;
  v4f acc[FM][FN];
  const v4f zero = {0.f, 0.f, 0.f, 0.f};
#pragma unroll
  for (int i = 0; i < FM; ++i)
#pragma unroll
    for (int j = 0; j < FN; ++j) acc[i][j] = zero;
  const int l15 = lane & 15, lk = lane >> 4;
  const int lr8 = lane >> 3;                       // row within 8-row stripe
  const int swz = ((lane & 7) ^ lr8) * 8;          // pre-swizzled source col
  const int l7 = l15 & 7;

  if constexpr (DBUF) {
    // prologue: stage tile 0 into buffer 0
#pragma unroll
    for (int s = 0; s < BM / 32; ++s)
      gl2lds16(A + (long)(w * (BM / 4) + s * 8 + lr8) * lda + swz,
               &As[0][w * (BM / 4) + s * 8][0]);
#pragma unroll
    for (int s = 0; s < BN / 32; ++s)
      gl2lds16(B + (long)(w * (BN / 4) + s * 8 + lr8) * ldb + swz,
               &Bs[0][w * (BN / 4) + s * 8][0]);

    const int NT = K >> 6;
    for (int kt = 0; kt < NT; ++kt) {
      const int cur = kt & 1;
      __syncthreads();   // drains prev stage + prev reads
      if (kt + 1 < NT) {
        const int k0 = (kt + 1) << 6;
#pragma unroll
        for (int s = 0; s < BM / 32; ++s)
          gl2lds16(A + (long)(w * (BM / 4) + s * 8 + lr8) * lda + k0 + swz,
                   &As[cur ^ 1][w * (BM / 4) + s * 8][0]);
#pragma unroll
        for (int s = 0; s < BN / 32; ++s)
          gl2lds16(B + (long)(w * (BN / 4) + s * 8 + lr8) * ldb + k0 + swz,
                   &Bs[cur ^ 1][w * (BN / 4) + s * 8][0]);
      }
#pragma unroll
      for (int t = 0; t < 2; ++t) {
        const int c0 = t * 4;
        v8bf af[FM], bfr[FN];
#pragma unroll
        for (int i = 0; i < FM; ++i)
          af[i] = *(const v8bf*)&As[cur][wm * (BM / 2) + i * 16 + l15][((c0 + lk) ^ l7) * 8];
#pragma unroll
        for (int j = 0; j < FN; ++j)
          bfr[j] = *(const v8bf*)&Bs[cur][wn * (BN / 2) + j * 16 + l15][((c0 + lk) ^ l7) * 8];
#pragma unroll
        for (int i = 0; i < FM; ++i)
#pragma unroll
          for (int j = 0; j < FN; ++j)
            acc[i][j] = __builtin_amdgcn_mfma_f32_16x16x32_bf16(af[i], bfr[j], acc[i][j], 0, 0, 0);
      }
    }
  } else {
    for (int k0 = 0; k0 < K; k0 += 64) {
      __syncthreads();
#pragma unroll
      for (int s = 0; s < BM / 32; ++s)
        gl2lds16(A + (long)(w * (BM / 4) + s * 8 + lr8) * lda + k0 + swz,
                 &As[0][w * (BM / 4) + s * 8][0]);
#pragma unroll
      for (int s = 0; s < BN / 32; ++s)
        gl2lds16(B + (long)(w * (BN / 4) + s * 8 + lr8) * ldb + k0 + swz,
                 &Bs[0][w * (BN / 4) + s * 8][0]);
      __syncthreads();
#pragma unroll
      for (int t = 0; t < 2; ++t) {
        const int c0 = t * 4;
        v8bf af[FM], bfr[FN];
#pragma unroll
        for (int i = 0; i < FM; ++i)
          af[i] = *(const v8bf*)&As[0][wm * (BM / 2) + i * 16 + l15][((c0 + lk) ^ l7) * 8];
#pragma unroll
        for (int j = 0; j < FN; ++j)
          bfr[j] = *(const v8bf*)&Bs[0][wn * (BN / 2) + j * 16 + l15][((c0 + lk) ^ l7) * 8];
#pragma unroll
        for (int i = 0; i < FM; ++i)
#pragma unroll
          for (int j = 0; j < FN; ++j)
            acc[i][j] = __builtin_amdgcn_mfma_f32_16x16x32_bf16(af[i], bfr[j], acc[i][j], 0, 0, 0);
      }
    }
  }

  const long m0 = (long)blockIdx.y * BM + wm * (BM / 2);
  const int n0 = blockIdx.x * BN + wn * (BN / 2);
#pragma unroll
  for (int j = 0; j < FN; ++j) {
    const int col = n0 + j * 16 + l15;
    const float bv = (bias && zb == 0) ? bias[zh * bstride + col] : 0.0f;
#pragma unroll
    for (int i = 0; i < FM; ++i) {
      const long row = m0 + i * 16 + lk * 4;
#pragma unroll
      for (int r = 0; r < 4; ++r) {
        float v = acc[i][j][r] * scale + bv;
        if (relu) v = fmaxf(v, 0.0f);
        const long idx = offC + (row + r) * ldc + col;
        if (OUTBF) ((u16*)Cv)[idx] = f2bf(v);
        else       ((float*)Cv)[idx] = v;
        if (VTR) {
          const int colS = (int)(offC % 3072) + col;   // column within (.,3072)
          if (colS >= 2048) {
            const int hh = (colS - 2048) >> 6, dd = (colS - 2048) & 63;
            const int rowg = (int)(row + r);
            vtw[((long)((rowg >> 9) * 16 + hh)) * 32768 + dd * 512 + (rowg & 511)] = f2bf(v);
          }
        }
      }
    }
  }
}

// ---------------------------------------------------------------------------
// Fused attention: per block 128 q-rows x one (b,h): QK^T (swizzled LDS),
// softmax (writes w f32 to d_out), then PV via padded-LDS P/V^T chunks,
// writes O bf16 into S3b (2048,1024). 512 threads = 8 waves (2 wm x 4 wn).
// ---------------------------------------------------------------------------
template <int CAUSAL>
__global__ __launch_bounds__(512)
void attn_fused(const u16* __restrict__ Qb, const u16* __restrict__ Kb,
                const u16* __restrict__ vtp, float* __restrict__ wout,
                u16* __restrict__ oout) {
  __shared__ __align__(16) char lds[81920];
  u16 (*Qs)[64] = (u16 (*)[64])lds;                 // [128][64]
  u16 (*Ks)[64] = (u16 (*)[64])(lds + 16384);       // [512][64]
  u16 (*Pl)[136] = (u16 (*)[136])lds;               // [128][136] 34816 B
  u16 (*Vt)[136] = (u16 (*)[136])(lds + 34816);     // [64][136]  17408 B
  __shared__ float redM[128][4];
  __shared__ float redS[128][4];
  const int tid = threadIdx.x, lane = tid & 63, w = tid >> 6;
  const int wm = w >> 2, wn = w & 3;
  const int l15 = lane & 15, lk = lane >> 4;
  const int lr8 = lane >> 3;
  const int swz = ((lane & 7) ^ lr8) * 8;
  const int l7 = l15 & 7;
  const int bx = blockIdx.x;
  const int z = blockIdx.y, zb = z >> 4, zh = z & 15;
  const u16* Q = Qb + (long)zb * 512 * 3072 + zh * 64 + (long)bx * 128 * 3072;
  const u16* Kp = Kb + (long)zb * 512 * 3072 + zh * 64;
  const u16* vtz = vtp + (long)((zb << 4) + zh) * 32768;
  const long obase = (long)zb * kHTT + (long)zh * kTT;

#pragma unroll
  for (int s = 0; s < 2; ++s)
    gl2lds16(Q + (long)(w * 16 + s * 8 + lr8) * 3072 + swz, &Qs[w * 16 + s * 8][0]);
#pragma unroll
  for (int s = 0; s < 8; ++s) {
    const int r0 = w * 64 + s * 8;
    if (!CAUSAL || r0 <= bx * 128 + 127)
      gl2lds16(Kp + (long)(r0 + lr8) * 3072 + swz, &Ks[r0][0]);
  }
  __syncthreads();

  v4f acc[4][8];
  const v4f zero = {0.f, 0.f, 0.f, 0.f};
#pragma unroll
  for (int i = 0; i < 4; ++i)
#pragma unroll
    for (int j = 0; j < 8; ++j) acc[i][j] = zero;

#pragma unroll
  for (int t = 0; t < 2; ++t) {
    const int c0 = t * 4;
    v8bf aq[4], bk[8];
#pragma unroll
    for (int i = 0; i < 4; ++i)
      aq[i] = *(const v8bf*)&Qs[wm * 64 + i * 16 + l15][((c0 + lk) ^ l7) * 8];
#pragma unroll
    for (int j = 0; j < 8; ++j)
      bk[j] = *(const v8bf*)&Ks[wn * 128 + j * 16 + l15][((c0 + lk) ^ l7) * 8];
#pragma unroll
    for (int i = 0; i < 4; ++i)
#pragma unroll
      for (int j = 0; j < 8; ++j)
        if (!(CAUSAL && wn * 128 + j * 16 > bx * 128 + wm * 64 + i * 16 + 15))
          acc[i][j] = __builtin_amdgcn_mfma_f32_16x16x32_bf16(aq[i], bk[j], acc[i][j], 0, 0, 0);
  }

  // row max
  float gmax[4][4];
#pragma unroll
  for (int i = 0; i < 4; ++i)
#pragma unroll
    for (int r = 0; r < 4; ++r) {
      const int q = bx * 128 + wm * 64 + i * 16 + lk * 4 + r;
      float m = -3.0e38f;
#pragma unroll
      for (int j = 0; j < 8; ++j) {
        const int col = wn * 128 + j * 16 + l15;
        if (!CAUSAL || col <= q) m = fmaxf(m, acc[i][j][r] * 0.125f);
      }
#pragma unroll
      for (int off = 1; off < 16; off <<= 1) m = fmaxf(m, __shfl_xor(m, off));
      if (l15 == 0) redM[wm * 64 + i * 16 + lk * 4 + r][wn] = m;
    }
  __syncthreads();
#pragma unroll
  for (int i = 0; i < 4; ++i)
#pragma unroll
    for (int r = 0; r < 4; ++r) {
      v4f mv = *(const v4f*)&redM[wm * 64 + i * 16 + lk * 4 + r][0];
      gmax[i][r] = fmaxf(fmaxf(mv[0], mv[1]), fmaxf(mv[2], mv[3]));
    }
  // exp + row sum
#pragma unroll
  for (int i = 0; i < 4; ++i)
#pragma unroll
    for (int r = 0; r < 4; ++r) {
      const int q = bx * 128 + wm * 64 + i * 16 + lk * 4 + r;
      float s = 0.0f;
#pragma unroll
      for (int j = 0; j < 8; ++j) {
        const int col = wn * 128 + j * 16 + l15;
        float e = (!CAUSAL || col <= q) ? __expf(acc[i][j][r] * 0.125f - gmax[i][r]) : 0.0f;
        acc[i][j][r] = e;
        s += e;
      }
#pragma unroll
      for (int off = 1; off < 16; off <<= 1) s += __shfl_xor(s, off);
      if (l15 == 0) redS[wm * 64 + i * 16 + lk * 4 + r][wn] = s;
    }
  __syncthreads();
  // normalize, write w (f32), keep normalized P in acc
#pragma unroll
  for (int i = 0; i < 4; ++i)
#pragma unroll
    for (int r = 0; r < 4; ++r) {
      v4f sv = *(const v4f*)&redS[wm * 64 + i * 16 + lk * 4 + r][0];
      const float inv = 1.0f / (sv[0] + sv[1] + sv[2] + sv[3]);
      const int q = bx * 128 + wm * 64 + i * 16 + lk * 4 + r;
      const long rowoff = obase + (long)q * 512;
#pragma unroll
      for (int j = 0; j < 8; ++j) {
        const int col = wn * 128 + j * 16 + l15;
        const float v = acc[i][j][r] * inv;
        acc[i][j][r] = v;
        wout[rowoff + col] = v;
      }
    }

  // ---- PV: O[128 q][64 d] = P @ V, chunked over k (128 per chunk) ----
  v4f acco[4];
#pragma unroll
  for (int i = 0; i < 4; ++i) acco[i] = zero;
  const int kcMax = CAUSAL ? bx : 3;
  for (int kc = 0; kc <= kcMax; ++kc) {
    __syncthreads();
    if (wn == kc) {       // this wave-group owns P cols [kc*128, kc*128+128)
#pragma unroll
      for (int i = 0; i < 4; ++i)
#pragma unroll
        for (int j = 0; j < 8; ++j) {
          const int colk = j * 16 + l15;
#pragma unroll
          for (int r = 0; r < 4; ++r)
            Pl[wm * 64 + i * 16 + lk * 4 + r][colk] = f2bf(acc[i][j][r]);
        }
    }
    // stage V^T chunk [64 d][128 k] into padded Vt
#pragma unroll
    for (int s = 0; s < 2; ++s) {
      const int c = tid * 2 + s;            // 0..1023 chunks of 16B
      const int d = c >> 4, off = (c & 15) * 8;
      uint4 vv = *(const uint4*)(vtz + (long)d * 512 + kc * 128 + off);
      *(uint4*)&Vt[d][off] = vv;
    }
    __syncthreads();
#pragma unroll
    for (int t = 0; t < 4; ++t) {
      v8bf bv = *(const v8bf*)&Vt[wn * 16 + l15][t * 32 + lk * 8];
#pragma unroll
      for (int i = 0; i < 4; ++i) {
        v8bf ap = *(const v8bf*)&Pl[wm * 64 + i * 16 + l15][t * 32 + lk * 8];
        acco[i] = __builtin_amdgcn_mfma_f32_16x16x32_bf16(ap, bv, acco[i], 0, 0, 0);
      }
    }
  }
  // write O bf16 into S3b (2048,1024) at column zh*64
#pragma unroll
  for (int i = 0; i < 4; ++i)
#pragma unroll
    for (int r = 0; r < 4; ++r) {
      const int row = bx * 128 + wm * 64 + i * 16 + lk * 4 + r;
      oout[(long)(zb * 512 + row) * 1024 + zh * 64 + wn * 16 + l15] = f2bf(acco[i][r]);
    }
}

// Weight transpose-convert: out(N,K) bf16 = in(K,N)^T f32; 64x64 tiles,
// float4 vectorized loads, uint2 vectorized stores. Up to 32 matrices/launch.
struct TPtrs32 { const float* in[32]; u16* out[32]; };

__global__ void transpose_wt_v4(TPtrs32 ps, int K, int N) {
  __shared__ float tile[64][65];
  const float* in = ps.in[blockIdx.z];
  u16* o = ps.out[blockIdx.z];
  const int n0 = blockIdx.x * 64, k0 = blockIdx.y * 64;
  const int tr = threadIdx.x >> 4;          // 0..15
  const int tc = (threadIdx.x & 15) * 4;    // 0,4,..,60
#pragma unroll
  for (int i = 0; i < 4; ++i) {
    float4 v = *(const float4*)(in + (long)(k0 + tr + 16 * i) * N + n0 + tc);
    tile[tr + 16 * i][tc + 0] = v.x;
    tile[tr + 16 * i][tc + 1] = v.y;
    tile[tr + 16 * i][tc + 2] = v.z;
    tile[tr + 16 * i][tc + 3] = v.w;
  }
  __syncthreads();
#pragma unroll
  for (int i = 0; i < 4; ++i) {
    const int rr = tr + 16 * i;             // n within tile
    u16 h[4];
#pragma unroll
    for (int j = 0; j < 4; ++j) h[j] = f2bf(tile[tc + j][rr]);
    *(uint2*)(o + (long)(n0 + rr) * K + k0 + tc) = *(const uint2*)h;
  }
}

__global__ void concat_bias(float* __restrict__ dst, const float* __restrict__ s0,
                            const float* __restrict__ s1, const float* __restrict__ s2,
                            const int nsrc) {
  const int idx = blockIdx.x * 256 + threadIdx.x;
  const int per = nsrc << 10;
  const int l = idx / per, rem = idx - l * per, s = rem >> 10, j = rem & 1023;
  const float* src = (s == 0) ? s0 : (s == 1 ? s1 : s2);
  dst[idx] = src[l * 1024 + j];
}

__global__ void cvt_bf16_v3(const float* __restrict__ in, u16* __restrict__ o1,
                            u16* __restrict__ o2) {
  const long i = ((long)blockIdx.x * 256 + threadIdx.x) * 4;
  float4 v = *(const float4*)(in + i);
  u16 h[4] = {f2bf(v.x), f2bf(v.y), f2bf(v.z), f2bf(v.w)};
  *(uint2*)(o1 + i) = *(const uint2*)h;
  *(uint2*)(o2 + i) = *(const uint2*)h;
}

__global__ void embed_v2(const int* __restrict__ tgt, const float* __restrict__ emb,
                         float* __restrict__ x, u16* __restrict__ xb) {
  const int row = blockIdx.x;
  const int t = row & (kT - 1);
  const int tok = tgt[row];
  const int c = threadIdx.x * 4;
  float4 e = *(const float4*)(emb + (long)tok * kD + c);
  const float nl = -9.210340371976184f / (float)kD;
  const float a0 = (float)t * expf((float)c * nl);
  const float a1 = (float)t * expf((float)(c + 2) * nl);
  float4 o;
  o.x = e.x * 32.0f + sinf(a0);
  o.y = e.y * 32.0f + cosf(a0);
  o.z = e.z * 32.0f + sinf(a1);
  o.w = e.w * 32.0f + cosf(a1);
  *(float4*)(x + (long)row * kD + c) = o;
  u16 h[4] = {f2bf(o.x), f2bf(o.y), f2bf(o.z), f2bf(o.w)};
  *(uint2*)(xb + (long)row * kD + c) = *(const uint2*)h;
}

// x = LN(x + sum_{p<nres} resb[p]) with bf16 partials; writes x f32 and xb bf16
__global__ void add_ln_v4(float* __restrict__ x, u16* __restrict__ xb,
                          const u16* __restrict__ resb, const int nres,
                          const float* __restrict__ g, const float* __restrict__ b) {
  const int row = blockIdx.x;
  const int c = threadIdx.x * 4;
  float4 xv = *(const float4*)(x + (long)row * kD + c);
  float v0 = xv.x, v1 = xv.y, v2 = xv.z, v3 = xv.w;
  for (int p = 0; p < nres; ++p) {
    uint2 rv = *(const uint2*)(resb + p * kPART + (long)row * kD + c);
    v0 += bf2f((u16)(rv.x & 0xffffu));
    v1 += bf2f((u16)(rv.x >> 16));
    v2 += bf2f((u16)(rv.y & 0xffffu));
    v3 += bf2f((u16)(rv.y >> 16));
  }
  float s = v0 + v1 + v2 + v3;
  float ss = v0 * v0 + v1 * v1 + v2 * v2 + v3 * v3;
#pragma unroll
  for (int o = 32; o > 0; o >>= 1) { s += __shfl_xor(s, o); ss += __shfl_xor(ss, o); }
  __shared__ float red[4][2];
  const int wv = threadIdx.x >> 6;
  if ((threadIdx.x & 63) == 0) { red[wv][0] = s; red[wv][1] = ss; }
  __syncthreads();
  s  = red[0][0] + red[1][0] + red[2][0] + red[3][0];
  ss = red[0][1] + red[1][1] + red[2][1] + red[3][1];
  const float mean = s * (1.0f / kD);
  const float var = ss * (1.0f / kD) - mean * mean;
  const float rs = rsqrtf(var + 1e-5f);
  float4 gv = *(const float4*)(g + c);
  float4 bv = *(const float4*)(b + c);
  float4 o;
  o.x = gv.x * (v0 - mean) * rs + bv.x;
  o.y = gv.y * (v1 - mean) * rs + bv.y;
  o.z = gv.z * (v2 - mean) * rs + bv.z;
  o.w = gv.w * (v3 - mean) * rs + bv.w;
  *(float4*)(x + (long)row * kD + c) = o;
  u16 h[4] = {f2bf(o.x), f2bf(o.y), f2bf(o.z), f2bf(o.w)};
  *(uint2*)(xb + (long)row * kD + c) = *(const uint2*)h;
}

// ===========================================================================
// FALLBACK PATH (Round-3 proven)
// ===========================================================================
template <int BM, int BN, typename TA, typename TB, int BKN>
__global__ __launch_bounds__(256)
void gemm_kernel(const void* __restrict__ Av, const void* __restrict__ Bv,
                 const float* __restrict__ bias, float* __restrict__ Cv,
                 const int K, const int lda, const int ldb, const int ldc,
                 const int nH, const long sAb, const long sAh,
                 const long sBb, const long sBh, const long sCb, const long sCh,
                 const float scale, const int relu) {
  constexpr int LP = 40;
  __shared__ u16 As[BM][LP];
  __shared__ u16 Bs[BN][LP];
  const int tid = threadIdx.x;
  const int z = blockIdx.z;
  const int zb = z / nH, zh = z - zb * nH;
  const TA* A = (const TA*)Av + zb * sAb + zh * sAh + (long)blockIdx.y * BM * lda;
  const TB* Bp;
  if constexpr (BKN)
    Bp = (const TB*)Bv + zb * sBb + zh * sBh + (long)blockIdx.x * BN;
  else
    Bp = (const TB*)Bv + zb * sBb + zh * sBh + (long)blockIdx.x * BN * ldb;
  const long offC = zb * sCb + zh * sCh;
  const int lane = tid & 63;
  const int wm = (tid >> 7) & 1, wn = (tid >> 6) & 1;
  constexpr int FM = BM / 32, FN = BN / 32;
  v4f acc[FM][FN];
  const v4f zero = {0.f, 0.f, 0.f, 0.f};
#pragma unroll
  for (int i = 0; i < FM; ++i)
#pragma unroll
    for (int j = 0; j < FN; ++j) acc[i][j] = zero;
  const int l15 = lane & 15, lk = lane >> 4;

  for (int k0 = 0; k0 < K; k0 += 32) {
    __syncthreads();
    if constexpr (sizeof(TA) == 4) {
      const int r = tid >> 3, c = (tid & 7) * 4;
#pragma unroll
      for (int rr = 0; rr < BM; rr += 32) {
        float4 vv = *(const float4*)((const float*)A + (long)(rr + r) * lda + k0 + c);
        unsigned lo = (unsigned)f2bf(vv.x) | ((unsigned)f2bf(vv.y) << 16);
        unsigned hi = (unsigned)f2bf(vv.z) | ((unsigned)f2bf(vv.w) << 16);
        *(uint2*)&As[rr + r][c] = make_uint2(lo, hi);
      }
    } else {
      const int r = tid >> 2, c = (tid & 3) * 8;
#pragma unroll
      for (int rr = 0; rr < BM; rr += 64) {
        uint4 vv = *(const uint4*)((const u16*)A + (long)(rr + r) * lda + k0 + c);
        *(uint4*)&As[rr + r][c] = vv;
      }
    }
    if constexpr (BKN) {
      const int r = tid >> 3, c = (tid & 7) * 4;
#pragma unroll
      for (int nn = 0; nn < BN; nn += 32) {
        float4 vv = *(const float4*)((const float*)Bp + (long)(k0 + r) * ldb + nn + c);
        Bs[nn + c + 0][r] = f2bf(vv.x);
        Bs[nn + c + 1][r] = f2bf(vv.y);
        Bs[nn + c + 2][r] = f2bf(vv.z);
        Bs[nn + c + 3][r] = f2bf(vv.w);
      }
    } else if constexpr (sizeof(TB) == 4) {
      const int r = tid >> 3, c = (tid & 7) * 4;
#pragma unroll
      for (int rr = 0; rr < BN; rr += 32) {
        float4 vv = *(const float4*)((const float*)Bp + (long)(rr + r) * ldb + k0 + c);
        unsigned lo = (unsigned)f2bf(vv.x) | ((unsigned)f2bf(vv.y) << 16);
        unsigned hi = (unsigned)f2bf(vv.z) | ((unsigned)f2bf(vv.w) << 16);
        *(uint2*)&Bs[rr + r][c] = make_uint2(lo, hi);
      }
    } else {
      const int r = tid >> 2, c = (tid & 3) * 8;
#pragma unroll
      for (int rr = 0; rr < BN; rr += 64) {
        uint4 vv = *(const uint4*)((const u16*)Bp + (long)(rr + r) * ldb + k0 + c);
        *(uint4*)&Bs[rr + r][c] = vv;
      }
    }
    __syncthreads();
    v8bf af[FM], bfr[FN];
#pragma unroll
    for (int i = 0; i < FM; ++i)
      af[i] = *(const v8bf*)&As[wm * (BM / 2) + i * 16 + l15][lk * 8];
#pragma unroll
    for (int j = 0; j < FN; ++j)
      bfr[j] = *(const v8bf*)&Bs[wn * (BN / 2) + j * 16 + l15][lk * 8];
#pragma unroll
    for (int i = 0; i < FM; ++i)
#pragma unroll
      for (int j = 0; j < FN; ++j)
        acc[i][j] = __builtin_amdgcn_mfma_f32_16x16x32_bf16(af[i], bfr[j], acc[i][j], 0, 0, 0);
  }

  const long m0 = (long)blockIdx.y * BM + wm * (BM / 2);
  const int n0 = blockIdx.x * BN + wn * (BN / 2);
#pragma unroll
  for (int j = 0; j < FN; ++j) {
    const int col = n0 + j * 16 + l15;
    const float bv = bias ? bias[col] : 0.0f;
#pragma unroll
    for (int i = 0; i < FM; ++i) {
      const long row = m0 + i * 16 + lk * 4;
#pragma unroll
      for (int r = 0; r < 4; ++r) {
        float v = acc[i][j][r] * scale + bv;
        if (relu) v = fmaxf(v, 0.0f);
        Cv[offC + (row + r) * ldc + col] = v;
      }
    }
  }
}

__global__ void embed_kernel(const int* __restrict__ tgt, const float* __restrict__ emb,
                             float* __restrict__ x) {
  const int row = blockIdx.x;
  const int t = row & (kT - 1);
  const int tok = tgt[row];
  const int c = threadIdx.x * 4;
  float4 e = *(const float4*)(emb + (long)tok * kD + c);
  const float nl = -9.210340371976184f / (float)kD;
  const float a0 = (float)t * expf((float)c * nl);
  const float a1 = (float)t * expf((float)(c + 2) * nl);
  float4 o;
  o.x = e.x * 32.0f + sinf(a0);
  o.y = e.y * 32.0f + cosf(a0);
  o.z = e.z * 32.0f + sinf(a1);
  o.w = e.w * 32.0f + cosf(a1);
  *(float4*)(x + (long)row * kD + c) = o;
}

__global__ void transpose_v_kernel(const float* __restrict__ v, u16* __restrict__ vt) {
  __shared__ float tile[32][33];
  const int z = blockIdx.z;
  const int b = z >> 4, h = z & 15;
  const int t0 = blockIdx.x * 32, d0 = blockIdx.y * 32;
  const int tx = threadIdx.x, ty = threadIdx.y;
  const float* in = v + (long)b * kTD + (long)h * kDK;
#pragma unroll
  for (int i = 0; i < 4; ++i)
    tile[ty + 8 * i][tx] = in[(long)(t0 + ty + 8 * i) * kD + d0 + tx];
  __syncthreads();
  u16* o = vt + (long)z * kDK * kT;
#pragma unroll
  for (int i = 0; i < 4; ++i)
    o[(long)(d0 + ty + 8 * i) * kT + t0 + tx] = f2bf(tile[tx][ty + 8 * i]);
}

__global__ void softmax_kernel(float* __restrict__ w, const int causal) {
  const int rowg = blockIdx.x * 4 + (threadIdx.x >> 6);
  const int lane = threadIdx.x & 63;
  const int q = rowg & (kT - 1);
  float* p = w + (long)rowg * kT + lane * 8;
  float4 v0 = *(const float4*)p;
  float4 v1 = *(const float4*)(p + 4);
  float f[8] = {v0.x, v0.y, v0.z, v0.w, v1.x, v1.y, v1.z, v1.w};
  const int base = lane * 8;
  float mx = -3.0e38f;
#pragma unroll
  for (int j = 0; j < 8; ++j)
    if (!causal || base + j <= q) mx = fmaxf(mx, f[j]);
#pragma unroll
  for (int o = 32; o > 0; o >>= 1) mx = fmaxf(mx, __shfl_xor(mx, o));
  float s = 0.0f;
#pragma unroll
  for (int j = 0; j < 8; ++j) {
    float e = (!causal || base + j <= q) ? __expf(f[j] - mx) : 0.0f;
    f[j] = e; s += e;
  }
#pragma unroll
  for (int o = 32; o > 0; o >>= 1) s += __shfl_xor(s, o);
  const float inv = 1.0f / s;
  float4 o0 = {f[0] * inv, f[1] * inv, f[2] * inv, f[3] * inv};
  float4 o1 = {f[4] * inv, f[5] * inv, f[6] * inv, f[7] * inv};
  *(float4*)p = o0;
  *(float4*)(p + 4) = o1;
}

__global__ void add_ln_kernel(float* __restrict__ x, const float* __restrict__ res,
                              const float* __restrict__ g, const float* __restrict__ b) {
  const int row = blockIdx.x;
  const int c = threadIdx.x * 4;
  float4 xv = *(const float4*)(x + (long)row * kD + c);
  float4 rv = *(const float4*)(res + (long)row * kD + c);
  const float v0 = xv.x + rv.x, v1 = xv.y + rv.y, v2 = xv.z + rv.z, v3 = xv.w + rv.w;
  float s = v0 + v1 + v2 + v3;
  float ss = v0 * v0 + v1 * v1 + v2 * v2 + v3 * v3;
#pragma unroll
  for (int o = 32; o > 0; o >>= 1) { s += __shfl_xor(s, o); ss += __shfl_xor(ss, o); }
  __shared__ float red[4][2];
  const int wv = threadIdx.x >> 6;
  if ((threadIdx.x & 63) == 0) { red[wv][0] = s; red[wv][1] = ss; }
  __syncthreads();
  s  = red[0][0] + red[1][0] + red[2][0] + red[3][0];
  ss = red[0][1] + red[1][1] + red[2][1] + red[3][1];
  const float mean = s * (1.0f / kD);
  const float var = ss * (1.0f / kD) - mean * mean;
  const float rs = rsqrtf(var + 1e-5f);
  float4 gv = *(const float4*)(g + c);
  float4 bv = *(const float4*)(b + c);
  float4 o;
  o.x = gv.x * (v0 - mean) * rs + bv.x;
  o.y = gv.y * (v1 - mean) * rs + bv.y;
  o.z = gv.z * (v2 - mean) * rs + bv.z;
  o.w = gv.w * (v3 - mean) * rs + bv.w;
  *(float4*)(x + (long)row * kD + c) = o;
}

// ===========================================================================
extern "C" void kernel_launch(void* const* d_in, const int* in_sizes, int n_in,
                              void* d_out, int out_size, void* d_ws, size_t ws_size,
                              hipStream_t stream) {
  const int*   tgt  = (const int*)d_in[0];
  const float* enc  = (const float*)d_in[1];
  const float* emb  = (const float*)d_in[3];
  const float* Wout = (const float*)d_in[4];
  const float* bout = (const float*)d_in[5];
  const float* Wq_s = (const float*)d_in[6];
  const float* bq_s = (const float*)d_in[7];
  const float* Wk_s = (const float*)d_in[8];
  const float* bk_s = (const float*)d_in[9];
  const float* Wv_s = (const float*)d_in[10];
  const float* bv_s = (const float*)d_in[11];
  const float* Wo_s = (const float*)d_in[12];
  const float* bo_s = (const float*)d_in[13];
  const float* Wq_c = (const float*)d_in[14];
  const float* bq_c = (const float*)d_in[15];
  const float* Wk_c = (const float*)d_in[16];
  const float* bk_c = (const float*)d_in[17];
  const float* Wv_c = (const float*)d_in[18];
  const float* bv_c = (const float*)d_in[19];
  const float* Wo_c = (const float*)d_in[20];
  const float* bo_c = (const float*)d_in[21];
  const float* W1   = (const float*)d_in[22];
  const float* b1   = (const float*)d_in[23];
  const float* W2   = (const float*)d_in[24];
  const float* b2   = (const float*)d_in[25];
  const float* ln1g = (const float*)d_in[26];
  const float* ln1b = (const float*)d_in[27];
  const float* ln2g = (const float*)d_in[28];
  const float* ln2b = (const float*)d_in[29];
  const float* ln3g = (const float*)d_in[30];
  const float* ln3b = (const float*)d_in[31];

  float* out = (float*)d_out;
  const long DD = (long)kD * kD;
  const dim3 blk256(256), blkT(32, 8);

  if (ws_size >= (320ll << 20)) {
    // =================== FAST PATH ===================
    char* ws = (char*)d_ws;
    float* x     = (float*)ws;                    // 8 MiB
    u16* xb      = (u16*)(ws + (8l << 20));       // 4 MiB (contiguous with encb)
    u16* encb    = (u16*)(ws + (12l << 20));      // 4 MiB (A source, merged cross)
    u16* encb2   = (u16*)(ws + (16l << 20));      // 4 MiB (second copy for V slice)
    u16* Sqkv    = (u16*)(ws + (20l << 20));      // 12 MiB (2048x3072)
    u16* vt      = (u16*)(ws + (32l << 20));      // 4 MiB (B,H,dk,T)
    u16* S3b     = (u16*)(ws + (36l << 20));      // 4 MiB
    u16* Hb      = (u16*)(ws + (40l << 20));      // 16 MiB (2048x4096)
    u16* SpartB  = (u16*)(ws + (56l << 20));      // 16 MiB (4 bf16 partials)
    u16* wbase   = (u16*)(ws + (88l << 20));      // 128 MiB
    u16* woutT   = (u16*)(ws + (216l << 20));     // 62.5 MiB
    float* bqkvS = (float*)(ws + (280l << 20));   // 48 KiB
    float* bqkvC = (float*)(ws + (280l << 20) + (64l << 10));  // 48 KiB
    const long WLAY = 16l * 1024 * 1024;          // u16 elems per layer block

    // ---- one-time prep (batched transposes: 4 dispatches total) ----
    {
      TPtrs32 pa{};
      for (int i = 0; i < kL; ++i) {
        u16* wqkvS = wbase + i * WLAY;
        u16* woS   = wqkvS + 3072 * 1024;
        u16* wqkvC = woS + 1024 * 1024;
        u16* woC   = wqkvC + 3072 * 1024;
        pa.in[i * 8 + 0] = Wq_s + i * DD; pa.out[i * 8 + 0] = wqkvS;
        pa.in[i * 8 + 1] = Wk_s + i * DD; pa.out[i * 8 + 1] = wqkvS + 1024 * 1024;
        pa.in[i * 8 + 2] = Wv_s + i * DD; pa.out[i * 8 + 2] = wqkvS + 2048 * 1024;
        pa.in[i * 8 + 3] = Wo_s + i * DD; pa.out[i * 8 + 3] = woS;
        pa.in[i * 8 + 4] = Wq_c + i * DD; pa.out[i * 8 + 4] = wqkvC;
        pa.in[i * 8 + 5] = Wk_c + i * DD; pa.out[i * 8 + 5] = wqkvC + 1024 * 1024;
        pa.in[i * 8 + 6] = Wv_c + i * DD; pa.out[i * 8 + 6] = wqkvC + 2048 * 1024;
        pa.in[i * 8 + 7] = Wo_c + i * DD; pa.out[i * 8 + 7] = woC;
      }
      transpose_wt_v4<<<dim3(16, 16, 32), blk256, 0, stream>>>(pa, 1024, 1024);
      TPtrs32 p1{};
      for (int i = 0; i < kL; ++i) {
        p1.in[i] = W1 + (long)i * kD * kF;
        p1.out[i] = wbase + i * WLAY + 8l * 1024 * 1024;  // w1t
      }
      transpose_wt_v4<<<dim3(64, 16, 4), blk256, 0, stream>>>(p1, 1024, 4096);
      TPtrs32 p2{};
      for (int i = 0; i < kL; ++i) {
        p2.in[i] = W2 + (long)i * kF * kD;
        p2.out[i] = wbase + i * WLAY + 12l * 1024 * 1024; // w2t
      }
      transpose_wt_v4<<<dim3(16, 64, 4), blk256, 0, stream>>>(p2, 4096, 1024);
      TPtrs32 po{}; po.in[0] = Wout; po.out[0] = woutT;
      transpose_wt_v4<<<dim3(500, 16, 1), blk256, 0, stream>>>(po, 1024, 32000);
    }
    concat_bias<<<dim3(48), blk256, 0, stream>>>(bqkvS, bq_s, bk_s, bv_s, 3);
    concat_bias<<<dim3(48), blk256, 0, stream>>>(bqkvC, bq_c, bk_c, bv_c, 3);
    cvt_bf16_v3<<<dim3(2048), blk256, 0, stream>>>(enc, encb, encb2);
    embed_v2<<<dim3(kM), blk256, 0, stream>>>(tgt, emb, x, xb);

    for (int i = 0; i < kL; ++i) {
      u16* wqkvS = wbase + i * WLAY;
      u16* woS   = wqkvS + 3072 * 1024;
      u16* wqkvC = woS + 1024 * 1024;
      u16* woC   = wqkvC + 3072 * 1024;
      u16* w1t   = woC + 1024 * 1024;
      u16* w2t   = w1t + (long)4096 * 1024;
      float* wSelf  = out + kLOG + (long)i * kBHTT;
      float* wCross = out + kLOG + (long)kL * kBHTT + (long)i * kBHTT;

      // -------- self attention --------
      gemm_bf<128, 128, 1, 1, 1><<<dim3(24, 16, 1), blk256, 0, stream>>>(
          xb, wqkvS, bqkvS + i * 3072, Sqkv, vt, 1024, 1024, 1024, 3072,
          1, 0, 0, 0, 0, 0, 0, 1.0f, 0, 0);
      attn_fused<1><<<dim3(4, 64), dim3(512), 0, stream>>>(Sqkv, Sqkv + 1024, vt, wSelf, S3b);
      // O-proj: split-K x4 (K=256 each), single-buffer, bf16 partials
      gemm_bf<128, 128, 1, 0, 0><<<dim3(8, 16, 4), blk256, 0, stream>>>(
          S3b, woS, bo_s + (long)i * kD, SpartB, nullptr, 256, 1024, 1024, 1024,
          1, 256, 0, 256, 0, kPART, 0, 1.0f, 0, 0);
      add_ln_v4<<<dim3(kM), blk256, 0, stream>>>(x, xb, SpartB, 4,
          ln1g + (long)i * kD, ln1b + (long)i * kD);

      // -------- cross attention (merged Q/K/V via z: xb|encb|encb2) --------
      gemm_bf<128, 128, 1, 1, 1><<<dim3(8, 16, 3), blk256, 0, stream>>>(
          xb, wqkvC, bqkvC + i * 3072, Sqkv, vt, 1024, 1024, 1024, 3072,
          3, 0, (long)2048 * 1024, 0, (long)1024 * 1024, 0, 1024, 1.0f, 0, 1024);
      attn_fused<0><<<dim3(4, 64), dim3(512), 0, stream>>>(Sqkv, Sqkv + 1024, vt, wCross, S3b);
      gemm_bf<128, 128, 1, 0, 0><<<dim3(8, 16, 4), blk256, 0, stream>>>(
          S3b, woC, bo_c + (long)i * kD, SpartB, nullptr, 256, 1024, 1024, 1024,
          1, 256, 0, 256, 0, kPART, 0, 1.0f, 0, 0);
      add_ln_v4<<<dim3(kM), blk256, 0, stream>>>(x, xb, SpartB, 4,
          ln2g + (long)i * kD, ln2b + (long)i * kD);

      // -------- FFN --------
      gemm_bf<128, 128, 1, 0, 1><<<dim3(32, 16, 1), blk256, 0, stream>>>(
          xb, w1t, b1 + (long)i * kF, Hb, nullptr, 1024, 1024, 1024, 4096,
          1, 0, 0, 0, 0, 0, 0, 1.0f, 1, 0);
      // FFN2: split-K x4 (K=1024 each), single-buffer, bf16 partials
      gemm_bf<128, 128, 1, 0, 0><<<dim3(8, 16, 4), blk256, 0, stream>>>(
          Hb, w2t, b2 + (long)i * kD, SpartB, nullptr, 1024, 4096, 4096, 1024,
          1, 1024, 0, 1024, 0, kPART, 0, 1.0f, 0, 0);
      add_ln_v4<<<dim3(kM), blk256, 0, stream>>>(x, xb, SpartB, 4,
          ln3g + (long)i * kD, ln3b + (long)i * kD);
    }

    // logits: BN=256 single-buffer (2000 blocks, 3 blocks/CU)
    gemm_bf<128, 256, 0, 0, 0><<<dim3(125, 16, 1), blk256, 0, stream>>>(
        xb, woutT, bout, out, nullptr, 1024, 1024, 1024, 32000,
        1, 0, 0, 0, 0, 0, 0, 1.0f, 0, 0);
    return;
  }

  // =================== FALLBACK (Round-3 verified) ===================
  float* x = (float*)d_ws;
  char* sc = (char*)d_out;
  float* S0 = (float*)sc;
  float* S1 = (float*)(sc + (8l  << 20));
  float* S2 = (float*)(sc + (16l << 20));
  float* S3 = (float*)(sc + (24l << 20));
  float* S4 = (float*)(sc + (32l << 20));
  u16*   vt = (u16*)  (sc + (40l << 20));

  embed_kernel<<<dim3(kM), blk256, 0, stream>>>(tgt, emb, x);
  auto wgemm = [&](const float* A, const float* W, const float* bias, float* C) {
    gemm_kernel<128, 128, float, float, 1><<<dim3(kD / 128, kM / 128, 1), blk256, 0, stream>>>(
        A, W, bias, C, kD, kD, kD, kD, 1, 0, 0, 0, 0, 0, 0, 1.0f, 0);
  };
  for (int i = 0; i < kL; ++i) {
    const long wOff = (long)i * DD;
    float* wSelf  = out + kLOG + (long)i * kBHTT;
    float* wCross = out + kLOG + (long)kL * kBHTT + (long)i * kBHTT;
    wgemm(x, Wq_s + wOff, bq_s + (long)i * kD, S0);
    wgemm(x, Wk_s + wOff, bk_s + (long)i * kD, S1);
    wgemm(x, Wv_s + wOff, bv_s + (long)i * kD, S2);
    transpose_v_kernel<<<dim3(16, 2, 64), blkT, 0, stream>>>(S2, vt);
    gemm_kernel<128, 128, float, float, 0><<<dim3(4, 4, 64), blk256, 0, stream>>>(
        S0, S1, nullptr, wSelf, kDK, kD, kD, kT,
        kH, kTD, (long)kDK, kTD, (long)kDK, kHTT, kTT, 0.125f, 0);
    softmax_kernel<<<dim3(kB * kH * kT / 4), blk256, 0, stream>>>(wSelf, 1);
    gemm_kernel<128, 64, float, u16, 0><<<dim3(1, 4, 64), blk256, 0, stream>>>(
        wSelf, vt, nullptr, S3, kT, kT, kT, kD,
        kH, kHTT, kTT, (long)kH * kDK * kT, (long)kDK * kT, kTD, (long)kDK, 1.0f, 0);
    wgemm(S3, Wo_s + wOff, bo_s + (long)i * kD, S0);
    add_ln_kernel<<<dim3(kM), blk256, 0, stream>>>(x, S0, ln1g + (long)i * kD, ln1b + (long)i * kD);
    wgemm(x,   Wq_c + wOff, bq_c + (long)i * kD, S0);
    wgemm(enc, Wk_c + wOff, bk_c + (long)i * kD, S1);
    wgemm(enc, Wv_c + wOff, bv_c + (long)i * kD, S2);
    transpose_v_kernel<<<dim3(16, 2, 64), blkT, 0, stream>>>(S2, vt);
    gemm_kernel<128, 128, float, float, 0><<<dim3(4, 4, 64), blk256, 0, stream>>>(
        S0, S1, nullptr, wCross, kDK, kD, kD, kT,
        kH, kTD, (long)kDK, kTD, (long)kDK, kHTT, kTT, 0.125f, 0);
    softmax_kernel<<<dim3(kB * kH * kT / 4), blk256, 0, stream>>>(wCross, 0);
    gemm_kernel<128, 64, float, u16, 0><<<dim3(1, 4, 64), blk256, 0, stream>>>(
        wCross, vt, nullptr, S3, kT, kT, kT, kD,
        kH, kHTT, kTT, (long)kH * kDK * kT, (long)kDK * kT, kTD, (long)kDK, 1.0f, 0);
    wgemm(S3, Wo_c + wOff, bo_c + (long)i * kD, S0);
    add_ln_kernel<<<dim3(kM), blk256, 0, stream>>>(x, S0, ln2g + (long)i * kD, ln2b + (long)i * kD);
    gemm_kernel<128, 128, float, float, 1><<<dim3(kF / 128, kM / 128, 1), blk256, 0, stream>>>(
        x, W1 + (long)i * kD * kF, b1 + (long)i * kF, S0, kD, kD, kF, kF,
        1, 0, 0, 0, 0, 0, 0, 1.0f, 1);
    gemm_kernel<128, 128, float, float, 1><<<dim3(kD / 128, kM / 128, 1), blk256, 0, stream>>>(
        S0, W2 + (long)i * kF * kD, b2 + (long)i * kD, S4, kF, kF, kD, kD,
        1, 0, 0, 0, 0, 0, 0, 1.0f, 0);
    add_ln_kernel<<<dim3(kM), blk256, 0, stream>>>(x, S4, ln3g + (long)i * kD, ln3b + (long)i * kD);
  }
  gemm_kernel<128, 128, float, float, 1><<<dim3(kV / 128, kM / 128, 1), blk256, 0, stream>>>(
      x, Wout, bout, out, kD, kD, kV, kV,
      1, 0, 0, 0, 0, 0, 0, 1.0f, 0);
}

// Round 12
// 1472.174 us; speedup vs baseline: 1.0542x; 1.0542x over previous
//
#include <hip/hip_runtime.h>

// TransformerDecoder on MI355X. Round 12:
// - attn_fused: Q read directly from global (L2-resident) instead of LDS;
//   LDS 84->68 KB => 2 blocks/CU (was 1) — doubles attention TLP.
// - logits reverted to BN=128 dbuf (R10-measured best; BN=256 regressed).
// - keeps R11's batched transposes + bf16 split-K partials.
// Fallback = Round-3 proven.

typedef unsigned short u16;
typedef __bf16 v8bf __attribute__((ext_vector_type(8)));
typedef float v4f __attribute__((ext_vector_type(4)));

namespace {
constexpr int kB = 4, kT = 512, kD = 1024, kH = 16, kDK = 64, kF = 4096, kV = 32000, kL = 4;
constexpr int kM = kB * kT;
constexpr long kTD = (long)kT * kD;
constexpr long kTT = (long)kT * kT;
constexpr long kHTT = (long)kH * kTT;
constexpr long kBHTT = (long)kB * kHTT;
constexpr long kLOG = (long)kM * kV;
constexpr long kPART = (long)kM * kD;
}

__device__ __forceinline__ u16 f2bf(float f) {
  union { float f; unsigned u; } v; v.f = f;
  unsigned r = v.u + 0x7FFFu + ((v.u >> 16) & 1u);
  return (u16)(r >> 16);
}
__device__ __forceinline__ float bf2f(u16 h) {
  union { unsigned u; float f; } v; v.u = ((unsigned)h) << 16;
  return v.f;
}

typedef __attribute__((address_space(3))) void lds_void;
typedef const __attribute__((address_space(1))) void glob_void;
__device__ __forceinline__ void gl2lds16(const void* g, void* l) {
  __builtin_amdgcn_global_load_lds((glob_void*)g, (lds_void*)l, 16, 0, 0);
}

// ---------------------------------------------------------------------------
// bf16 GEMM, BK=64, swizzled LDS. DBUF=1: double-buffered (1 barrier/step).
// DBUF=0: single buffer (2 barriers/step, less LDS -> higher residency).
// C[m][n] = scale*sum A[m][k]*B[n][k] + bias[zh*bstride+n] (zb==0 only).
// VTR: cols>=2048 of a (.,3072) C also written transposed into vt (B,H,dk,T).
// ---------------------------------------------------------------------------
template <int BM, int BN, int OUTBF, int VTR, int DBUF>
__global__ __launch_bounds__(256)
void gemm_bf(const u16* __restrict__ A0, const u16* __restrict__ B0,
             const float* __restrict__ bias, void* __restrict__ Cv,
             u16* __restrict__ vtw,
             const int K, const int lda, const int ldb, const int ldc,
             const int nH, const long sAb, const long sAh,
             const long sBb, const long sBh, const long sCb, const long sCh,
             const float scale, const int relu, const int bstride) {
  static_assert(BM % 32 == 0 && BN % 32 == 0, "tiles");
  __shared__ u16 As[DBUF + 1][BM][64];
  __shared__ u16 Bs[DBUF + 1][BN][64];
  const int tid = threadIdx.x;
  const int lane = tid & 63;
  const int w = tid >> 6;
  const int z = blockIdx.z;
  const int zb = z / nH, zh = z - zb * nH;
  const u16* A = A0 + zb * sAb + zh * sAh + (long)blockIdx.y * BM * lda;
  const u16* B = B0 + zb * sBb + zh * sBh + (long)blockIdx.x * BN * ldb;
  const long offC = zb * sCb + zh * sCh;
  const int wm = w >> 1, wn = w & 1;
  constexpr int FM = BM / 32, FN = BN / 32;
  v4f acc[FM][FN];
  const v4f zero = {0.f, 0.f, 0.f, 0.f};
#pragma unroll
  for (int i = 0; i < FM; ++i)
#pragma unroll
    for (int j = 0; j < FN; ++j) acc[i][j] = zero;
  const int l15 = lane & 15, lk = lane >> 4;
  const int lr8 = lane >> 3;                       // row within 8-row stripe
  const int swz = ((lane & 7) ^ lr8) * 8;          // pre-swizzled source col
  const int l7 = l15 & 7;

  if constexpr (DBUF) {
    // prologue: stage tile 0 into buffer 0
#pragma unroll
    for (int s = 0; s < BM / 32; ++s)
      gl2lds16(A + (long)(w * (BM / 4) + s * 8 + lr8) * lda + swz,
               &As[0][w * (BM / 4) + s * 8][0]);
#pragma unroll
    for (int s = 0; s < BN / 32; ++s)
      gl2lds16(B + (long)(w * (BN / 4) + s * 8 + lr8) * ldb + swz,
               &Bs[0][w * (BN / 4) + s * 8][0]);

    const int NT = K >> 6;
    for (int kt = 0; kt < NT; ++kt) {
      const int cur = kt & 1;
      __syncthreads();   // drains prev stage + prev reads
      if (kt + 1 < NT) {
        const int k0 = (kt + 1) << 6;
#pragma unroll
        for (int s = 0; s < BM / 32; ++s)
          gl2lds16(A + (long)(w * (BM / 4) + s * 8 + lr8) * lda + k0 + swz,
                   &As[cur ^ 1][w * (BM / 4) + s * 8][0]);
#pragma unroll
        for (int s = 0; s < BN / 32; ++s)
          gl2lds16(B + (long)(w * (BN / 4) + s * 8 + lr8) * ldb + k0 + swz,
                   &Bs[cur ^ 1][w * (BN / 4) + s * 8][0]);
      }
#pragma unroll
      for (int t = 0; t < 2; ++t) {
        const int c0 = t * 4;
        v8bf af[FM], bfr[FN];
#pragma unroll
        for (int i = 0; i < FM; ++i)
          af[i] = *(const v8bf*)&As[cur][wm * (BM / 2) + i * 16 + l15][((c0 + lk) ^ l7) * 8];
#pragma unroll
        for (int j = 0; j < FN; ++j)
          bfr[j] = *(const v8bf*)&Bs[cur][wn * (BN / 2) + j * 16 + l15][((c0 + lk) ^ l7) * 8];
#pragma unroll
        for (int i = 0; i < FM; ++i)
#pragma unroll
          for (int j = 0; j < FN; ++j)
            acc[i][j] = __builtin_amdgcn_mfma_f32_16x16x32_bf16(af[i], bfr[j], acc[i][j], 0, 0, 0);
      }
    }
  } else {
    for (int k0 = 0; k0 < K; k0 += 64) {
      __syncthreads();
#pragma unroll
      for (int s = 0; s < BM / 32; ++s)
        gl2lds16(A + (long)(w * (BM / 4) + s * 8 + lr8) * lda + k0 + swz,
                 &As[0][w * (BM / 4) + s * 8][0]);
#pragma unroll
      for (int s = 0; s < BN / 32; ++s)
        gl2lds16(B + (long)(w * (BN / 4) + s * 8 + lr8) * ldb + k0 + swz,
                 &Bs[0][w * (BN / 4) + s * 8][0]);
      __syncthreads();
#pragma unroll
      for (int t = 0; t < 2; ++t) {
        const int c0 = t * 4;
        v8bf af[FM], bfr[FN];
#pragma unroll
        for (int i = 0; i < FM; ++i)
          af[i] = *(const v8bf*)&As[0][wm * (BM / 2) + i * 16 + l15][((c0 + lk) ^ l7) * 8];
#pragma unroll
        for (int j = 0; j < FN; ++j)
          bfr[j] = *(const v8bf*)&Bs[0][wn * (BN / 2) + j * 16 + l15][((c0 + lk) ^ l7) * 8];
#pragma unroll
        for (int i = 0; i < FM; ++i)
#pragma unroll
          for (int j = 0; j < FN; ++j)
            acc[i][j] = __builtin_amdgcn_mfma_f32_16x16x32_bf16(af[i], bfr[j], acc[i][j], 0, 0, 0);
      }
    }
  }

  const long m0 = (long)blockIdx.y * BM + wm * (BM / 2);
  const int n0 = blockIdx.x * BN + wn * (BN / 2);
#pragma unroll
  for (int j = 0; j < FN; ++j) {
    const int col = n0 + j * 16 + l15;
    const float bv = (bias && zb == 0) ? bias[zh * bstride + col] : 0.0f;
#pragma unroll
    for (int i = 0; i < FM; ++i) {
      const long row = m0 + i * 16 + lk * 4;
#pragma unroll
      for (int r = 0; r < 4; ++r) {
        float v = acc[i][j][r] * scale + bv;
        if (relu) v = fmaxf(v, 0.0f);
        const long idx = offC + (row + r) * ldc + col;
        if (OUTBF) ((u16*)Cv)[idx] = f2bf(v);
        else       ((float*)Cv)[idx] = v;
        if (VTR) {
          const int colS = (int)(offC % 3072) + col;   // column within (.,3072)
          if (colS >= 2048) {
            const int hh = (colS - 2048) >> 6, dd = (colS - 2048) & 63;
            const int rowg = (int)(row + r);
            vtw[((long)((rowg >> 9) * 16 + hh)) * 32768 + dd * 512 + (rowg & 511)] = f2bf(v);
          }
        }
      }
    }
  }
}

// ---------------------------------------------------------------------------
// Fused attention: per block 128 q-rows x one (b,h): QK^T (K in swizzled LDS,
// Q fragments read directly from global/L2), softmax (writes w f32 to d_out),
// then PV via padded-LDS P/V^T chunks, O bf16 into S3b (2048,1024).
// 512 threads = 8 waves (2 wm x 4 wn). LDS 68KB -> 2 blocks/CU.
// ---------------------------------------------------------------------------
template <int CAUSAL>
__global__ __launch_bounds__(512)
void attn_fused(const u16* __restrict__ Qb, const u16* __restrict__ Kb,
                const u16* __restrict__ vtp, float* __restrict__ wout,
                u16* __restrict__ oout) {
  __shared__ __align__(16) char lds[65536];
  u16 (*Ks)[64] = (u16 (*)[64])lds;                 // [512][64] = 64KB
  u16 (*Pl)[136] = (u16 (*)[136])lds;               // [128][136] 34816 B (aliases Ks)
  u16 (*Vt)[136] = (u16 (*)[136])(lds + 34816);     // [64][136]  17408 B (aliases Ks)
  __shared__ float redM[128][4];
  __shared__ float redS[128][4];
  const int tid = threadIdx.x, lane = tid & 63, w = tid >> 6;
  const int wm = w >> 2, wn = w & 3;
  const int l15 = lane & 15, lk = lane >> 4;
  const int lr8 = lane >> 3;
  const int swz = ((lane & 7) ^ lr8) * 8;
  const int l7 = l15 & 7;
  const int bx = blockIdx.x;
  const int z = blockIdx.y, zb = z >> 4, zh = z & 15;
  const u16* Q = Qb + (long)zb * 512 * 3072 + zh * 64 + (long)bx * 128 * 3072;
  const u16* Kp = Kb + (long)zb * 512 * 3072 + zh * 64;
  const u16* vtz = vtp + (long)((zb << 4) + zh) * 32768;
  const long obase = (long)zb * kHTT + (long)zh * kTT;

#pragma unroll
  for (int s = 0; s < 8; ++s) {
    const int r0 = w * 64 + s * 8;
    if (!CAUSAL || r0 <= bx * 128 + 127)
      gl2lds16(Kp + (long)(r0 + lr8) * 3072 + swz, &Ks[r0][0]);
  }
  __syncthreads();

  v4f acc[4][8];
  const v4f zero = {0.f, 0.f, 0.f, 0.f};
#pragma unroll
  for (int i = 0; i < 4; ++i)
#pragma unroll
    for (int j = 0; j < 8; ++j) acc[i][j] = zero;

#pragma unroll
  for (int t = 0; t < 2; ++t) {
    const int c0 = t * 4;
    v8bf aq[4], bk[8];
#pragma unroll
    for (int i = 0; i < 4; ++i)
      aq[i] = *(const v8bf*)(Q + (long)(wm * 64 + i * 16 + l15) * 3072 + (c0 + lk) * 8);
#pragma unroll
    for (int j = 0; j < 8; ++j)
      bk[j] = *(const v8bf*)&Ks[wn * 128 + j * 16 + l15][((c0 + lk) ^ l7) * 8];
#pragma unroll
    for (int i = 0; i < 4; ++i)
#pragma unroll
      for (int j = 0; j < 8; ++j)
        if (!(CAUSAL && wn * 128 + j * 16 > bx * 128 + wm * 64 + i * 16 + 15))
          acc[i][j] = __builtin_amdgcn_mfma_f32_16x16x32_bf16(aq[i], bk[j], acc[i][j], 0, 0, 0);
  }

  // row max
  float gmax[4][4];
#pragma unroll
  for (int i = 0; i < 4; ++i)
#pragma unroll
    for (int r = 0; r < 4; ++r) {
      const int q = bx * 128 + wm * 64 + i * 16 + lk * 4 + r;
      float m = -3.0e38f;
#pragma unroll
      for (int j = 0; j < 8; ++j) {
        const int col = wn * 128 + j * 16 + l15;
        if (!CAUSAL || col <= q) m = fmaxf(m, acc[i][j][r] * 0.125f);
      }
#pragma unroll
      for (int off = 1; off < 16; off <<= 1) m = fmaxf(m, __shfl_xor(m, off));
      if (l15 == 0) redM[wm * 64 + i * 16 + lk * 4 + r][wn] = m;
    }
  __syncthreads();
#pragma unroll
  for (int i = 0; i < 4; ++i)
#pragma unroll
    for (int r = 0; r < 4; ++r) {
      v4f mv = *(const v4f*)&redM[wm * 64 + i * 16 + lk * 4 + r][0];
      gmax[i][r] = fmaxf(fmaxf(mv[0], mv[1]), fmaxf(mv[2], mv[3]));
    }
  // exp + row sum
#pragma unroll
  for (int i = 0; i < 4; ++i)
#pragma unroll
    for (int r = 0; r < 4; ++r) {
      const int q = bx * 128 + wm * 64 + i * 16 + lk * 4 + r;
      float s = 0.0f;
#pragma unroll
      for (int j = 0; j < 8; ++j) {
        const int col = wn * 128 + j * 16 + l15;
        float e = (!CAUSAL || col <= q) ? __expf(acc[i][j][r] * 0.125f - gmax[i][r]) : 0.0f;
        acc[i][j][r] = e;
        s += e;
      }
#pragma unroll
      for (int off = 1; off < 16; off <<= 1) s += __shfl_xor(s, off);
      if (l15 == 0) redS[wm * 64 + i * 16 + lk * 4 + r][wn] = s;
    }
  __syncthreads();
  // normalize, write w (f32), keep normalized P in acc
#pragma unroll
  for (int i = 0; i < 4; ++i)
#pragma unroll
    for (int r = 0; r < 4; ++r) {
      v4f sv = *(const v4f*)&redS[wm * 64 + i * 16 + lk * 4 + r][0];
      const float inv = 1.0f / (sv[0] + sv[1] + sv[2] + sv[3]);
      const int q = bx * 128 + wm * 64 + i * 16 + lk * 4 + r;
      const long rowoff = obase + (long)q * 512;
#pragma unroll
      for (int j = 0; j < 8; ++j) {
        const int col = wn * 128 + j * 16 + l15;
        const float v = acc[i][j][r] * inv;
        acc[i][j][r] = v;
        wout[rowoff + col] = v;
      }
    }

  // ---- PV: O[128 q][64 d] = P @ V, chunked over k (128 per chunk) ----
  // Pl/Vt alias Ks; safe: all Ks reads completed before the barrier below.
  v4f acco[4];
#pragma unroll
  for (int i = 0; i < 4; ++i) acco[i] = zero;
  const int kcMax = CAUSAL ? bx : 3;
  for (int kc = 0; kc <= kcMax; ++kc) {
    __syncthreads();
    if (wn == kc) {       // this wave-group owns P cols [kc*128, kc*128+128)
#pragma unroll
      for (int i = 0; i < 4; ++i)
#pragma unroll
        for (int j = 0; j < 8; ++j) {
          const int colk = j * 16 + l15;
#pragma unroll
          for (int r = 0; r < 4; ++r)
            Pl[wm * 64 + i * 16 + lk * 4 + r][colk] = f2bf(acc[i][j][r]);
        }
    }
    // stage V^T chunk [64 d][128 k] into padded Vt
#pragma unroll
    for (int s = 0; s < 2; ++s) {
      const int c = tid * 2 + s;            // 0..1023 chunks of 16B
      const int d = c >> 4, off = (c & 15) * 8;
      uint4 vv = *(const uint4*)(vtz + (long)d * 512 + kc * 128 + off);
      *(uint4*)&Vt[d][off] = vv;
    }
    __syncthreads();
#pragma unroll
    for (int t = 0; t < 4; ++t) {
      v8bf bv = *(const v8bf*)&Vt[wn * 16 + l15][t * 32 + lk * 8];
#pragma unroll
      for (int i = 0; i < 4; ++i) {
        v8bf ap = *(const v8bf*)&Pl[wm * 64 + i * 16 + l15][t * 32 + lk * 8];
        acco[i] = __builtin_amdgcn_mfma_f32_16x16x32_bf16(ap, bv, acco[i], 0, 0, 0);
      }
    }
  }
  // write O bf16 into S3b (2048,1024) at column zh*64
#pragma unroll
  for (int i = 0; i < 4; ++i)
#pragma unroll
    for (int r = 0; r < 4; ++r) {
      const int row = bx * 128 + wm * 64 + i * 16 + lk * 4 + r;
      oout[(long)(zb * 512 + row) * 1024 + zh * 64 + wn * 16 + l15] = f2bf(acco[i][r]);
    }
}

// Weight transpose-convert: out(N,K) bf16 = in(K,N)^T f32; 64x64 tiles,
// float4 vectorized loads, uint2 vectorized stores. Up to 32 matrices/launch.
struct TPtrs32 { const float* in[32]; u16* out[32]; };

__global__ void transpose_wt_v4(TPtrs32 ps, int K, int N) {
  __shared__ float tile[64][65];
  const float* in = ps.in[blockIdx.z];
  u16* o = ps.out[blockIdx.z];
  const int n0 = blockIdx.x * 64, k0 = blockIdx.y * 64;
  const int tr = threadIdx.x >> 4;          // 0..15
  const int tc = (threadIdx.x & 15) * 4;    // 0,4,..,60
#pragma unroll
  for (int i = 0; i < 4; ++i) {
    float4 v = *(const float4*)(in + (long)(k0 + tr + 16 * i) * N + n0 + tc);
    tile[tr + 16 * i][tc + 0] = v.x;
    tile[tr + 16 * i][tc + 1] = v.y;
    tile[tr + 16 * i][tc + 2] = v.z;
    tile[tr + 16 * i][tc + 3] = v.w;
  }
  __syncthreads();
#pragma unroll
  for (int i = 0; i < 4; ++i) {
    const int rr = tr + 16 * i;             // n within tile
    u16 h[4];
#pragma unroll
    for (int j = 0; j < 4; ++j) h[j] = f2bf(tile[tc + j][rr]);
    *(uint2*)(o + (long)(n0 + rr) * K + k0 + tc) = *(const uint2*)h;
  }
}

__global__ void concat_bias(float* __restrict__ dst, const float* __restrict__ s0,
                            const float* __restrict__ s1, const float* __restrict__ s2,
                            const int nsrc) {
  const int idx = blockIdx.x * 256 + threadIdx.x;
  const int per = nsrc << 10;
  const int l = idx / per, rem = idx - l * per, s = rem >> 10, j = rem & 1023;
  const float* src = (s == 0) ? s0 : (s == 1 ? s1 : s2);
  dst[idx] = src[l * 1024 + j];
}

__global__ void cvt_bf16_v3(const float* __restrict__ in, u16* __restrict__ o1,
                            u16* __restrict__ o2) {
  const long i = ((long)blockIdx.x * 256 + threadIdx.x) * 4;
  float4 v = *(const float4*)(in + i);
  u16 h[4] = {f2bf(v.x), f2bf(v.y), f2bf(v.z), f2bf(v.w)};
  *(uint2*)(o1 + i) = *(const uint2*)h;
  *(uint2*)(o2 + i) = *(const uint2*)h;
}

__global__ void embed_v2(const int* __restrict__ tgt, const float* __restrict__ emb,
                         float* __restrict__ x, u16* __restrict__ xb) {
  const int row = blockIdx.x;
  const int t = row & (kT - 1);
  const int tok = tgt[row];
  const int c = threadIdx.x * 4;
  float4 e = *(const float4*)(emb + (long)tok * kD + c);
  const float nl = -9.210340371976184f / (float)kD;
  const float a0 = (float)t * expf((float)c * nl);
  const float a1 = (float)t * expf((float)(c + 2) * nl);
  float4 o;
  o.x = e.x * 32.0f + sinf(a0);
  o.y = e.y * 32.0f + cosf(a0);
  o.z = e.z * 32.0f + sinf(a1);
  o.w = e.w * 32.0f + cosf(a1);
  *(float4*)(x + (long)row * kD + c) = o;
  u16 h[4] = {f2bf(o.x), f2bf(o.y), f2bf(o.z), f2bf(o.w)};
  *(uint2*)(xb + (long)row * kD + c) = *(const uint2*)h;
}

// x = LN(x + sum_{p<nres} resb[p]) with bf16 partials; writes x f32 and xb bf16
__global__ void add_ln_v4(float* __restrict__ x, u16* __restrict__ xb,
                          const u16* __restrict__ resb, const int nres,
                          const float* __restrict__ g, const float* __restrict__ b) {
  const int row = blockIdx.x;
  const int c = threadIdx.x * 4;
  float4 xv = *(const float4*)(x + (long)row * kD + c);
  float v0 = xv.x, v1 = xv.y, v2 = xv.z, v3 = xv.w;
  for (int p = 0; p < nres; ++p) {
    uint2 rv = *(const uint2*)(resb + p * kPART + (long)row * kD + c);
    v0 += bf2f((u16)(rv.x & 0xffffu));
    v1 += bf2f((u16)(rv.x >> 16));
    v2 += bf2f((u16)(rv.y & 0xffffu));
    v3 += bf2f((u16)(rv.y >> 16));
  }
  float s = v0 + v1 + v2 + v3;
  float ss = v0 * v0 + v1 * v1 + v2 * v2 + v3 * v3;
#pragma unroll
  for (int o = 32; o > 0; o >>= 1) { s += __shfl_xor(s, o); ss += __shfl_xor(ss, o); }
  __shared__ float red[4][2];
  const int wv = threadIdx.x >> 6;
  if ((threadIdx.x & 63) == 0) { red[wv][0] = s; red[wv][1] = ss; }
  __syncthreads();
  s  = red[0][0] + red[1][0] + red[2][0] + red[3][0];
  ss = red[0][1] + red[1][1] + red[2][1] + red[3][1];
  const float mean = s * (1.0f / kD);
  const float var = ss * (1.0f / kD) - mean * mean;
  const float rs = rsqrtf(var + 1e-5f);
  float4 gv = *(const float4*)(g + c);
  float4 bv = *(const float4*)(b + c);
  float4 o;
  o.x = gv.x * (v0 - mean) * rs + bv.x;
  o.y = gv.y * (v1 - mean) * rs + bv.y;
  o.z = gv.z * (v2 - mean) * rs + bv.z;
  o.w = gv.w * (v3 - mean) * rs + bv.w;
  *(float4*)(x + (long)row * kD + c) = o;
  u16 h[4] = {f2bf(o.x), f2bf(o.y), f2bf(o.z), f2bf(o.w)};
  *(uint2*)(xb + (long)row * kD + c) = *(const uint2*)h;
}

// ===========================================================================
// FALLBACK PATH (Round-3 proven)
// ===========================================================================
template <int BM, int BN, typename TA, typename TB, int BKN>
__global__ __launch_bounds__(256)
void gemm_kernel(const void* __restrict__ Av, const void* __restrict__ Bv,
                 const float* __restrict__ bias, float* __restrict__ Cv,
                 const int K, const int lda, const int ldb, const int ldc,
                 const int nH, const long sAb, const long sAh,
                 const long sBb, const long sBh, const long sCb, const long sCh,
                 const float scale, const int relu) {
  constexpr int LP = 40;
  __shared__ u16 As[BM][LP];
  __shared__ u16 Bs[BN][LP];
  const int tid = threadIdx.x;
  const int z = blockIdx.z;
  const int zb = z / nH, zh = z - zb * nH;
  const TA* A = (const TA*)Av + zb * sAb + zh * sAh + (long)blockIdx.y * BM * lda;
  const TB* Bp;
  if constexpr (BKN)
    Bp = (const TB*)Bv + zb * sBb + zh * sBh + (long)blockIdx.x * BN;
  else
    Bp = (const TB*)Bv + zb * sBb + zh * sBh + (long)blockIdx.x * BN * ldb;
  const long offC = zb * sCb + zh * sCh;
  const int lane = tid & 63;
  const int wm = (tid >> 7) & 1, wn = (tid >> 6) & 1;
  constexpr int FM = BM / 32, FN = BN / 32;
  v4f acc[FM][FN];
  const v4f zero = {0.f, 0.f, 0.f, 0.f};
#pragma unroll
  for (int i = 0; i < FM; ++i)
#pragma unroll
    for (int j = 0; j < FN; ++j) acc[i][j] = zero;
  const int l15 = lane & 15, lk = lane >> 4;

  for (int k0 = 0; k0 < K; k0 += 32) {
    __syncthreads();
    if constexpr (sizeof(TA) == 4) {
      const int r = tid >> 3, c = (tid & 7) * 4;
#pragma unroll
      for (int rr = 0; rr < BM; rr += 32) {
        float4 vv = *(const float4*)((const float*)A + (long)(rr + r) * lda + k0 + c);
        unsigned lo = (unsigned)f2bf(vv.x) | ((unsigned)f2bf(vv.y) << 16);
        unsigned hi = (unsigned)f2bf(vv.z) | ((unsigned)f2bf(vv.w) << 16);
        *(uint2*)&As[rr + r][c] = make_uint2(lo, hi);
      }
    } else {
      const int r = tid >> 2, c = (tid & 3) * 8;
#pragma unroll
      for (int rr = 0; rr < BM; rr += 64) {
        uint4 vv = *(const uint4*)((const u16*)A + (long)(rr + r) * lda + k0 + c);
        *(uint4*)&As[rr + r][c] = vv;
      }
    }
    if constexpr (BKN) {
      const int r = tid >> 3, c = (tid & 7) * 4;
#pragma unroll
      for (int nn = 0; nn < BN; nn += 32) {
        float4 vv = *(const float4*)((const float*)Bp + (long)(k0 + r) * ldb + nn + c);
        Bs[nn + c + 0][r] = f2bf(vv.x);
        Bs[nn + c + 1][r] = f2bf(vv.y);
        Bs[nn + c + 2][r] = f2bf(vv.z);
        Bs[nn + c + 3][r] = f2bf(vv.w);
      }
    } else if constexpr (sizeof(TB) == 4) {
      const int r = tid >> 3, c = (tid & 7) * 4;
#pragma unroll
      for (int rr = 0; rr < BN; rr += 32) {
        float4 vv = *(const float4*)((const float*)Bp + (long)(rr + r) * ldb + k0 + c);
        unsigned lo = (unsigned)f2bf(vv.x) | ((unsigned)f2bf(vv.y) << 16);
        unsigned hi = (unsigned)f2bf(vv.z) | ((unsigned)f2bf(vv.w) << 16);
        *(uint2*)&Bs[rr + r][c] = make_uint2(lo, hi);
      }
    } else {
      const int r = tid >> 2, c = (tid & 3) * 8;
#pragma unroll
      for (int rr = 0; rr < BN; rr += 64) {
        uint4 vv = *(const uint4*)((const u16*)Bp + (long)(rr + r) * ldb + k0 + c);
        *(uint4*)&Bs[rr + r][c] = vv;
      }
    }
    __syncthreads();
    v8bf af[FM], bfr[FN];
#pragma unroll
    for (int i = 0; i < FM; ++i)
      af[i] = *(const v8bf*)&As[wm * (BM / 2) + i * 16 + l15][lk * 8];
#pragma unroll
    for (int j = 0; j < FN; ++j)
      bfr[j] = *(const v8bf*)&Bs[wn * (BN / 2) + j * 16 + l15][lk * 8];
#pragma unroll
    for (int i = 0; i < FM; ++i)
#pragma unroll
      for (int j = 0; j < FN; ++j)
        acc[i][j] = __builtin_amdgcn_mfma_f32_16x16x32_bf16(af[i], bfr[j], acc[i][j], 0, 0, 0);
  }

  const long m0 = (long)blockIdx.y * BM + wm * (BM / 2);
  const int n0 = blockIdx.x * BN + wn * (BN / 2);
#pragma unroll
  for (int j = 0; j < FN; ++j) {
    const int col = n0 + j * 16 + l15;
    const float bv = bias ? bias[col] : 0.0f;
#pragma unroll
    for (int i = 0; i < FM; ++i) {
      const long row = m0 + i * 16 + lk * 4;
#pragma unroll
      for (int r = 0; r < 4; ++r) {
        float v = acc[i][j][r] * scale + bv;
        if (relu) v = fmaxf(v, 0.0f);
        Cv[offC + (row + r) * ldc + col] = v;
      }
    }
  }
}

__global__ void embed_kernel(const int* __restrict__ tgt, const float* __restrict__ emb,
                             float* __restrict__ x) {
  const int row = blockIdx.x;
  const int t = row & (kT - 1);
  const int tok = tgt[row];
  const int c = threadIdx.x * 4;
  float4 e = *(const float4*)(emb + (long)tok * kD + c);
  const float nl = -9.210340371976184f / (float)kD;
  const float a0 = (float)t * expf((float)c * nl);
  const float a1 = (float)t * expf((float)(c + 2) * nl);
  float4 o;
  o.x = e.x * 32.0f + sinf(a0);
  o.y = e.y * 32.0f + cosf(a0);
  o.z = e.z * 32.0f + sinf(a1);
  o.w = e.w * 32.0f + cosf(a1);
  *(float4*)(x + (long)row * kD + c) = o;
}

__global__ void transpose_v_kernel(const float* __restrict__ v, u16* __restrict__ vt) {
  __shared__ float tile[32][33];
  const int z = blockIdx.z;
  const int b = z >> 4, h = z & 15;
  const int t0 = blockIdx.x * 32, d0 = blockIdx.y * 32;
  const int tx = threadIdx.x, ty = threadIdx.y;
  const float* in = v + (long)b * kTD + (long)h * kDK;
#pragma unroll
  for (int i = 0; i < 4; ++i)
    tile[ty + 8 * i][tx] = in[(long)(t0 + ty + 8 * i) * kD + d0 + tx];
  __syncthreads();
  u16* o = vt + (long)z * kDK * kT;
#pragma unroll
  for (int i = 0; i < 4; ++i)
    o[(long)(d0 + ty + 8 * i) * kT + t0 + tx] = f2bf(tile[tx][ty + 8 * i]);
}

__global__ void softmax_kernel(float* __restrict__ w, const int causal) {
  const int rowg = blockIdx.x * 4 + (threadIdx.x >> 6);
  const int lane = threadIdx.x & 63;
  const int q = rowg & (kT - 1);
  float* p = w + (long)rowg * kT + lane * 8;
  float4 v0 = *(const float4*)p;
  float4 v1 = *(const float4*)(p + 4);
  float f[8] = {v0.x, v0.y, v0.z, v0.w, v1.x, v1.y, v1.z, v1.w};
  const int base = lane * 8;
  float mx = -3.0e38f;
#pragma unroll
  for (int j = 0; j < 8; ++j)
    if (!causal || base + j <= q) mx = fmaxf(mx, f[j]);
#pragma unroll
  for (int o = 32; o > 0; o >>= 1) mx = fmaxf(mx, __shfl_xor(mx, o));
  float s = 0.0f;
#pragma unroll
  for (int j = 0; j < 8; ++j) {
    float e = (!causal || base + j <= q) ? __expf(f[j] - mx) : 0.0f;
    f[j] = e; s += e;
  }
#pragma unroll
  for (int o = 32; o > 0; o >>= 1) s += __shfl_xor(s, o);
  const float inv = 1.0f / s;
  float4 o0 = {f[0] * inv, f[1] * inv, f[2] * inv, f[3] * inv};
  float4 o1 = {f[4] * inv, f[5] * inv, f[6] * inv, f[7] * inv};
  *(float4*)p = o0;
  *(float4*)(p + 4) = o1;
}

__global__ void add_ln_kernel(float* __restrict__ x, const float* __restrict__ res,
                              const float* __restrict__ g, const float* __restrict__ b) {
  const int row = blockIdx.x;
  const int c = threadIdx.x * 4;
  float4 xv = *(const float4*)(x + (long)row * kD + c);
  float4 rv = *(const float4*)(res + (long)row * kD + c);
  const float v0 = xv.x + rv.x, v1 = xv.y + rv.y, v2 = xv.z + rv.z, v3 = xv.w + rv.w;
  float s = v0 + v1 + v2 + v3;
  float ss = v0 * v0 + v1 * v1 + v2 * v2 + v3 * v3;
#pragma unroll
  for (int o = 32; o > 0; o >>= 1) { s += __shfl_xor(s, o); ss += __shfl_xor(ss, o); }
  __shared__ float red[4][2];
  const int wv = threadIdx.x >> 6;
  if ((threadIdx.x & 63) == 0) { red[wv][0] = s; red[wv][1] = ss; }
  __syncthreads();
  s  = red[0][0] + red[1][0] + red[2][0] + red[3][0];
  ss = red[0][1] + red[1][1] + red[2][1] + red[3][1];
  const float mean = s * (1.0f / kD);
  const float var = ss * (1.0f / kD) - mean * mean;
  const float rs = rsqrtf(var + 1e-5f);
  float4 gv = *(const float4*)(g + c);
  float4 bv = *(const float4*)(b + c);
  float4 o;
  o.x = gv.x * (v0 - mean) * rs + bv.x;
  o.y = gv.y * (v1 - mean) * rs + bv.y;
  o.z = gv.z * (v2 - mean) * rs + bv.z;
  o.w = gv.w * (v3 - mean) * rs + bv.w;
  *(float4*)(x + (long)row * kD + c) = o;
}

// ===========================================================================
extern "C" void kernel_launch(void* const* d_in, const int* in_sizes, int n_in,
                              void* d_out, int out_size, void* d_ws, size_t ws_size,
                              hipStream_t stream) {
  const int*   tgt  = (const int*)d_in[0];
  const float* enc  = (const float*)d_in[1];
  const float* emb  = (const float*)d_in[3];
  const float* Wout = (const float*)d_in[4];
  const float* bout = (const float*)d_in[5];
  const float* Wq_s = (const float*)d_in[6];
  const float* bq_s = (const float*)d_in[7];
  const float* Wk_s = (const float*)d_in[8];
  const float* bk_s = (const float*)d_in[9];
  const float* Wv_s = (const float*)d_in[10];
  const float* bv_s = (const float*)d_in[11];
  const float* Wo_s = (const float*)d_in[12];
  const float* bo_s = (const float*)d_in[13];
  const float* Wq_c = (const float*)d_in[14];
  const float* bq_c = (const float*)d_in[15];
  const float* Wk_c = (const float*)d_in[16];
  const float* bk_c = (const float*)d_in[17];
  const float* Wv_c = (const float*)d_in[18];
  const float* bv_c = (const float*)d_in[19];
  const float* Wo_c = (const float*)d_in[20];
  const float* bo_c = (const float*)d_in[21];
  const float* W1   = (const float*)d_in[22];
  const float* b1   = (const float*)d_in[23];
  const float* W2   = (const float*)d_in[24];
  const float* b2   = (const float*)d_in[25];
  const float* ln1g = (const float*)d_in[26];
  const float* ln1b = (const float*)d_in[27];
  const float* ln2g = (const float*)d_in[28];
  const float* ln2b = (const float*)d_in[29];
  const float* ln3g = (const float*)d_in[30];
  const float* ln3b = (const float*)d_in[31];

  float* out = (float*)d_out;
  const long DD = (long)kD * kD;
  const dim3 blk256(256), blkT(32, 8);

  if (ws_size >= (320ll << 20)) {
    // =================== FAST PATH ===================
    char* ws = (char*)d_ws;
    float* x     = (float*)ws;                    // 8 MiB
    u16* xb      = (u16*)(ws + (8l << 20));       // 4 MiB (contiguous with encb)
    u16* encb    = (u16*)(ws + (12l << 20));      // 4 MiB (A source, merged cross)
    u16* encb2   = (u16*)(ws + (16l << 20));      // 4 MiB (second copy for V slice)
    u16* Sqkv    = (u16*)(ws + (20l << 20));      // 12 MiB (2048x3072)
    u16* vt      = (u16*)(ws + (32l << 20));      // 4 MiB (B,H,dk,T)
    u16* S3b     = (u16*)(ws + (36l << 20));      // 4 MiB
    u16* Hb      = (u16*)(ws + (40l << 20));      // 16 MiB (2048x4096)
    u16* SpartB  = (u16*)(ws + (56l << 20));      // 16 MiB (4 bf16 partials)
    u16* wbase   = (u16*)(ws + (88l << 20));      // 128 MiB
    u16* woutT   = (u16*)(ws + (216l << 20));     // 62.5 MiB
    float* bqkvS = (float*)(ws + (280l << 20));   // 48 KiB
    float* bqkvC = (float*)(ws + (280l << 20) + (64l << 10));  // 48 KiB
    const long WLAY = 16l * 1024 * 1024;          // u16 elems per layer block

    // ---- one-time prep (batched transposes: 4 dispatches total) ----
    {
      TPtrs32 pa{};
      for (int i = 0; i < kL; ++i) {
        u16* wqkvS = wbase + i * WLAY;
        u16* woS   = wqkvS + 3072 * 1024;
        u16* wqkvC = woS + 1024 * 1024;
        u16* woC   = wqkvC + 3072 * 1024;
        pa.in[i * 8 + 0] = Wq_s + i * DD; pa.out[i * 8 + 0] = wqkvS;
        pa.in[i * 8 + 1] = Wk_s + i * DD; pa.out[i * 8 + 1] = wqkvS + 1024 * 1024;
        pa.in[i * 8 + 2] = Wv_s + i * DD; pa.out[i * 8 + 2] = wqkvS + 2048 * 1024;
        pa.in[i * 8 + 3] = Wo_s + i * DD; pa.out[i * 8 + 3] = woS;
        pa.in[i * 8 + 4] = Wq_c + i * DD; pa.out[i * 8 + 4] = wqkvC;
        pa.in[i * 8 + 5] = Wk_c + i * DD; pa.out[i * 8 + 5] = wqkvC + 1024 * 1024;
        pa.in[i * 8 + 6] = Wv_c + i * DD; pa.out[i * 8 + 6] = wqkvC + 2048 * 1024;
        pa.in[i * 8 + 7] = Wo_c + i * DD; pa.out[i * 8 + 7] = woC;
      }
      transpose_wt_v4<<<dim3(16, 16, 32), blk256, 0, stream>>>(pa, 1024, 1024);
      TPtrs32 p1{};
      for (int i = 0; i < kL; ++i) {
        p1.in[i] = W1 + (long)i * kD * kF;
        p1.out[i] = wbase + i * WLAY + 8l * 1024 * 1024;  // w1t
      }
      transpose_wt_v4<<<dim3(64, 16, 4), blk256, 0, stream>>>(p1, 1024, 4096);
      TPtrs32 p2{};
      for (int i = 0; i < kL; ++i) {
        p2.in[i] = W2 + (long)i * kF * kD;
        p2.out[i] = wbase + i * WLAY + 12l * 1024 * 1024; // w2t
      }
      transpose_wt_v4<<<dim3(16, 64, 4), blk256, 0, stream>>>(p2, 4096, 1024);
      TPtrs32 po{}; po.in[0] = Wout; po.out[0] = woutT;
      transpose_wt_v4<<<dim3(500, 16, 1), blk256, 0, stream>>>(po, 1024, 32000);
    }
    concat_bias<<<dim3(48), blk256, 0, stream>>>(bqkvS, bq_s, bk_s, bv_s, 3);
    concat_bias<<<dim3(48), blk256, 0, stream>>>(bqkvC, bq_c, bk_c, bv_c, 3);
    cvt_bf16_v3<<<dim3(2048), blk256, 0, stream>>>(enc, encb, encb2);
    embed_v2<<<dim3(kM), blk256, 0, stream>>>(tgt, emb, x, xb);

    for (int i = 0; i < kL; ++i) {
      u16* wqkvS = wbase + i * WLAY;
      u16* woS   = wqkvS + 3072 * 1024;
      u16* wqkvC = woS + 1024 * 1024;
      u16* woC   = wqkvC + 3072 * 1024;
      u16* w1t   = woC + 1024 * 1024;
      u16* w2t   = w1t + (long)4096 * 1024;
      float* wSelf  = out + kLOG + (long)i * kBHTT;
      float* wCross = out + kLOG + (long)kL * kBHTT + (long)i * kBHTT;

      // -------- self attention --------
      gemm_bf<128, 128, 1, 1, 1><<<dim3(24, 16, 1), blk256, 0, stream>>>(
          xb, wqkvS, bqkvS + i * 3072, Sqkv, vt, 1024, 1024, 1024, 3072,
          1, 0, 0, 0, 0, 0, 0, 1.0f, 0, 0);
      attn_fused<1><<<dim3(4, 64), dim3(512), 0, stream>>>(Sqkv, Sqkv + 1024, vt, wSelf, S3b);
      // O-proj: split-K x4 (K=256 each), single-buffer, bf16 partials
      gemm_bf<128, 128, 1, 0, 0><<<dim3(8, 16, 4), blk256, 0, stream>>>(
          S3b, woS, bo_s + (long)i * kD, SpartB, nullptr, 256, 1024, 1024, 1024,
          1, 256, 0, 256, 0, kPART, 0, 1.0f, 0, 0);
      add_ln_v4<<<dim3(kM), blk256, 0, stream>>>(x, xb, SpartB, 4,
          ln1g + (long)i * kD, ln1b + (long)i * kD);

      // -------- cross attention (merged Q/K/V via z: xb|encb|encb2) --------
      gemm_bf<128, 128, 1, 1, 1><<<dim3(8, 16, 3), blk256, 0, stream>>>(
          xb, wqkvC, bqkvC + i * 3072, Sqkv, vt, 1024, 1024, 1024, 3072,
          3, 0, (long)2048 * 1024, 0, (long)1024 * 1024, 0, 1024, 1.0f, 0, 1024);
      attn_fused<0><<<dim3(4, 64), dim3(512), 0, stream>>>(Sqkv, Sqkv + 1024, vt, wCross, S3b);
      gemm_bf<128, 128, 1, 0, 0><<<dim3(8, 16, 4), blk256, 0, stream>>>(
          S3b, woC, bo_c + (long)i * kD, SpartB, nullptr, 256, 1024, 1024, 1024,
          1, 256, 0, 256, 0, kPART, 0, 1.0f, 0, 0);
      add_ln_v4<<<dim3(kM), blk256, 0, stream>>>(x, xb, SpartB, 4,
          ln2g + (long)i * kD, ln2b + (long)i * kD);

      // -------- FFN --------
      gemm_bf<128, 128, 1, 0, 1><<<dim3(32, 16, 1), blk256, 0, stream>>>(
          xb, w1t, b1 + (long)i * kF, Hb, nullptr, 1024, 1024, 1024, 4096,
          1, 0, 0, 0, 0, 0, 0, 1.0f, 1, 0);
      // FFN2: split-K x4 (K=1024 each), single-buffer, bf16 partials
      gemm_bf<128, 128, 1, 0, 0><<<dim3(8, 16, 4), blk256, 0, stream>>>(
          Hb, w2t, b2 + (long)i * kD, SpartB, nullptr, 1024, 4096, 4096, 1024,
          1, 1024, 0, 1024, 0, kPART, 0, 1.0f, 0, 0);
      add_ln_v4<<<dim3(kM), blk256, 0, stream>>>(x, xb, SpartB, 4,
          ln3g + (long)i * kD, ln3b + (long)i * kD);
    }

    // logits: BN=128 double-buffered (R10-measured best)
    gemm_bf<128, 128, 0, 0, 1><<<dim3(250, 16, 1), blk256, 0, stream>>>(
        xb, woutT, bout, out, nullptr, 1024, 1024, 1024, 32000,
        1, 0, 0, 0, 0, 0, 0, 1.0f, 0, 0);
    return;
  }

  // =================== FALLBACK (Round-3 verified) ===================
  float* x = (float*)d_ws;
  char* sc = (char*)d_out;
  float* S0 = (float*)sc;
  float* S1 = (float*)(sc + (8l  << 20));
  float* S2 = (float*)(sc + (16l << 20));
  float* S3 = (float*)(sc + (24l << 20));
  float* S4 = (float*)(sc + (32l << 20));
  u16*   vt = (u16*)  (sc + (40l << 20));

  embed_kernel<<<dim3(kM), blk256, 0, stream>>>(tgt, emb, x);
  auto wgemm = [&](const float* A, const float* W, const float* bias, float* C) {
    gemm_kernel<128, 128, float, float, 1><<<dim3(kD / 128, kM / 128, 1), blk256, 0, stream>>>(
        A, W, bias, C, kD, kD, kD, kD, 1, 0, 0, 0, 0, 0, 0, 1.0f, 0);
  };
  for (int i = 0; i < kL; ++i) {
    const long wOff = (long)i * DD;
    float* wSelf  = out + kLOG + (long)i * kBHTT;
    float* wCross = out + kLOG + (long)kL * kBHTT + (long)i * kBHTT;
    wgemm(x, Wq_s + wOff, bq_s + (long)i * kD, S0);
    wgemm(x, Wk_s + wOff, bk_s + (long)i * kD, S1);
    wgemm(x, Wv_s + wOff, bv_s + (long)i * kD, S2);
    transpose_v_kernel<<<dim3(16, 2, 64), blkT, 0, stream>>>(S2, vt);
    gemm_kernel<128, 128, float, float, 0><<<dim3(4, 4, 64), blk256, 0, stream>>>(
        S0, S1, nullptr, wSelf, kDK, kD, kD, kT,
        kH, kTD, (long)kDK, kTD, (long)kDK, kHTT, kTT, 0.125f, 0);
    softmax_kernel<<<dim3(kB * kH * kT / 4), blk256, 0, stream>>>(wSelf, 1);
    gemm_kernel<128, 64, float, u16, 0><<<dim3(1, 4, 64), blk256, 0, stream>>>(
        wSelf, vt, nullptr, S3, kT, kT, kT, kD,
        kH, kHTT, kTT, (long)kH * kDK * kT, (long)kDK * kT, kTD, (long)kDK, 1.0f, 0);
    wgemm(S3, Wo_s + wOff, bo_s + (long)i * kD, S0);
    add_ln_kernel<<<dim3(kM), blk256, 0, stream>>>(x, S0, ln1g + (long)i * kD, ln1b + (long)i * kD);
    wgemm(x,   Wq_c + wOff, bq_c + (long)i * kD, S0);
    wgemm(enc, Wk_c + wOff, bk_c + (long)i * kD, S1);
    wgemm(enc, Wv_c + wOff, bv_c + (long)i * kD, S2);
    transpose_v_kernel<<<dim3(16, 2, 64), blkT, 0, stream>>>(S2, vt);
    gemm_kernel<128, 128, float, float, 0><<<dim3(4, 4, 64), blk256, 0, stream>>>(
        S0, S1, nullptr, wCross, kDK, kD, kD, kT,
        kH, kTD, (long)kDK, kTD, (long)kDK, kHTT, kTT, 0.125f, 0);
    softmax_kernel<<<dim3(kB * kH * kT / 4), blk256, 0, stream>>>(wCross, 0);
    gemm_kernel<128, 64, float, u16, 0><<<dim3(1, 4, 64), blk256, 0, stream>>>(
        wCross, vt, nullptr, S3, kT, kT, kT, kD,
        kH, kHTT, kTT, (long)kH * kDK * kT, (long)kDK * kT, kTD, (long)kDK, 1.0f, 0);
    wgemm(S3, Wo_c + wOff, bo_c + (long)i * kD, S0);
    add_ln_kernel<<<dim3(kM), blk256, 0, stream>>>(x, S0, ln2g + (long)i * kD, ln2b + (long)i * kD);
    gemm_kernel<128, 128, float, float, 1><<<dim3(kF / 128, kM / 128, 1), blk256, 0, stream>>>(
        x, W1 + (long)i * kD * kF, b1 + (long)i * kF, S0, kD, kD, kF, kF,
        1, 0, 0, 0, 0, 0, 0, 1.0f, 1);
    gemm_kernel<128, 128, float, float, 1><<<dim3(kD / 128, kM / 128, 1), blk256, 0, stream>>>(
        S0, W2 + (long)i * kF * kD, b2 + (long)i * kD, S4, kF, kF, kD, kD,
        1, 0, 0, 0, 0, 0, 0, 1.0f, 0);
    add_ln_kernel<<<dim3(kM), blk256, 0, stream>>>(x, S4, ln3g + (long)i * kD, ln3b + (long)i * kD);
  }
  gemm_kernel<128, 128, float, float, 1><<<dim3(kV / 128, kM / 128, 1), blk256, 0, stream>>>(
      x, Wout, bout, out, kD, kD, kV, kV,
      1, 0, 0, 0, 0, 0, 0, 1.0f, 0);
}

// Round 13
// 1380.021 us; speedup vs baseline: 1.1246x; 1.0668x over previous
//
#include <hip/hip_runtime.h>

// TransformerDecoder on MI355X. Round 13:
// - attn_fused QBLK 128->64: grid 256->512 blocks (2/CU on ALL 256 CUs; was
//   half the chip). acc halves to [2][8], causal skip finer-grained.
// Everything else = Round-12 passing code. Fallback = Round-3 proven.

typedef unsigned short u16;
typedef __bf16 v8bf __attribute__((ext_vector_type(8)));
typedef float v4f __attribute__((ext_vector_type(4)));

namespace {
constexpr int kB = 4, kT = 512, kD = 1024, kH = 16, kDK = 64, kF = 4096, kV = 32000, kL = 4;
constexpr int kM = kB * kT;
constexpr long kTD = (long)kT * kD;
constexpr long kTT = (long)kT * kT;
constexpr long kHTT = (long)kH * kTT;
constexpr long kBHTT = (long)kB * kHTT;
constexpr long kLOG = (long)kM * kV;
constexpr long kPART = (long)kM * kD;
}

__device__ __forceinline__ u16 f2bf(float f) {
  union { float f; unsigned u; } v; v.f = f;
  unsigned r = v.u + 0x7FFFu + ((v.u >> 16) & 1u);
  return (u16)(r >> 16);
}
__device__ __forceinline__ float bf2f(u16 h) {
  union { unsigned u; float f; } v; v.u = ((unsigned)h) << 16;
  return v.f;
}

typedef __attribute__((address_space(3))) void lds_void;
typedef const __attribute__((address_space(1))) void glob_void;
__device__ __forceinline__ void gl2lds16(const void* g, void* l) {
  __builtin_amdgcn_global_load_lds((glob_void*)g, (lds_void*)l, 16, 0, 0);
}

// ---------------------------------------------------------------------------
// bf16 GEMM, BK=64, swizzled LDS. DBUF=1: double-buffered (1 barrier/step).
// DBUF=0: single buffer (2 barriers/step, less LDS -> higher residency).
// C[m][n] = scale*sum A[m][k]*B[n][k] + bias[zh*bstride+n] (zb==0 only).
// VTR: cols>=2048 of a (.,3072) C also written transposed into vt (B,H,dk,T).
// ---------------------------------------------------------------------------
template <int BM, int BN, int OUTBF, int VTR, int DBUF>
__global__ __launch_bounds__(256)
void gemm_bf(const u16* __restrict__ A0, const u16* __restrict__ B0,
             const float* __restrict__ bias, void* __restrict__ Cv,
             u16* __restrict__ vtw,
             const int K, const int lda, const int ldb, const int ldc,
             const int nH, const long sAb, const long sAh,
             const long sBb, const long sBh, const long sCb, const long sCh,
             const float scale, const int relu, const int bstride) {
  static_assert(BM % 32 == 0 && BN % 32 == 0, "tiles");
  __shared__ u16 As[DBUF + 1][BM][64];
  __shared__ u16 Bs[DBUF + 1][BN][64];
  const int tid = threadIdx.x;
  const int lane = tid & 63;
  const int w = tid >> 6;
  const int z = blockIdx.z;
  const int zb = z / nH, zh = z - zb * nH;
  const u16* A = A0 + zb * sAb + zh * sAh + (long)blockIdx.y * BM * lda;
  const u16* B = B0 + zb * sBb + zh * sBh + (long)blockIdx.x * BN * ldb;
  const long offC = zb * sCb + zh * sCh;
  const int wm = w >> 1, wn = w & 1;
  constexpr int FM = BM / 32, FN = BN / 32;
  v4f acc[FM][FN];
  const v4f zero = {0.f, 0.f, 0.f, 0.f};
#pragma unroll
  for (int i = 0; i < FM; ++i)
#pragma unroll
    for (int j = 0; j < FN; ++j) acc[i][j] = zero;
  const int l15 = lane & 15, lk = lane >> 4;
  const int lr8 = lane >> 3;                       // row within 8-row stripe
  const int swz = ((lane & 7) ^ lr8) * 8;          // pre-swizzled source col
  const int l7 = l15 & 7;

  if constexpr (DBUF) {
    // prologue: stage tile 0 into buffer 0
#pragma unroll
    for (int s = 0; s < BM / 32; ++s)
      gl2lds16(A + (long)(w * (BM / 4) + s * 8 + lr8) * lda + swz,
               &As[0][w * (BM / 4) + s * 8][0]);
#pragma unroll
    for (int s = 0; s < BN / 32; ++s)
      gl2lds16(B + (long)(w * (BN / 4) + s * 8 + lr8) * ldb + swz,
               &Bs[0][w * (BN / 4) + s * 8][0]);

    const int NT = K >> 6;
    for (int kt = 0; kt < NT; ++kt) {
      const int cur = kt & 1;
      __syncthreads();   // drains prev stage + prev reads
      if (kt + 1 < NT) {
        const int k0 = (kt + 1) << 6;
#pragma unroll
        for (int s = 0; s < BM / 32; ++s)
          gl2lds16(A + (long)(w * (BM / 4) + s * 8 + lr8) * lda + k0 + swz,
                   &As[cur ^ 1][w * (BM / 4) + s * 8][0]);
#pragma unroll
        for (int s = 0; s < BN / 32; ++s)
          gl2lds16(B + (long)(w * (BN / 4) + s * 8 + lr8) * ldb + k0 + swz,
                   &Bs[cur ^ 1][w * (BN / 4) + s * 8][0]);
      }
#pragma unroll
      for (int t = 0; t < 2; ++t) {
        const int c0 = t * 4;
        v8bf af[FM], bfr[FN];
#pragma unroll
        for (int i = 0; i < FM; ++i)
          af[i] = *(const v8bf*)&As[cur][wm * (BM / 2) + i * 16 + l15][((c0 + lk) ^ l7) * 8];
#pragma unroll
        for (int j = 0; j < FN; ++j)
          bfr[j] = *(const v8bf*)&Bs[cur][wn * (BN / 2) + j * 16 + l15][((c0 + lk) ^ l7) * 8];
#pragma unroll
        for (int i = 0; i < FM; ++i)
#pragma unroll
          for (int j = 0; j < FN; ++j)
            acc[i][j] = __builtin_amdgcn_mfma_f32_16x16x32_bf16(af[i], bfr[j], acc[i][j], 0, 0, 0);
      }
    }
  } else {
    for (int k0 = 0; k0 < K; k0 += 64) {
      __syncthreads();
#pragma unroll
      for (int s = 0; s < BM / 32; ++s)
        gl2lds16(A + (long)(w * (BM / 4) + s * 8 + lr8) * lda + k0 + swz,
                 &As[0][w * (BM / 4) + s * 8][0]);
#pragma unroll
      for (int s = 0; s < BN / 32; ++s)
        gl2lds16(B + (long)(w * (BN / 4) + s * 8 + lr8) * ldb + k0 + swz,
                 &Bs[0][w * (BN / 4) + s * 8][0]);
      __syncthreads();
#pragma unroll
      for (int t = 0; t < 2; ++t) {
        const int c0 = t * 4;
        v8bf af[FM], bfr[FN];
#pragma unroll
        for (int i = 0; i < FM; ++i)
          af[i] = *(const v8bf*)&As[0][wm * (BM / 2) + i * 16 + l15][((c0 + lk) ^ l7) * 8];
#pragma unroll
        for (int j = 0; j < FN; ++j)
          bfr[j] = *(const v8bf*)&Bs[0][wn * (BN / 2) + j * 16 + l15][((c0 + lk) ^ l7) * 8];
#pragma unroll
        for (int i = 0; i < FM; ++i)
#pragma unroll
          for (int j = 0; j < FN; ++j)
            acc[i][j] = __builtin_amdgcn_mfma_f32_16x16x32_bf16(af[i], bfr[j], acc[i][j], 0, 0, 0);
      }
    }
  }

  const long m0 = (long)blockIdx.y * BM + wm * (BM / 2);
  const int n0 = blockIdx.x * BN + wn * (BN / 2);
#pragma unroll
  for (int j = 0; j < FN; ++j) {
    const int col = n0 + j * 16 + l15;
    const float bv = (bias && zb == 0) ? bias[zh * bstride + col] : 0.0f;
#pragma unroll
    for (int i = 0; i < FM; ++i) {
      const long row = m0 + i * 16 + lk * 4;
#pragma unroll
      for (int r = 0; r < 4; ++r) {
        float v = acc[i][j][r] * scale + bv;
        if (relu) v = fmaxf(v, 0.0f);
        const long idx = offC + (row + r) * ldc + col;
        if (OUTBF) ((u16*)Cv)[idx] = f2bf(v);
        else       ((float*)Cv)[idx] = v;
        if (VTR) {
          const int colS = (int)(offC % 3072) + col;   // column within (.,3072)
          if (colS >= 2048) {
            const int hh = (colS - 2048) >> 6, dd = (colS - 2048) & 63;
            const int rowg = (int)(row + r);
            vtw[((long)((rowg >> 9) * 16 + hh)) * 32768 + dd * 512 + (rowg & 511)] = f2bf(v);
          }
        }
      }
    }
  }
}

// ---------------------------------------------------------------------------
// Fused attention, QBLK=64: per block 64 q-rows x one (b,h). K in swizzled
// LDS, Q fragments from global/L2, softmax (w f32 to d_out), PV via padded
// LDS P/V^T chunks, O bf16 into S3b. 512 threads = 8 waves (2 wm x 4 wn);
// per-wave 32 q-rows. Grid (8,64)=512 blocks, 2/CU on all 256 CUs.
// ---------------------------------------------------------------------------
template <int CAUSAL>
__global__ __launch_bounds__(512)
void attn_fused(const u16* __restrict__ Qb, const u16* __restrict__ Kb,
                const u16* __restrict__ vtp, float* __restrict__ wout,
                u16* __restrict__ oout) {
  __shared__ __align__(16) char lds[65536];
  u16 (*Ks)[64] = (u16 (*)[64])lds;                 // [512][64] = 64KB
  u16 (*Pl)[136] = (u16 (*)[136])lds;               // [64][136] 17408 B (aliases Ks)
  u16 (*Vt)[136] = (u16 (*)[136])(lds + 17408);     // [64][136] 17408 B (aliases Ks)
  __shared__ float redM[64][4];
  __shared__ float redS[64][4];
  const int tid = threadIdx.x, lane = tid & 63, w = tid >> 6;
  const int wm = w >> 2, wn = w & 3;
  const int l15 = lane & 15, lk = lane >> 4;
  const int lr8 = lane >> 3;
  const int swz = ((lane & 7) ^ lr8) * 8;
  const int l7 = l15 & 7;
  const int bx = blockIdx.x;                 // q tile 0..7 (64 rows each)
  const int z = blockIdx.y, zb = z >> 4, zh = z & 15;
  const u16* Q = Qb + (long)zb * 512 * 3072 + zh * 64 + (long)bx * 64 * 3072;
  const u16* Kp = Kb + (long)zb * 512 * 3072 + zh * 64;
  const u16* vtz = vtp + (long)((zb << 4) + zh) * 32768;
  const long obase = (long)zb * kHTT + (long)zh * kTT;
  const int qmax = bx * 64 + 63;

#pragma unroll
  for (int s = 0; s < 8; ++s) {
    const int r0 = w * 64 + s * 8;
    if (!CAUSAL || r0 <= qmax)
      gl2lds16(Kp + (long)(r0 + lr8) * 3072 + swz, &Ks[r0][0]);
  }
  __syncthreads();

  v4f acc[2][8];
  const v4f zero = {0.f, 0.f, 0.f, 0.f};
#pragma unroll
  for (int i = 0; i < 2; ++i)
#pragma unroll
    for (int j = 0; j < 8; ++j) acc[i][j] = zero;

#pragma unroll
  for (int t = 0; t < 2; ++t) {
    const int c0 = t * 4;
    v8bf aq[2], bk[8];
#pragma unroll
    for (int i = 0; i < 2; ++i)
      aq[i] = *(const v8bf*)(Q + (long)(wm * 32 + i * 16 + l15) * 3072 + (c0 + lk) * 8);
#pragma unroll
    for (int j = 0; j < 8; ++j)
      bk[j] = *(const v8bf*)&Ks[wn * 128 + j * 16 + l15][((c0 + lk) ^ l7) * 8];
#pragma unroll
    for (int i = 0; i < 2; ++i)
#pragma unroll
      for (int j = 0; j < 8; ++j)
        if (!(CAUSAL && wn * 128 + j * 16 > bx * 64 + wm * 32 + i * 16 + 15))
          acc[i][j] = __builtin_amdgcn_mfma_f32_16x16x32_bf16(aq[i], bk[j], acc[i][j], 0, 0, 0);
  }

  // row max
  float gmax[2][4];
#pragma unroll
  for (int i = 0; i < 2; ++i)
#pragma unroll
    for (int r = 0; r < 4; ++r) {
      const int q = bx * 64 + wm * 32 + i * 16 + lk * 4 + r;
      float m = -3.0e38f;
#pragma unroll
      for (int j = 0; j < 8; ++j) {
        const int col = wn * 128 + j * 16 + l15;
        if (!CAUSAL || col <= q) m = fmaxf(m, acc[i][j][r] * 0.125f);
      }
#pragma unroll
      for (int off = 1; off < 16; off <<= 1) m = fmaxf(m, __shfl_xor(m, off));
      if (l15 == 0) redM[wm * 32 + i * 16 + lk * 4 + r][wn] = m;
    }
  __syncthreads();
#pragma unroll
  for (int i = 0; i < 2; ++i)
#pragma unroll
    for (int r = 0; r < 4; ++r) {
      v4f mv = *(const v4f*)&redM[wm * 32 + i * 16 + lk * 4 + r][0];
      gmax[i][r] = fmaxf(fmaxf(mv[0], mv[1]), fmaxf(mv[2], mv[3]));
    }
  // exp + row sum
#pragma unroll
  for (int i = 0; i < 2; ++i)
#pragma unroll
    for (int r = 0; r < 4; ++r) {
      const int q = bx * 64 + wm * 32 + i * 16 + lk * 4 + r;
      float s = 0.0f;
#pragma unroll
      for (int j = 0; j < 8; ++j) {
        const int col = wn * 128 + j * 16 + l15;
        float e = (!CAUSAL || col <= q) ? __expf(acc[i][j][r] * 0.125f - gmax[i][r]) : 0.0f;
        acc[i][j][r] = e;
        s += e;
      }
#pragma unroll
      for (int off = 1; off < 16; off <<= 1) s += __shfl_xor(s, off);
      if (l15 == 0) redS[wm * 32 + i * 16 + lk * 4 + r][wn] = s;
    }
  __syncthreads();
  // normalize, write w (f32), keep normalized P in acc
#pragma unroll
  for (int i = 0; i < 2; ++i)
#pragma unroll
    for (int r = 0; r < 4; ++r) {
      v4f sv = *(const v4f*)&redS[wm * 32 + i * 16 + lk * 4 + r][0];
      const float inv = 1.0f / (sv[0] + sv[1] + sv[2] + sv[3]);
      const int q = bx * 64 + wm * 32 + i * 16 + lk * 4 + r;
      const long rowoff = obase + (long)q * 512;
#pragma unroll
      for (int j = 0; j < 8; ++j) {
        const int col = wn * 128 + j * 16 + l15;
        const float v = acc[i][j][r] * inv;
        acc[i][j][r] = v;
        wout[rowoff + col] = v;
      }
    }

  // ---- PV: O[64 q][64 d] = P @ V, chunked over k (128 per chunk) ----
  // Pl/Vt alias Ks; safe: all Ks reads completed before the barrier below.
  v4f acco[2];
#pragma unroll
  for (int i = 0; i < 2; ++i) acco[i] = zero;
  const int kcMax = CAUSAL ? (bx >> 1) : 3;
  for (int kc = 0; kc <= kcMax; ++kc) {
    __syncthreads();
    if (wn == kc) {       // this wave-group owns P cols [kc*128, kc*128+128)
#pragma unroll
      for (int i = 0; i < 2; ++i)
#pragma unroll
        for (int j = 0; j < 8; ++j) {
          const int colk = j * 16 + l15;
#pragma unroll
          for (int r = 0; r < 4; ++r)
            Pl[wm * 32 + i * 16 + lk * 4 + r][colk] = f2bf(acc[i][j][r]);
        }
    }
    // stage V^T chunk [64 d][128 k] into padded Vt
#pragma unroll
    for (int s = 0; s < 2; ++s) {
      const int c = tid * 2 + s;            // 0..1023 chunks of 8 u16
      const int d = c >> 4, off = (c & 15) * 8;
      uint4 vv = *(const uint4*)(vtz + (long)d * 512 + kc * 128 + off);
      *(uint4*)&Vt[d][off] = vv;
    }
    __syncthreads();
#pragma unroll
    for (int t = 0; t < 4; ++t) {
      v8bf bv = *(const v8bf*)&Vt[wn * 16 + l15][t * 32 + lk * 8];
#pragma unroll
      for (int i = 0; i < 2; ++i) {
        v8bf ap = *(const v8bf*)&Pl[wm * 32 + i * 16 + l15][t * 32 + lk * 8];
        acco[i] = __builtin_amdgcn_mfma_f32_16x16x32_bf16(ap, bv, acco[i], 0, 0, 0);
      }
    }
  }
  // write O bf16 into S3b (2048,1024) at column zh*64
#pragma unroll
  for (int i = 0; i < 2; ++i)
#pragma unroll
    for (int r = 0; r < 4; ++r) {
      const int row = bx * 64 + wm * 32 + i * 16 + lk * 4 + r;
      oout[(long)(zb * 512 + row) * 1024 + zh * 64 + wn * 16 + l15] = f2bf(acco[i][r]);
    }
}

// Weight transpose-convert: out(N,K) bf16 = in(K,N)^T f32; 64x64 tiles,
// float4 vectorized loads, uint2 vectorized stores. Up to 32 matrices/launch.
struct TPtrs32 { const float* in[32]; u16* out[32]; };

__global__ void transpose_wt_v4(TPtrs32 ps, int K, int N) {
  __shared__ float tile[64][65];
  const float* in = ps.in[blockIdx.z];
  u16* o = ps.out[blockIdx.z];
  const int n0 = blockIdx.x * 64, k0 = blockIdx.y * 64;
  const int tr = threadIdx.x >> 4;          // 0..15
  const int tc = (threadIdx.x & 15) * 4;    // 0,4,..,60
#pragma unroll
  for (int i = 0; i < 4; ++i) {
    float4 v = *(const float4*)(in + (long)(k0 + tr + 16 * i) * N + n0 + tc);
    tile[tr + 16 * i][tc + 0] = v.x;
    tile[tr + 16 * i][tc + 1] = v.y;
    tile[tr + 16 * i][tc + 2] = v.z;
    tile[tr + 16 * i][tc + 3] = v.w;
  }
  __syncthreads();
#pragma unroll
  for (int i = 0; i < 4; ++i) {
    const int rr = tr + 16 * i;             // n within tile
    u16 h[4];
#pragma unroll
    for (int j = 0; j < 4; ++j) h[j] = f2bf(tile[tc + j][rr]);
    *(uint2*)(o + (long)(n0 + rr) * K + k0 + tc) = *(const uint2*)h;
  }
}

__global__ void concat_bias(float* __restrict__ dst, const float* __restrict__ s0,
                            const float* __restrict__ s1, const float* __restrict__ s2,
                            const int nsrc) {
  const int idx = blockIdx.x * 256 + threadIdx.x;
  const int per = nsrc << 10;
  const int l = idx / per, rem = idx - l * per, s = rem >> 10, j = rem & 1023;
  const float* src = (s == 0) ? s0 : (s == 1 ? s1 : s2);
  dst[idx] = src[l * 1024 + j];
}

__global__ void cvt_bf16_v3(const float* __restrict__ in, u16* __restrict__ o1,
                            u16* __restrict__ o2) {
  const long i = ((long)blockIdx.x * 256 + threadIdx.x) * 4;
  float4 v = *(const float4*)(in + i);
  u16 h[4] = {f2bf(v.x), f2bf(v.y), f2bf(v.z), f2bf(v.w)};
  *(uint2*)(o1 + i) = *(const uint2*)h;
  *(uint2*)(o2 + i) = *(const uint2*)h;
}

__global__ void embed_v2(const int* __restrict__ tgt, const float* __restrict__ emb,
                         float* __restrict__ x, u16* __restrict__ xb) {
  const int row = blockIdx.x;
  const int t = row & (kT - 1);
  const int tok = tgt[row];
  const int c = threadIdx.x * 4;
  float4 e = *(const float4*)(emb + (long)tok * kD + c);
  const float nl = -9.210340371976184f / (float)kD;
  const float a0 = (float)t * expf((float)c * nl);
  const float a1 = (float)t * expf((float)(c + 2) * nl);
  float4 o;
  o.x = e.x * 32.0f + sinf(a0);
  o.y = e.y * 32.0f + cosf(a0);
  o.z = e.z * 32.0f + sinf(a1);
  o.w = e.w * 32.0f + cosf(a1);
  *(float4*)(x + (long)row * kD + c) = o;
  u16 h[4] = {f2bf(o.x), f2bf(o.y), f2bf(o.z), f2bf(o.w)};
  *(uint2*)(xb + (long)row * kD + c) = *(const uint2*)h;
}

// x = LN(x + sum_{p<nres} resb[p]) with bf16 partials; writes x f32 and xb bf16
__global__ void add_ln_v4(float* __restrict__ x, u16* __restrict__ xb,
                          const u16* __restrict__ resb, const int nres,
                          const float* __restrict__ g, const float* __restrict__ b) {
  const int row = blockIdx.x;
  const int c = threadIdx.x * 4;
  float4 xv = *(const float4*)(x + (long)row * kD + c);
  float v0 = xv.x, v1 = xv.y, v2 = xv.z, v3 = xv.w;
  for (int p = 0; p < nres; ++p) {
    uint2 rv = *(const uint2*)(resb + p * kPART + (long)row * kD + c);
    v0 += bf2f((u16)(rv.x & 0xffffu));
    v1 += bf2f((u16)(rv.x >> 16));
    v2 += bf2f((u16)(rv.y & 0xffffu));
    v3 += bf2f((u16)(rv.y >> 16));
  }
  float s = v0 + v1 + v2 + v3;
  float ss = v0 * v0 + v1 * v1 + v2 * v2 + v3 * v3;
#pragma unroll
  for (int o = 32; o > 0; o >>= 1) { s += __shfl_xor(s, o); ss += __shfl_xor(ss, o); }
  __shared__ float red[4][2];
  const int wv = threadIdx.x >> 6;
  if ((threadIdx.x & 63) == 0) { red[wv][0] = s; red[wv][1] = ss; }
  __syncthreads();
  s  = red[0][0] + red[1][0] + red[2][0] + red[3][0];
  ss = red[0][1] + red[1][1] + red[2][1] + red[3][1];
  const float mean = s * (1.0f / kD);
  const float var = ss * (1.0f / kD) - mean * mean;
  const float rs = rsqrtf(var + 1e-5f);
  float4 gv = *(const float4*)(g + c);
  float4 bv = *(const float4*)(b + c);
  float4 o;
  o.x = gv.x * (v0 - mean) * rs + bv.x;
  o.y = gv.y * (v1 - mean) * rs + bv.y;
  o.z = gv.z * (v2 - mean) * rs + bv.z;
  o.w = gv.w * (v3 - mean) * rs + bv.w;
  *(float4*)(x + (long)row * kD + c) = o;
  u16 h[4] = {f2bf(o.x), f2bf(o.y), f2bf(o.z), f2bf(o.w)};
  *(uint2*)(xb + (long)row * kD + c) = *(const uint2*)h;
}

// ===========================================================================
// FALLBACK PATH (Round-3 proven)
// ===========================================================================
template <int BM, int BN, typename TA, typename TB, int BKN>
__global__ __launch_bounds__(256)
void gemm_kernel(const void* __restrict__ Av, const void* __restrict__ Bv,
                 const float* __restrict__ bias, float* __restrict__ Cv,
                 const int K, const int lda, const int ldb, const int ldc,
                 const int nH, const long sAb, const long sAh,
                 const long sBb, const long sBh, const long sCb, const long sCh,
                 const float scale, const int relu) {
  constexpr int LP = 40;
  __shared__ u16 As[BM][LP];
  __shared__ u16 Bs[BN][LP];
  const int tid = threadIdx.x;
  const int z = blockIdx.z;
  const int zb = z / nH, zh = z - zb * nH;
  const TA* A = (const TA*)Av + zb * sAb + zh * sAh + (long)blockIdx.y * BM * lda;
  const TB* Bp;
  if constexpr (BKN)
    Bp = (const TB*)Bv + zb * sBb + zh * sBh + (long)blockIdx.x * BN;
  else
    Bp = (const TB*)Bv + zb * sBb + zh * sBh + (long)blockIdx.x * BN * ldb;
  const long offC = zb * sCb + zh * sCh;
  const int lane = tid & 63;
  const int wm = (tid >> 7) & 1, wn = (tid >> 6) & 1;
  constexpr int FM = BM / 32, FN = BN / 32;
  v4f acc[FM][FN];
  const v4f zero = {0.f, 0.f, 0.f, 0.f};
#pragma unroll
  for (int i = 0; i < FM; ++i)
#pragma unroll
    for (int j = 0; j < FN; ++j) acc[i][j] = zero;
  const int l15 = lane & 15, lk = lane >> 4;

  for (int k0 = 0; k0 < K; k0 += 32) {
    __syncthreads();
    if constexpr (sizeof(TA) == 4) {
      const int r = tid >> 3, c = (tid & 7) * 4;
#pragma unroll
      for (int rr = 0; rr < BM; rr += 32) {
        float4 vv = *(const float4*)((const float*)A + (long)(rr + r) * lda + k0 + c);
        unsigned lo = (unsigned)f2bf(vv.x) | ((unsigned)f2bf(vv.y) << 16);
        unsigned hi = (unsigned)f2bf(vv.z) | ((unsigned)f2bf(vv.w) << 16);
        *(uint2*)&As[rr + r][c] = make_uint2(lo, hi);
      }
    } else {
      const int r = tid >> 2, c = (tid & 3) * 8;
#pragma unroll
      for (int rr = 0; rr < BM; rr += 64) {
        uint4 vv = *(const uint4*)((const u16*)A + (long)(rr + r) * lda + k0 + c);
        *(uint4*)&As[rr + r][c] = vv;
      }
    }
    if constexpr (BKN) {
      const int r = tid >> 3, c = (tid & 7) * 4;
#pragma unroll
      for (int nn = 0; nn < BN; nn += 32) {
        float4 vv = *(const float4*)((const float*)Bp + (long)(k0 + r) * ldb + nn + c);
        Bs[nn + c + 0][r] = f2bf(vv.x);
        Bs[nn + c + 1][r] = f2bf(vv.y);
        Bs[nn + c + 2][r] = f2bf(vv.z);
        Bs[nn + c + 3][r] = f2bf(vv.w);
      }
    } else if constexpr (sizeof(TB) == 4) {
      const int r = tid >> 3, c = (tid & 7) * 4;
#pragma unroll
      for (int rr = 0; rr < BN; rr += 32) {
        float4 vv = *(const float4*)((const float*)Bp + (long)(rr + r) * ldb + k0 + c);
        unsigned lo = (unsigned)f2bf(vv.x) | ((unsigned)f2bf(vv.y) << 16);
        unsigned hi = (unsigned)f2bf(vv.z) | ((unsigned)f2bf(vv.w) << 16);
        *(uint2*)&Bs[rr + r][c] = make_uint2(lo, hi);
      }
    } else {
      const int r = tid >> 2, c = (tid & 3) * 8;
#pragma unroll
      for (int rr = 0; rr < BN; rr += 64) {
        uint4 vv = *(const uint4*)((const u16*)Bp + (long)(rr + r) * ldb + k0 + c);
        *(uint4*)&Bs[rr + r][c] = vv;
      }
    }
    __syncthreads();
    v8bf af[FM], bfr[FN];
#pragma unroll
    for (int i = 0; i < FM; ++i)
      af[i] = *(const v8bf*)&As[wm * (BM / 2) + i * 16 + l15][lk * 8];
#pragma unroll
    for (int j = 0; j < FN; ++j)
      bfr[j] = *(const v8bf*)&Bs[wn * (BN / 2) + j * 16 + l15][lk * 8];
#pragma unroll
    for (int i = 0; i < FM; ++i)
#pragma unroll
      for (int j = 0; j < FN; ++j)
        acc[i][j] = __builtin_amdgcn_mfma_f32_16x16x32_bf16(af[i], bfr[j], acc[i][j], 0, 0, 0);
  }

  const long m0 = (long)blockIdx.y * BM + wm * (BM / 2);
  const int n0 = blockIdx.x * BN + wn * (BN / 2);
#pragma unroll
  for (int j = 0; j < FN; ++j) {
    const int col = n0 + j * 16 + l15;
    const float bv = bias ? bias[col] : 0.0f;
#pragma unroll
    for (int i = 0; i < FM; ++i) {
      const long row = m0 + i * 16 + lk * 4;
#pragma unroll
      for (int r = 0; r < 4; ++r) {
        float v = acc[i][j][r] * scale + bv;
        if (relu) v = fmaxf(v, 0.0f);
        Cv[offC + (row + r) * ldc + col] = v;
      }
    }
  }
}

__global__ void embed_kernel(const int* __restrict__ tgt, const float* __restrict__ emb,
                             float* __restrict__ x) {
  const int row = blockIdx.x;
  const int t = row & (kT - 1);
  const int tok = tgt[row];
  const int c = threadIdx.x * 4;
  float4 e = *(const float4*)(emb + (long)tok * kD + c);
  const float nl = -9.210340371976184f / (float)kD;
  const float a0 = (float)t * expf((float)c * nl);
  const float a1 = (float)t * expf((float)(c + 2) * nl);
  float4 o;
  o.x = e.x * 32.0f + sinf(a0);
  o.y = e.y * 32.0f + cosf(a0);
  o.z = e.z * 32.0f + sinf(a1);
  o.w = e.w * 32.0f + cosf(a1);
  *(float4*)(x + (long)row * kD + c) = o;
}

__global__ void transpose_v_kernel(const float* __restrict__ v, u16* __restrict__ vt) {
  __shared__ float tile[32][33];
  const int z = blockIdx.z;
  const int b = z >> 4, h = z & 15;
  const int t0 = blockIdx.x * 32, d0 = blockIdx.y * 32;
  const int tx = threadIdx.x, ty = threadIdx.y;
  const float* in = v + (long)b * kTD + (long)h * kDK;
#pragma unroll
  for (int i = 0; i < 4; ++i)
    tile[ty + 8 * i][tx] = in[(long)(t0 + ty + 8 * i) * kD + d0 + tx];
  __syncthreads();
  u16* o = vt + (long)z * kDK * kT;
#pragma unroll
  for (int i = 0; i < 4; ++i)
    o[(long)(d0 + ty + 8 * i) * kT + t0 + tx] = f2bf(tile[tx][ty + 8 * i]);
}

__global__ void softmax_kernel(float* __restrict__ w, const int causal) {
  const int rowg = blockIdx.x * 4 + (threadIdx.x >> 6);
  const int lane = threadIdx.x & 63;
  const int q = rowg & (kT - 1);
  float* p = w + (long)rowg * kT + lane * 8;
  float4 v0 = *(const float4*)p;
  float4 v1 = *(const float4*)(p + 4);
  float f[8] = {v0.x, v0.y, v0.z, v0.w, v1.x, v1.y, v1.z, v1.w};
  const int base = lane * 8;
  float mx = -3.0e38f;
#pragma unroll
  for (int j = 0; j < 8; ++j)
    if (!causal || base + j <= q) mx = fmaxf(mx, f[j]);
#pragma unroll
  for (int o = 32; o > 0; o >>= 1) mx = fmaxf(mx, __shfl_xor(mx, o));
  float s = 0.0f;
#pragma unroll
  for (int j = 0; j < 8; ++j) {
    float e = (!causal || base + j <= q) ? __expf(f[j] - mx) : 0.0f;
    f[j] = e; s += e;
  }
#pragma unroll
  for (int o = 32; o > 0; o >>= 1) s += __shfl_xor(s, o);
  const float inv = 1.0f / s;
  float4 o0 = {f[0] * inv, f[1] * inv, f[2] * inv, f[3] * inv};
  float4 o1 = {f[4] * inv, f[5] * inv, f[6] * inv, f[7] * inv};
  *(float4*)p = o0;
  *(float4*)(p + 4) = o1;
}

__global__ void add_ln_kernel(float* __restrict__ x, const float* __restrict__ res,
                              const float* __restrict__ g, const float* __restrict__ b) {
  const int row = blockIdx.x;
  const int c = threadIdx.x * 4;
  float4 xv = *(const float4*)(x + (long)row * kD + c);
  float4 rv = *(const float4*)(res + (long)row * kD + c);
  const float v0 = xv.x + rv.x, v1 = xv.y + rv.y, v2 = xv.z + rv.z, v3 = xv.w + rv.w;
  float s = v0 + v1 + v2 + v3;
  float ss = v0 * v0 + v1 * v1 + v2 * v2 + v3 * v3;
#pragma unroll
  for (int o = 32; o > 0; o >>= 1) { s += __shfl_xor(s, o); ss += __shfl_xor(ss, o); }
  __shared__ float red[4][2];
  const int wv = threadIdx.x >> 6;
  if ((threadIdx.x & 63) == 0) { red[wv][0] = s; red[wv][1] = ss; }
  __syncthreads();
  s  = red[0][0] + red[1][0] + red[2][0] + red[3][0];
  ss = red[0][1] + red[1][1] + red[2][1] + red[3][1];
  const float mean = s * (1.0f / kD);
  const float var = ss * (1.0f / kD) - mean * mean;
  const float rs = rsqrtf(var + 1e-5f);
  float4 gv = *(const float4*)(g + c);
  float4 bv = *(const float4*)(b + c);
  float4 o;
  o.x = gv.x * (v0 - mean) * rs + bv.x;
  o.y = gv.y * (v1 - mean) * rs + bv.y;
  o.z = gv.z * (v2 - mean) * rs + bv.z;
  o.w = gv.w * (v3 - mean) * rs + bv.w;
  *(float4*)(x + (long)row * kD + c) = o;
}

// ===========================================================================
extern "C" void kernel_launch(void* const* d_in, const int* in_sizes, int n_in,
                              void* d_out, int out_size, void* d_ws, size_t ws_size,
                              hipStream_t stream) {
  const int*   tgt  = (const int*)d_in[0];
  const float* enc  = (const float*)d_in[1];
  const float* emb  = (const float*)d_in[3];
  const float* Wout = (const float*)d_in[4];
  const float* bout = (const float*)d_in[5];
  const float* Wq_s = (const float*)d_in[6];
  const float* bq_s = (const float*)d_in[7];
  const float* Wk_s = (const float*)d_in[8];
  const float* bk_s = (const float*)d_in[9];
  const float* Wv_s = (const float*)d_in[10];
  const float* bv_s = (const float*)d_in[11];
  const float* Wo_s = (const float*)d_in[12];
  const float* bo_s = (const float*)d_in[13];
  const float* Wq_c = (const float*)d_in[14];
  const float* bq_c = (const float*)d_in[15];
  const float* Wk_c = (const float*)d_in[16];
  const float* bk_c = (const float*)d_in[17];
  const float* Wv_c = (const float*)d_in[18];
  const float* bv_c = (const float*)d_in[19];
  const float* Wo_c = (const float*)d_in[20];
  const float* bo_c = (const float*)d_in[21];
  const float* W1   = (const float*)d_in[22];
  const float* b1   = (const float*)d_in[23];
  const float* W2   = (const float*)d_in[24];
  const float* b2   = (const float*)d_in[25];
  const float* ln1g = (const float*)d_in[26];
  const float* ln1b = (const float*)d_in[27];
  const float* ln2g = (const float*)d_in[28];
  const float* ln2b = (const float*)d_in[29];
  const float* ln3g = (const float*)d_in[30];
  const float* ln3b = (const float*)d_in[31];

  float* out = (float*)d_out;
  const long DD = (long)kD * kD;
  const dim3 blk256(256), blkT(32, 8);

  if (ws_size >= (320ll << 20)) {
    // =================== FAST PATH ===================
    char* ws = (char*)d_ws;
    float* x     = (float*)ws;                    // 8 MiB
    u16* xb      = (u16*)(ws + (8l << 20));       // 4 MiB (contiguous with encb)
    u16* encb    = (u16*)(ws + (12l << 20));      // 4 MiB (A source, merged cross)
    u16* encb2   = (u16*)(ws + (16l << 20));      // 4 MiB (second copy for V slice)
    u16* Sqkv    = (u16*)(ws + (20l << 20));      // 12 MiB (2048x3072)
    u16* vt      = (u16*)(ws + (32l << 20));      // 4 MiB (B,H,dk,T)
    u16* S3b     = (u16*)(ws + (36l << 20));      // 4 MiB
    u16* Hb      = (u16*)(ws + (40l << 20));      // 16 MiB (2048x4096)
    u16* SpartB  = (u16*)(ws + (56l << 20));      // 16 MiB (4 bf16 partials)
    u16* wbase   = (u16*)(ws + (88l << 20));      // 128 MiB
    u16* woutT   = (u16*)(ws + (216l << 20));     // 62.5 MiB
    float* bqkvS = (float*)(ws + (280l << 20));   // 48 KiB
    float* bqkvC = (float*)(ws + (280l << 20) + (64l << 10));  // 48 KiB
    const long WLAY = 16l * 1024 * 1024;          // u16 elems per layer block

    // ---- one-time prep (batched transposes: 4 dispatches total) ----
    {
      TPtrs32 pa{};
      for (int i = 0; i < kL; ++i) {
        u16* wqkvS = wbase + i * WLAY;
        u16* woS   = wqkvS + 3072 * 1024;
        u16* wqkvC = woS + 1024 * 1024;
        u16* woC   = wqkvC + 3072 * 1024;
        pa.in[i * 8 + 0] = Wq_s + i * DD; pa.out[i * 8 + 0] = wqkvS;
        pa.in[i * 8 + 1] = Wk_s + i * DD; pa.out[i * 8 + 1] = wqkvS + 1024 * 1024;
        pa.in[i * 8 + 2] = Wv_s + i * DD; pa.out[i * 8 + 2] = wqkvS + 2048 * 1024;
        pa.in[i * 8 + 3] = Wo_s + i * DD; pa.out[i * 8 + 3] = woS;
        pa.in[i * 8 + 4] = Wq_c + i * DD; pa.out[i * 8 + 4] = wqkvC;
        pa.in[i * 8 + 5] = Wk_c + i * DD; pa.out[i * 8 + 5] = wqkvC + 1024 * 1024;
        pa.in[i * 8 + 6] = Wv_c + i * DD; pa.out[i * 8 + 6] = wqkvC + 2048 * 1024;
        pa.in[i * 8 + 7] = Wo_c + i * DD; pa.out[i * 8 + 7] = woC;
      }
      transpose_wt_v4<<<dim3(16, 16, 32), blk256, 0, stream>>>(pa, 1024, 1024);
      TPtrs32 p1{};
      for (int i = 0; i < kL; ++i) {
        p1.in[i] = W1 + (long)i * kD * kF;
        p1.out[i] = wbase + i * WLAY + 8l * 1024 * 1024;  // w1t
      }
      transpose_wt_v4<<<dim3(64, 16, 4), blk256, 0, stream>>>(p1, 1024, 4096);
      TPtrs32 p2{};
      for (int i = 0; i < kL; ++i) {
        p2.in[i] = W2 + (long)i * kF * kD;
        p2.out[i] = wbase + i * WLAY + 12l * 1024 * 1024; // w2t
      }
      transpose_wt_v4<<<dim3(16, 64, 4), blk256, 0, stream>>>(p2, 4096, 1024);
      TPtrs32 po{}; po.in[0] = Wout; po.out[0] = woutT;
      transpose_wt_v4<<<dim3(500, 16, 1), blk256, 0, stream>>>(po, 1024, 32000);
    }
    concat_bias<<<dim3(48), blk256, 0, stream>>>(bqkvS, bq_s, bk_s, bv_s, 3);
    concat_bias<<<dim3(48), blk256, 0, stream>>>(bqkvC, bq_c, bk_c, bv_c, 3);
    cvt_bf16_v3<<<dim3(2048), blk256, 0, stream>>>(enc, encb, encb2);
    embed_v2<<<dim3(kM), blk256, 0, stream>>>(tgt, emb, x, xb);

    for (int i = 0; i < kL; ++i) {
      u16* wqkvS = wbase + i * WLAY;
      u16* woS   = wqkvS + 3072 * 1024;
      u16* wqkvC = woS + 1024 * 1024;
      u16* woC   = wqkvC + 3072 * 1024;
      u16* w1t   = woC + 1024 * 1024;
      u16* w2t   = w1t + (long)4096 * 1024;
      float* wSelf  = out + kLOG + (long)i * kBHTT;
      float* wCross = out + kLOG + (long)kL * kBHTT + (long)i * kBHTT;

      // -------- self attention --------
      gemm_bf<128, 128, 1, 1, 1><<<dim3(24, 16, 1), blk256, 0, stream>>>(
          xb, wqkvS, bqkvS + i * 3072, Sqkv, vt, 1024, 1024, 1024, 3072,
          1, 0, 0, 0, 0, 0, 0, 1.0f, 0, 0);
      attn_fused<1><<<dim3(8, 64), dim3(512), 0, stream>>>(Sqkv, Sqkv + 1024, vt, wSelf, S3b);
      // O-proj: split-K x4 (K=256 each), single-buffer, bf16 partials
      gemm_bf<128, 128, 1, 0, 0><<<dim3(8, 16, 4), blk256, 0, stream>>>(
          S3b, woS, bo_s + (long)i * kD, SpartB, nullptr, 256, 1024, 1024, 1024,
          1, 256, 0, 256, 0, kPART, 0, 1.0f, 0, 0);
      add_ln_v4<<<dim3(kM), blk256, 0, stream>>>(x, xb, SpartB, 4,
          ln1g + (long)i * kD, ln1b + (long)i * kD);

      // -------- cross attention (merged Q/K/V via z: xb|encb|encb2) --------
      gemm_bf<128, 128, 1, 1, 1><<<dim3(8, 16, 3), blk256, 0, stream>>>(
          xb, wqkvC, bqkvC + i * 3072, Sqkv, vt, 1024, 1024, 1024, 3072,
          3, 0, (long)2048 * 1024, 0, (long)1024 * 1024, 0, 1024, 1.0f, 0, 1024);
      attn_fused<0><<<dim3(8, 64), dim3(512), 0, stream>>>(Sqkv, Sqkv + 1024, vt, wCross, S3b);
      gemm_bf<128, 128, 1, 0, 0><<<dim3(8, 16, 4), blk256, 0, stream>>>(
          S3b, woC, bo_c + (long)i * kD, SpartB, nullptr, 256, 1024, 1024, 1024,
          1, 256, 0, 256, 0, kPART, 0, 1.0f, 0, 0);
      add_ln_v4<<<dim3(kM), blk256, 0, stream>>>(x, xb, SpartB, 4,
          ln2g + (long)i * kD, ln2b + (long)i * kD);

      // -------- FFN --------
      gemm_bf<128, 128, 1, 0, 1><<<dim3(32, 16, 1), blk256, 0, stream>>>(
          xb, w1t, b1 + (long)i * kF, Hb, nullptr, 1024, 1024, 1024, 4096,
          1, 0, 0, 0, 0, 0, 0, 1.0f, 1, 0);
      // FFN2: split-K x4 (K=1024 each), single-buffer, bf16 partials
      gemm_bf<128, 128, 1, 0, 0><<<dim3(8, 16, 4), blk256, 0, stream>>>(
          Hb, w2t, b2 + (long)i * kD, SpartB, nullptr, 1024, 4096, 4096, 1024,
          1, 1024, 0, 1024, 0, kPART, 0, 1.0f, 0, 0);
      add_ln_v4<<<dim3(kM), blk256, 0, stream>>>(x, xb, SpartB, 4,
          ln3g + (long)i * kD, ln3b + (long)i * kD);
    }

    // logits: BN=128 double-buffered (R10-measured best)
    gemm_bf<128, 128, 0, 0, 1><<<dim3(250, 16, 1), blk256, 0, stream>>>(
        xb, woutT, bout, out, nullptr, 1024, 1024, 1024, 32000,
        1, 0, 0, 0, 0, 0, 0, 1.0f, 0, 0);
    return;
  }

  // =================== FALLBACK (Round-3 verified) ===================
  float* x = (float*)d_ws;
  char* sc = (char*)d_out;
  float* S0 = (float*)sc;
  float* S1 = (float*)(sc + (8l  << 20));
  float* S2 = (float*)(sc + (16l << 20));
  float* S3 = (float*)(sc + (24l << 20));
  float* S4 = (float*)(sc + (32l << 20));
  u16*   vt = (u16*)  (sc + (40l << 20));

  embed_kernel<<<dim3(kM), blk256, 0, stream>>>(tgt, emb, x);
  auto wgemm = [&](const float* A, const float* W, const float* bias, float* C) {
    gemm_kernel<128, 128, float, float, 1><<<dim3(kD / 128, kM / 128, 1), blk256, 0, stream>>>(
        A, W, bias, C, kD, kD, kD, kD, 1, 0, 0, 0, 0, 0, 0, 1.0f, 0);
  };
  for (int i = 0; i < kL; ++i) {
    const long wOff = (long)i * DD;
    float* wSelf  = out + kLOG + (long)i * kBHTT;
    float* wCross = out + kLOG + (long)kL * kBHTT + (long)i * kBHTT;
    wgemm(x, Wq_s + wOff, bq_s + (long)i * kD, S0);
    wgemm(x, Wk_s + wOff, bk_s + (long)i * kD, S1);
    wgemm(x, Wv_s + wOff, bv_s + (long)i * kD, S2);
    transpose_v_kernel<<<dim3(16, 2, 64), blkT, 0, stream>>>(S2, vt);
    gemm_kernel<128, 128, float, float, 0><<<dim3(4, 4, 64), blk256, 0, stream>>>(
        S0, S1, nullptr, wSelf, kDK, kD, kD, kT,
        kH, kTD, (long)kDK, kTD, (long)kDK, kHTT, kTT, 0.125f, 0);
    softmax_kernel<<<dim3(kB * kH * kT / 4), blk256, 0, stream>>>(wSelf, 1);
    gemm_kernel<128, 64, float, u16, 0><<<dim3(1, 4, 64), blk256, 0, stream>>>(
        wSelf, vt, nullptr, S3, kT, kT, kT, kD,
        kH, kHTT, kTT, (long)kH * kDK * kT, (long)kDK * kT, kTD, (long)kDK, 1.0f, 0);
    wgemm(S3, Wo_s + wOff, bo_s + (long)i * kD, S0);
    add_ln_kernel<<<dim3(kM), blk256, 0, stream>>>(x, S0, ln1g + (long)i * kD, ln1b + (long)i * kD);
    wgemm(x,   Wq_c + wOff, bq_c + (long)i * kD, S0);
    wgemm(enc, Wk_c + wOff, bk_c + (long)i * kD, S1);
    wgemm(enc, Wv_c + wOff, bv_c + (long)i * kD, S2);
    transpose_v_kernel<<<dim3(16, 2, 64), blkT, 0, stream>>>(S2, vt);
    gemm_kernel<128, 128, float, float, 0><<<dim3(4, 4, 64), blk256, 0, stream>>>(
        S0, S1, nullptr, wCross, kDK, kD, kD, kT,
        kH, kTD, (long)kDK, kTD, (long)kDK, kHTT, kTT, 0.125f, 0);
    softmax_kernel<<<dim3(kB * kH * kT / 4), blk256, 0, stream>>>(wCross, 0);
    gemm_kernel<128, 64, float, u16, 0><<<dim3(1, 4, 64), blk256, 0, stream>>>(
        wCross, vt, nullptr, S3, kT, kT, kT, kD,
        kH, kHTT, kTT, (long)kH * kDK * kT, (long)kDK * kT, kTD, (long)kDK, 1.0f, 0);
    wgemm(S3, Wo_c + wOff, bo_c + (long)i * kD, S0);
    add_ln_kernel<<<dim3(kM), blk256, 0, stream>>>(x, S0, ln2g + (long)i * kD, ln2b + (long)i * kD);
    gemm_kernel<128, 128, float, float, 1><<<dim3(kF / 128, kM / 128, 1), blk256, 0, stream>>>(
        x, W1 + (long)i * kD * kF, b1 + (long)i * kF, S0, kD, kD, kF, kF,
        1, 0, 0, 0, 0, 0, 0, 1.0f, 1);
    gemm_kernel<128, 128, float, float, 1><<<dim3(kD / 128, kM / 128, 1), blk256, 0, stream>>>(
        S0, W2 + (long)i * kF * kD, b2 + (long)i * kD, S4, kF, kF, kD, kD,
        1, 0, 0, 0, 0, 0, 0, 1.0f, 0);
    add_ln_kernel<<<dim3(kM), blk256, 0, stream>>>(x, S4, ln3g + (long)i * kD, ln3b + (long)i * kD);
  }
  gemm_kernel<128, 128, float, float, 1><<<dim3(kV / 128, kM / 128, 1), blk256, 0, stream>>>(
      x, Wout, bout, out, kD, kD, kV, kV,
      1, 0, 0, 0, 0, 0, 0, 1.0f, 0);
}

// Round 14
// 1377.653 us; speedup vs baseline: 1.1265x; 1.0017x over previous
//
#include <hip/hip_runtime.h>

// TransformerDecoder on MI355X. Round 14:
// - gemm_bf gains SWAP flag: M becomes the fastest grid dim for weight GEMMs,
//   so co-dispatched blocks share the WEIGHT panel (HBM once) and re-read the
//   small L2-resident activation panel instead. Applied to QKV/O/FFN/logits.
//   (Round-13 analysis: logits alone re-fetched woutT 16x = ~1 GB HBM.)
// Everything else = Round-13 passing code. Fallback = Round-3 proven.

typedef unsigned short u16;
typedef __bf16 v8bf __attribute__((ext_vector_type(8)));
typedef float v4f __attribute__((ext_vector_type(4)));

namespace {
constexpr int kB = 4, kT = 512, kD = 1024, kH = 16, kDK = 64, kF = 4096, kV = 32000, kL = 4;
constexpr int kM = kB * kT;
constexpr long kTD = (long)kT * kD;
constexpr long kTT = (long)kT * kT;
constexpr long kHTT = (long)kH * kTT;
constexpr long kBHTT = (long)kB * kHTT;
constexpr long kLOG = (long)kM * kV;
constexpr long kPART = (long)kM * kD;
}

__device__ __forceinline__ u16 f2bf(float f) {
  union { float f; unsigned u; } v; v.f = f;
  unsigned r = v.u + 0x7FFFu + ((v.u >> 16) & 1u);
  return (u16)(r >> 16);
}
__device__ __forceinline__ float bf2f(u16 h) {
  union { unsigned u; float f; } v; v.u = ((unsigned)h) << 16;
  return v.f;
}

typedef __attribute__((address_space(3))) void lds_void;
typedef const __attribute__((address_space(1))) void glob_void;
__device__ __forceinline__ void gl2lds16(const void* g, void* l) {
  __builtin_amdgcn_global_load_lds((glob_void*)g, (lds_void*)l, 16, 0, 0);
}

// ---------------------------------------------------------------------------
// bf16 GEMM, BK=64, swizzled LDS. DBUF=1: double-buffered (1 barrier/step).
// DBUF=0: single buffer. SWAP=1: blockIdx.x indexes M (weight-panel reuse
// across co-dispatched blocks), blockIdx.y indexes N.
// C[m][n] = scale*sum A[m][k]*B[n][k] + bias[zh*bstride+n] (zb==0 only).
// VTR: cols>=2048 of a (.,3072) C also written transposed into vt (B,H,dk,T).
// ---------------------------------------------------------------------------
template <int BM, int BN, int OUTBF, int VTR, int DBUF, int SWAP>
__global__ __launch_bounds__(256)
void gemm_bf(const u16* __restrict__ A0, const u16* __restrict__ B0,
             const float* __restrict__ bias, void* __restrict__ Cv,
             u16* __restrict__ vtw,
             const int K, const int lda, const int ldb, const int ldc,
             const int nH, const long sAb, const long sAh,
             const long sBb, const long sBh, const long sCb, const long sCh,
             const float scale, const int relu, const int bstride) {
  static_assert(BM % 32 == 0 && BN % 32 == 0, "tiles");
  __shared__ u16 As[DBUF + 1][BM][64];
  __shared__ u16 Bs[DBUF + 1][BN][64];
  const int tid = threadIdx.x;
  const int lane = tid & 63;
  const int w = tid >> 6;
  const int byM = SWAP ? blockIdx.x : blockIdx.y;   // M tile index
  const int bxN = SWAP ? blockIdx.y : blockIdx.x;   // N tile index
  const int z = blockIdx.z;
  const int zb = z / nH, zh = z - zb * nH;
  const u16* A = A0 + zb * sAb + zh * sAh + (long)byM * BM * lda;
  const u16* B = B0 + zb * sBb + zh * sBh + (long)bxN * BN * ldb;
  const long offC = zb * sCb + zh * sCh;
  const int wm = w >> 1, wn = w & 1;
  constexpr int FM = BM / 32, FN = BN / 32;
  v4f acc[FM][FN];
  const v4f zero = {0.f, 0.f, 0.f, 0.f};
#pragma unroll
  for (int i = 0; i < FM; ++i)
#pragma unroll
    for (int j = 0; j < FN; ++j) acc[i][j] = zero;
  const int l15 = lane & 15, lk = lane >> 4;
  const int lr8 = lane >> 3;                       // row within 8-row stripe
  const int swz = ((lane & 7) ^ lr8) * 8;          // pre-swizzled source col
  const int l7 = l15 & 7;

  if constexpr (DBUF) {
    // prologue: stage tile 0 into buffer 0
#pragma unroll
    for (int s = 0; s < BM / 32; ++s)
      gl2lds16(A + (long)(w * (BM / 4) + s * 8 + lr8) * lda + swz,
               &As[0][w * (BM / 4) + s * 8][0]);
#pragma unroll
    for (int s = 0; s < BN / 32; ++s)
      gl2lds16(B + (long)(w * (BN / 4) + s * 8 + lr8) * ldb + swz,
               &Bs[0][w * (BN / 4) + s * 8][0]);

    const int NT = K >> 6;
    for (int kt = 0; kt < NT; ++kt) {
      const int cur = kt & 1;
      __syncthreads();   // drains prev stage + prev reads
      if (kt + 1 < NT) {
        const int k0 = (kt + 1) << 6;
#pragma unroll
        for (int s = 0; s < BM / 32; ++s)
          gl2lds16(A + (long)(w * (BM / 4) + s * 8 + lr8) * lda + k0 + swz,
                   &As[cur ^ 1][w * (BM / 4) + s * 8][0]);
#pragma unroll
        for (int s = 0; s < BN / 32; ++s)
          gl2lds16(B + (long)(w * (BN / 4) + s * 8 + lr8) * ldb + k0 + swz,
                   &Bs[cur ^ 1][w * (BN / 4) + s * 8][0]);
      }
#pragma unroll
      for (int t = 0; t < 2; ++t) {
        const int c0 = t * 4;
        v8bf af[FM], bfr[FN];
#pragma unroll
        for (int i = 0; i < FM; ++i)
          af[i] = *(const v8bf*)&As[cur][wm * (BM / 2) + i * 16 + l15][((c0 + lk) ^ l7) * 8];
#pragma unroll
        for (int j = 0; j < FN; ++j)
          bfr[j] = *(const v8bf*)&Bs[cur][wn * (BN / 2) + j * 16 + l15][((c0 + lk) ^ l7) * 8];
#pragma unroll
        for (int i = 0; i < FM; ++i)
#pragma unroll
          for (int j = 0; j < FN; ++j)
            acc[i][j] = __builtin_amdgcn_mfma_f32_16x16x32_bf16(af[i], bfr[j], acc[i][j], 0, 0, 0);
      }
    }
  } else {
    for (int k0 = 0; k0 < K; k0 += 64) {
      __syncthreads();
#pragma unroll
      for (int s = 0; s < BM / 32; ++s)
        gl2lds16(A + (long)(w * (BM / 4) + s * 8 + lr8) * lda + k0 + swz,
                 &As[0][w * (BM / 4) + s * 8][0]);
#pragma unroll
      for (int s = 0; s < BN / 32; ++s)
        gl2lds16(B + (long)(w * (BN / 4) + s * 8 + lr8) * ldb + k0 + swz,
                 &Bs[0][w * (BN / 4) + s * 8][0]);
      __syncthreads();
#pragma unroll
      for (int t = 0; t < 2; ++t) {
        const int c0 = t * 4;
        v8bf af[FM], bfr[FN];
#pragma unroll
        for (int i = 0; i < FM; ++i)
          af[i] = *(const v8bf*)&As[0][wm * (BM / 2) + i * 16 + l15][((c0 + lk) ^ l7) * 8];
#pragma unroll
        for (int j = 0; j < FN; ++j)
          bfr[j] = *(const v8bf*)&Bs[0][wn * (BN / 2) + j * 16 + l15][((c0 + lk) ^ l7) * 8];
#pragma unroll
        for (int i = 0; i < FM; ++i)
#pragma unroll
          for (int j = 0; j < FN; ++j)
            acc[i][j] = __builtin_amdgcn_mfma_f32_16x16x32_bf16(af[i], bfr[j], acc[i][j], 0, 0, 0);
      }
    }
  }

  const long m0 = (long)byM * BM + wm * (BM / 2);
  const int n0 = bxN * BN + wn * (BN / 2);
#pragma unroll
  for (int j = 0; j < FN; ++j) {
    const int col = n0 + j * 16 + l15;
    const float bv = (bias && zb == 0) ? bias[zh * bstride + col] : 0.0f;
#pragma unroll
    for (int i = 0; i < FM; ++i) {
      const long row = m0 + i * 16 + lk * 4;
#pragma unroll
      for (int r = 0; r < 4; ++r) {
        float v = acc[i][j][r] * scale + bv;
        if (relu) v = fmaxf(v, 0.0f);
        const long idx = offC + (row + r) * ldc + col;
        if (OUTBF) ((u16*)Cv)[idx] = f2bf(v);
        else       ((float*)Cv)[idx] = v;
        if (VTR) {
          const int colS = (int)(offC % 3072) + col;   // column within (.,3072)
          if (colS >= 2048) {
            const int hh = (colS - 2048) >> 6, dd = (colS - 2048) & 63;
            const int rowg = (int)(row + r);
            vtw[((long)((rowg >> 9) * 16 + hh)) * 32768 + dd * 512 + (rowg & 511)] = f2bf(v);
          }
        }
      }
    }
  }
}

// ---------------------------------------------------------------------------
// Fused attention, QBLK=64: per block 64 q-rows x one (b,h). K in swizzled
// LDS, Q fragments from global/L2, softmax (w f32 to d_out), PV via padded
// LDS P/V^T chunks, O bf16 into S3b. 512 threads = 8 waves (2 wm x 4 wn);
// per-wave 32 q-rows. Grid (8,64)=512 blocks, 2/CU on all 256 CUs.
// ---------------------------------------------------------------------------
template <int CAUSAL>
__global__ __launch_bounds__(512)
void attn_fused(const u16* __restrict__ Qb, const u16* __restrict__ Kb,
                const u16* __restrict__ vtp, float* __restrict__ wout,
                u16* __restrict__ oout) {
  __shared__ __align__(16) char lds[65536];
  u16 (*Ks)[64] = (u16 (*)[64])lds;                 // [512][64] = 64KB
  u16 (*Pl)[136] = (u16 (*)[136])lds;               // [64][136] 17408 B (aliases Ks)
  u16 (*Vt)[136] = (u16 (*)[136])(lds + 17408);     // [64][136] 17408 B (aliases Ks)
  __shared__ float redM[64][4];
  __shared__ float redS[64][4];
  const int tid = threadIdx.x, lane = tid & 63, w = tid >> 6;
  const int wm = w >> 2, wn = w & 3;
  const int l15 = lane & 15, lk = lane >> 4;
  const int lr8 = lane >> 3;
  const int swz = ((lane & 7) ^ lr8) * 8;
  const int l7 = l15 & 7;
  const int bx = blockIdx.x;                 // q tile 0..7 (64 rows each)
  const int z = blockIdx.y, zb = z >> 4, zh = z & 15;
  const u16* Q = Qb + (long)zb * 512 * 3072 + zh * 64 + (long)bx * 64 * 3072;
  const u16* Kp = Kb + (long)zb * 512 * 3072 + zh * 64;
  const u16* vtz = vtp + (long)((zb << 4) + zh) * 32768;
  const long obase = (long)zb * kHTT + (long)zh * kTT;
  const int qmax = bx * 64 + 63;

#pragma unroll
  for (int s = 0; s < 8; ++s) {
    const int r0 = w * 64 + s * 8;
    if (!CAUSAL || r0 <= qmax)
      gl2lds16(Kp + (long)(r0 + lr8) * 3072 + swz, &Ks[r0][0]);
  }
  __syncthreads();

  v4f acc[2][8];
  const v4f zero = {0.f, 0.f, 0.f, 0.f};
#pragma unroll
  for (int i = 0; i < 2; ++i)
#pragma unroll
    for (int j = 0; j < 8; ++j) acc[i][j] = zero;

#pragma unroll
  for (int t = 0; t < 2; ++t) {
    const int c0 = t * 4;
    v8bf aq[2], bk[8];
#pragma unroll
    for (int i = 0; i < 2; ++i)
      aq[i] = *(const v8bf*)(Q + (long)(wm * 32 + i * 16 + l15) * 3072 + (c0 + lk) * 8);
#pragma unroll
    for (int j = 0; j < 8; ++j)
      bk[j] = *(const v8bf*)&Ks[wn * 128 + j * 16 + l15][((c0 + lk) ^ l7) * 8];
#pragma unroll
    for (int i = 0; i < 2; ++i)
#pragma unroll
      for (int j = 0; j < 8; ++j)
        if (!(CAUSAL && wn * 128 + j * 16 > bx * 64 + wm * 32 + i * 16 + 15))
          acc[i][j] = __builtin_amdgcn_mfma_f32_16x16x32_bf16(aq[i], bk[j], acc[i][j], 0, 0, 0);
  }

  // row max
  float gmax[2][4];
#pragma unroll
  for (int i = 0; i < 2; ++i)
#pragma unroll
    for (int r = 0; r < 4; ++r) {
      const int q = bx * 64 + wm * 32 + i * 16 + lk * 4 + r;
      float m = -3.0e38f;
#pragma unroll
      for (int j = 0; j < 8; ++j) {
        const int col = wn * 128 + j * 16 + l15;
        if (!CAUSAL || col <= q) m = fmaxf(m, acc[i][j][r] * 0.125f);
      }
#pragma unroll
      for (int off = 1; off < 16; off <<= 1) m = fmaxf(m, __shfl_xor(m, off));
      if (l15 == 0) redM[wm * 32 + i * 16 + lk * 4 + r][wn] = m;
    }
  __syncthreads();
#pragma unroll
  for (int i = 0; i < 2; ++i)
#pragma unroll
    for (int r = 0; r < 4; ++r) {
      v4f mv = *(const v4f*)&redM[wm * 32 + i * 16 + lk * 4 + r][0];
      gmax[i][r] = fmaxf(fmaxf(mv[0], mv[1]), fmaxf(mv[2], mv[3]));
    }
  // exp + row sum
#pragma unroll
  for (int i = 0; i < 2; ++i)
#pragma unroll
    for (int r = 0; r < 4; ++r) {
      const int q = bx * 64 + wm * 32 + i * 16 + lk * 4 + r;
      float s = 0.0f;
#pragma unroll
      for (int j = 0; j < 8; ++j) {
        const int col = wn * 128 + j * 16 + l15;
        float e = (!CAUSAL || col <= q) ? __expf(acc[i][j][r] * 0.125f - gmax[i][r]) : 0.0f;
        acc[i][j][r] = e;
        s += e;
      }
#pragma unroll
      for (int off = 1; off < 16; off <<= 1) s += __shfl_xor(s, off);
      if (l15 == 0) redS[wm * 32 + i * 16 + lk * 4 + r][wn] = s;
    }
  __syncthreads();
  // normalize, write w (f32), keep normalized P in acc
#pragma unroll
  for (int i = 0; i < 2; ++i)
#pragma unroll
    for (int r = 0; r < 4; ++r) {
      v4f sv = *(const v4f*)&redS[wm * 32 + i * 16 + lk * 4 + r][0];
      const float inv = 1.0f / (sv[0] + sv[1] + sv[2] + sv[3]);
      const int q = bx * 64 + wm * 32 + i * 16 + lk * 4 + r;
      const long rowoff = obase + (long)q * 512;
#pragma unroll
      for (int j = 0; j < 8; ++j) {
        const int col = wn * 128 + j * 16 + l15;
        const float v = acc[i][j][r] * inv;
        acc[i][j][r] = v;
        wout[rowoff + col] = v;
      }
    }

  // ---- PV: O[64 q][64 d] = P @ V, chunked over k (128 per chunk) ----
  // Pl/Vt alias Ks; safe: all Ks reads completed before the barrier below.
  v4f acco[2];
#pragma unroll
  for (int i = 0; i < 2; ++i) acco[i] = zero;
  const int kcMax = CAUSAL ? (bx >> 1) : 3;
  for (int kc = 0; kc <= kcMax; ++kc) {
    __syncthreads();
    if (wn == kc) {       // this wave-group owns P cols [kc*128, kc*128+128)
#pragma unroll
      for (int i = 0; i < 2; ++i)
#pragma unroll
        for (int j = 0; j < 8; ++j) {
          const int colk = j * 16 + l15;
#pragma unroll
          for (int r = 0; r < 4; ++r)
            Pl[wm * 32 + i * 16 + lk * 4 + r][colk] = f2bf(acc[i][j][r]);
        }
    }
    // stage V^T chunk [64 d][128 k] into padded Vt
#pragma unroll
    for (int s = 0; s < 2; ++s) {
      const int c = tid * 2 + s;            // 0..1023 chunks of 8 u16
      const int d = c >> 4, off = (c & 15) * 8;
      uint4 vv = *(const uint4*)(vtz + (long)d * 512 + kc * 128 + off);
      *(uint4*)&Vt[d][off] = vv;
    }
    __syncthreads();
#pragma unroll
    for (int t = 0; t < 4; ++t) {
      v8bf bv = *(const v8bf*)&Vt[wn * 16 + l15][t * 32 + lk * 8];
#pragma unroll
      for (int i = 0; i < 2; ++i) {
        v8bf ap = *(const v8bf*)&Pl[wm * 32 + i * 16 + l15][t * 32 + lk * 8];
        acco[i] = __builtin_amdgcn_mfma_f32_16x16x32_bf16(ap, bv, acco[i], 0, 0, 0);
      }
    }
  }
  // write O bf16 into S3b (2048,1024) at column zh*64
#pragma unroll
  for (int i = 0; i < 2; ++i)
#pragma unroll
    for (int r = 0; r < 4; ++r) {
      const int row = bx * 64 + wm * 32 + i * 16 + lk * 4 + r;
      oout[(long)(zb * 512 + row) * 1024 + zh * 64 + wn * 16 + l15] = f2bf(acco[i][r]);
    }
}

// Weight transpose-convert: out(N,K) bf16 = in(K,N)^T f32; 64x64 tiles,
// float4 vectorized loads, uint2 vectorized stores. Up to 32 matrices/launch.
struct TPtrs32 { const float* in[32]; u16* out[32]; };

__global__ void transpose_wt_v4(TPtrs32 ps, int K, int N) {
  __shared__ float tile[64][65];
  const float* in = ps.in[blockIdx.z];
  u16* o = ps.out[blockIdx.z];
  const int n0 = blockIdx.x * 64, k0 = blockIdx.y * 64;
  const int tr = threadIdx.x >> 4;          // 0..15
  const int tc = (threadIdx.x & 15) * 4;    // 0,4,..,60
#pragma unroll
  for (int i = 0; i < 4; ++i) {
    float4 v = *(const float4*)(in + (long)(k0 + tr + 16 * i) * N + n0 + tc);
    tile[tr + 16 * i][tc + 0] = v.x;
    tile[tr + 16 * i][tc + 1] = v.y;
    tile[tr + 16 * i][tc + 2] = v.z;
    tile[tr + 16 * i][tc + 3] = v.w;
  }
  __syncthreads();
#pragma unroll
  for (int i = 0; i < 4; ++i) {
    const int rr = tr + 16 * i;             // n within tile
    u16 h[4];
#pragma unroll
    for (int j = 0; j < 4; ++j) h[j] = f2bf(tile[tc + j][rr]);
    *(uint2*)(o + (long)(n0 + rr) * K + k0 + tc) = *(const uint2*)h;
  }
}

__global__ void concat_bias(float* __restrict__ dst, const float* __restrict__ s0,
                            const float* __restrict__ s1, const float* __restrict__ s2,
                            const int nsrc) {
  const int idx = blockIdx.x * 256 + threadIdx.x;
  const int per = nsrc << 10;
  const int l = idx / per, rem = idx - l * per, s = rem >> 10, j = rem & 1023;
  const float* src = (s == 0) ? s0 : (s == 1 ? s1 : s2);
  dst[idx] = src[l * 1024 + j];
}

__global__ void cvt_bf16_v3(const float* __restrict__ in, u16* __restrict__ o1,
                            u16* __restrict__ o2) {
  const long i = ((long)blockIdx.x * 256 + threadIdx.x) * 4;
  float4 v = *(const float4*)(in + i);
  u16 h[4] = {f2bf(v.x), f2bf(v.y), f2bf(v.z), f2bf(v.w)};
  *(uint2*)(o1 + i) = *(const uint2*)h;
  *(uint2*)(o2 + i) = *(const uint2*)h;
}

__global__ void embed_v2(const int* __restrict__ tgt, const float* __restrict__ emb,
                         float* __restrict__ x, u16* __restrict__ xb) {
  const int row = blockIdx.x;
  const int t = row & (kT - 1);
  const int tok = tgt[row];
  const int c = threadIdx.x * 4;
  float4 e = *(const float4*)(emb + (long)tok * kD + c);
  const float nl = -9.210340371976184f / (float)kD;
  const float a0 = (float)t * expf((float)c * nl);
  const float a1 = (float)t * expf((float)(c + 2) * nl);
  float4 o;
  o.x = e.x * 32.0f + sinf(a0);
  o.y = e.y * 32.0f + cosf(a0);
  o.z = e.z * 32.0f + sinf(a1);
  o.w = e.w * 32.0f + cosf(a1);
  *(float4*)(x + (long)row * kD + c) = o;
  u16 h[4] = {f2bf(o.x), f2bf(o.y), f2bf(o.z), f2bf(o.w)};
  *(uint2*)(xb + (long)row * kD + c) = *(const uint2*)h;
}

// x = LN(x + sum_{p<nres} resb[p]) with bf16 partials; writes x f32 and xb bf16
__global__ void add_ln_v4(float* __restrict__ x, u16* __restrict__ xb,
                          const u16* __restrict__ resb, const int nres,
                          const float* __restrict__ g, const float* __restrict__ b) {
  const int row = blockIdx.x;
  const int c = threadIdx.x * 4;
  float4 xv = *(const float4*)(x + (long)row * kD + c);
  float v0 = xv.x, v1 = xv.y, v2 = xv.z, v3 = xv.w;
  for (int p = 0; p < nres; ++p) {
    uint2 rv = *(const uint2*)(resb + p * kPART + (long)row * kD + c);
    v0 += bf2f((u16)(rv.x & 0xffffu));
    v1 += bf2f((u16)(rv.x >> 16));
    v2 += bf2f((u16)(rv.y & 0xffffu));
    v3 += bf2f((u16)(rv.y >> 16));
  }
  float s = v0 + v1 + v2 + v3;
  float ss = v0 * v0 + v1 * v1 + v2 * v2 + v3 * v3;
#pragma unroll
  for (int o = 32; o > 0; o >>= 1) { s += __shfl_xor(s, o); ss += __shfl_xor(ss, o); }
  __shared__ float red[4][2];
  const int wv = threadIdx.x >> 6;
  if ((threadIdx.x & 63) == 0) { red[wv][0] = s; red[wv][1] = ss; }
  __syncthreads();
  s  = red[0][0] + red[1][0] + red[2][0] + red[3][0];
  ss = red[0][1] + red[1][1] + red[2][1] + red[3][1];
  const float mean = s * (1.0f / kD);
  const float var = ss * (1.0f / kD) - mean * mean;
  const float rs = rsqrtf(var + 1e-5f);
  float4 gv = *(const float4*)(g + c);
  float4 bv = *(const float4*)(b + c);
  float4 o;
  o.x = gv.x * (v0 - mean) * rs + bv.x;
  o.y = gv.y * (v1 - mean) * rs + bv.y;
  o.z = gv.z * (v2 - mean) * rs + bv.z;
  o.w = gv.w * (v3 - mean) * rs + bv.w;
  *(float4*)(x + (long)row * kD + c) = o;
  u16 h[4] = {f2bf(o.x), f2bf(o.y), f2bf(o.z), f2bf(o.w)};
  *(uint2*)(xb + (long)row * kD + c) = *(const uint2*)h;
}

// ===========================================================================
// FALLBACK PATH (Round-3 proven)
// ===========================================================================
template <int BM, int BN, typename TA, typename TB, int BKN>
__global__ __launch_bounds__(256)
void gemm_kernel(const void* __restrict__ Av, const void* __restrict__ Bv,
                 const float* __restrict__ bias, float* __restrict__ Cv,
                 const int K, const int lda, const int ldb, const int ldc,
                 const int nH, const long sAb, const long sAh,
                 const long sBb, const long sBh, const long sCb, const long sCh,
                 const float scale, const int relu) {
  constexpr int LP = 40;
  __shared__ u16 As[BM][LP];
  __shared__ u16 Bs[BN][LP];
  const int tid = threadIdx.x;
  const int z = blockIdx.z;
  const int zb = z / nH, zh = z - zb * nH;
  const TA* A = (const TA*)Av + zb * sAb + zh * sAh + (long)blockIdx.y * BM * lda;
  const TB* Bp;
  if constexpr (BKN)
    Bp = (const TB*)Bv + zb * sBb + zh * sBh + (long)blockIdx.x * BN;
  else
    Bp = (const TB*)Bv + zb * sBb + zh * sBh + (long)blockIdx.x * BN * ldb;
  const long offC = zb * sCb + zh * sCh;
  const int lane = tid & 63;
  const int wm = (tid >> 7) & 1, wn = (tid >> 6) & 1;
  constexpr int FM = BM / 32, FN = BN / 32;
  v4f acc[FM][FN];
  const v4f zero = {0.f, 0.f, 0.f, 0.f};
#pragma unroll
  for (int i = 0; i < FM; ++i)
#pragma unroll
    for (int j = 0; j < FN; ++j) acc[i][j] = zero;
  const int l15 = lane & 15, lk = lane >> 4;

  for (int k0 = 0; k0 < K; k0 += 32) {
    __syncthreads();
    if constexpr (sizeof(TA) == 4) {
      const int r = tid >> 3, c = (tid & 7) * 4;
#pragma unroll
      for (int rr = 0; rr < BM; rr += 32) {
        float4 vv = *(const float4*)((const float*)A + (long)(rr + r) * lda + k0 + c);
        unsigned lo = (unsigned)f2bf(vv.x) | ((unsigned)f2bf(vv.y) << 16);
        unsigned hi = (unsigned)f2bf(vv.z) | ((unsigned)f2bf(vv.w) << 16);
        *(uint2*)&As[rr + r][c] = make_uint2(lo, hi);
      }
    } else {
      const int r = tid >> 2, c = (tid & 3) * 8;
#pragma unroll
      for (int rr = 0; rr < BM; rr += 64) {
        uint4 vv = *(const uint4*)((const u16*)A + (long)(rr + r) * lda + k0 + c);
        *(uint4*)&As[rr + r][c] = vv;
      }
    }
    if constexpr (BKN) {
      const int r = tid >> 3, c = (tid & 7) * 4;
#pragma unroll
      for (int nn = 0; nn < BN; nn += 32) {
        float4 vv = *(const float4*)((const float*)Bp + (long)(k0 + r) * ldb + nn + c);
        Bs[nn + c + 0][r] = f2bf(vv.x);
        Bs[nn + c + 1][r] = f2bf(vv.y);
        Bs[nn + c + 2][r] = f2bf(vv.z);
        Bs[nn + c + 3][r] = f2bf(vv.w);
      }
    } else if constexpr (sizeof(TB) == 4) {
      const int r = tid >> 3, c = (tid & 7) * 4;
#pragma unroll
      for (int rr = 0; rr < BN; rr += 32) {
        float4 vv = *(const float4*)((const float*)Bp + (long)(rr + r) * ldb + k0 + c);
        unsigned lo = (unsigned)f2bf(vv.x) | ((unsigned)f2bf(vv.y) << 16);
        unsigned hi = (unsigned)f2bf(vv.z) | ((unsigned)f2bf(vv.w) << 16);
        *(uint2*)&Bs[rr + r][c] = make_uint2(lo, hi);
      }
    } else {
      const int r = tid >> 2, c = (tid & 3) * 8;
#pragma unroll
      for (int rr = 0; rr < BN; rr += 64) {
        uint4 vv = *(const uint4*)((const u16*)Bp + (long)(rr + r) * ldb + k0 + c);
        *(uint4*)&Bs[rr + r][c] = vv;
      }
    }
    __syncthreads();
    v8bf af[FM], bfr[FN];
#pragma unroll
    for (int i = 0; i < FM; ++i)
      af[i] = *(const v8bf*)&As[wm * (BM / 2) + i * 16 + l15][lk * 8];
#pragma unroll
    for (int j = 0; j < FN; ++j)
      bfr[j] = *(const v8bf*)&Bs[wn * (BN / 2) + j * 16 + l15][lk * 8];
#pragma unroll
    for (int i = 0; i < FM; ++i)
#pragma unroll
      for (int j = 0; j < FN; ++j)
        acc[i][j] = __builtin_amdgcn_mfma_f32_16x16x32_bf16(af[i], bfr[j], acc[i][j], 0, 0, 0);
  }

  const long m0 = (long)blockIdx.y * BM + wm * (BM / 2);
  const int n0 = blockIdx.x * BN + wn * (BN / 2);
#pragma unroll
  for (int j = 0; j < FN; ++j) {
    const int col = n0 + j * 16 + l15;
    const float bv = bias ? bias[col] : 0.0f;
#pragma unroll
    for (int i = 0; i < FM; ++i) {
      const long row = m0 + i * 16 + lk * 4;
#pragma unroll
      for (int r = 0; r < 4; ++r) {
        float v = acc[i][j][r] * scale + bv;
        if (relu) v = fmaxf(v, 0.0f);
        Cv[offC + (row + r) * ldc + col] = v;
      }
    }
  }
}

__global__ void embed_kernel(const int* __restrict__ tgt, const float* __restrict__ emb,
                             float* __restrict__ x) {
  const int row = blockIdx.x;
  const int t = row & (kT - 1);
  const int tok = tgt[row];
  const int c = threadIdx.x * 4;
  float4 e = *(const float4*)(emb + (long)tok * kD + c);
  const float nl = -9.210340371976184f / (float)kD;
  const float a0 = (float)t * expf((float)c * nl);
  const float a1 = (float)t * expf((float)(c + 2) * nl);
  float4 o;
  o.x = e.x * 32.0f + sinf(a0);
  o.y = e.y * 32.0f + cosf(a0);
  o.z = e.z * 32.0f + sinf(a1);
  o.w = e.w * 32.0f + cosf(a1);
  *(float4*)(x + (long)row * kD + c) = o;
}

__global__ void transpose_v_kernel(const float* __restrict__ v, u16* __restrict__ vt) {
  __shared__ float tile[32][33];
  const int z = blockIdx.z;
  const int b = z >> 4, h = z & 15;
  const int t0 = blockIdx.x * 32, d0 = blockIdx.y * 32;
  const int tx = threadIdx.x, ty = threadIdx.y;
  const float* in = v + (long)b * kTD + (long)h * kDK;
#pragma unroll
  for (int i = 0; i < 4; ++i)
    tile[ty + 8 * i][tx] = in[(long)(t0 + ty + 8 * i) * kD + d0 + tx];
  __syncthreads();
  u16* o = vt + (long)z * kDK * kT;
#pragma unroll
  for (int i = 0; i < 4; ++i)
    o[(long)(d0 + ty + 8 * i) * kT + t0 + tx] = f2bf(tile[tx][ty + 8 * i]);
}

__global__ void softmax_kernel(float* __restrict__ w, const int causal) {
  const int rowg = blockIdx.x * 4 + (threadIdx.x >> 6);
  const int lane = threadIdx.x & 63;
  const int q = rowg & (kT - 1);
  float* p = w + (long)rowg * kT + lane * 8;
  float4 v0 = *(const float4*)p;
  float4 v1 = *(const float4*)(p + 4);
  float f[8] = {v0.x, v0.y, v0.z, v0.w, v1.x, v1.y, v1.z, v1.w};
  const int base = lane * 8;
  float mx = -3.0e38f;
#pragma unroll
  for (int j = 0; j < 8; ++j)
    if (!causal || base + j <= q) mx = fmaxf(mx, f[j]);
#pragma unroll
  for (int o = 32; o > 0; o >>= 1) mx = fmaxf(mx, __shfl_xor(mx, o));
  float s = 0.0f;
#pragma unroll
  for (int j = 0; j < 8; ++j) {
    float e = (!causal || base + j <= q) ? __expf(f[j] - mx) : 0.0f;
    f[j] = e; s += e;
  }
#pragma unroll
  for (int o = 32; o > 0; o >>= 1) s += __shfl_xor(s, o);
  const float inv = 1.0f / s;
  float4 o0 = {f[0] * inv, f[1] * inv, f[2] * inv, f[3] * inv};
  float4 o1 = {f[4] * inv, f[5] * inv, f[6] * inv, f[7] * inv};
  *(float4*)p = o0;
  *(float4*)(p + 4) = o1;
}

__global__ void add_ln_kernel(float* __restrict__ x, const float* __restrict__ res,
                              const float* __restrict__ g, const float* __restrict__ b) {
  const int row = blockIdx.x;
  const int c = threadIdx.x * 4;
  float4 xv = *(const float4*)(x + (long)row * kD + c);
  float4 rv = *(const float4*)(res + (long)row * kD + c);
  const float v0 = xv.x + rv.x, v1 = xv.y + rv.y, v2 = xv.z + rv.z, v3 = xv.w + rv.w;
  float s = v0 + v1 + v2 + v3;
  float ss = v0 * v0 + v1 * v1 + v2 * v2 + v3 * v3;
#pragma unroll
  for (int o = 32; o > 0; o >>= 1) { s += __shfl_xor(s, o); ss += __shfl_xor(ss, o); }
  __shared__ float red[4][2];
  const int wv = threadIdx.x >> 6;
  if ((threadIdx.x & 63) == 0) { red[wv][0] = s; red[wv][1] = ss; }
  __syncthreads();
  s  = red[0][0] + red[1][0] + red[2][0] + red[3][0];
  ss = red[0][1] + red[1][1] + red[2][1] + red[3][1];
  const float mean = s * (1.0f / kD);
  const float var = ss * (1.0f / kD) - mean * mean;
  const float rs = rsqrtf(var + 1e-5f);
  float4 gv = *(const float4*)(g + c);
  float4 bv = *(const float4*)(b + c);
  float4 o;
  o.x = gv.x * (v0 - mean) * rs + bv.x;
  o.y = gv.y * (v1 - mean) * rs + bv.y;
  o.z = gv.z * (v2 - mean) * rs + bv.z;
  o.w = gv.w * (v3 - mean) * rs + bv.w;
  *(float4*)(x + (long)row * kD + c) = o;
}

// ===========================================================================
extern "C" void kernel_launch(void* const* d_in, const int* in_sizes, int n_in,
                              void* d_out, int out_size, void* d_ws, size_t ws_size,
                              hipStream_t stream) {
  const int*   tgt  = (const int*)d_in[0];
  const float* enc  = (const float*)d_in[1];
  const float* emb  = (const float*)d_in[3];
  const float* Wout = (const float*)d_in[4];
  const float* bout = (const float*)d_in[5];
  const float* Wq_s = (const float*)d_in[6];
  const float* bq_s = (const float*)d_in[7];
  const float* Wk_s = (const float*)d_in[8];
  const float* bk_s = (const float*)d_in[9];
  const float* Wv_s = (const float*)d_in[10];
  const float* bv_s = (const float*)d_in[11];
  const float* Wo_s = (const float*)d_in[12];
  const float* bo_s = (const float*)d_in[13];
  const float* Wq_c = (const float*)d_in[14];
  const float* bq_c = (const float*)d_in[15];
  const float* Wk_c = (const float*)d_in[16];
  const float* bk_c = (const float*)d_in[17];
  const float* Wv_c = (const float*)d_in[18];
  const float* bv_c = (const float*)d_in[19];
  const float* Wo_c = (const float*)d_in[20];
  const float* bo_c = (const float*)d_in[21];
  const float* W1   = (const float*)d_in[22];
  const float* b1   = (const float*)d_in[23];
  const float* W2   = (const float*)d_in[24];
  const float* b2   = (const float*)d_in[25];
  const float* ln1g = (const float*)d_in[26];
  const float* ln1b = (const float*)d_in[27];
  const float* ln2g = (const float*)d_in[28];
  const float* ln2b = (const float*)d_in[29];
  const float* ln3g = (const float*)d_in[30];
  const float* ln3b = (const float*)d_in[31];

  float* out = (float*)d_out;
  const long DD = (long)kD * kD;
  const dim3 blk256(256), blkT(32, 8);

  if (ws_size >= (320ll << 20)) {
    // =================== FAST PATH ===================
    char* ws = (char*)d_ws;
    float* x     = (float*)ws;                    // 8 MiB
    u16* xb      = (u16*)(ws + (8l << 20));       // 4 MiB (contiguous with encb)
    u16* encb    = (u16*)(ws + (12l << 20));      // 4 MiB (A source, merged cross)
    u16* encb2   = (u16*)(ws + (16l << 20));      // 4 MiB (second copy for V slice)
    u16* Sqkv    = (u16*)(ws + (20l << 20));      // 12 MiB (2048x3072)
    u16* vt      = (u16*)(ws + (32l << 20));      // 4 MiB (B,H,dk,T)
    u16* S3b     = (u16*)(ws + (36l << 20));      // 4 MiB
    u16* Hb      = (u16*)(ws + (40l << 20));      // 16 MiB (2048x4096)
    u16* SpartB  = (u16*)(ws + (56l << 20));      // 16 MiB (4 bf16 partials)
    u16* wbase   = (u16*)(ws + (88l << 20));      // 128 MiB
    u16* woutT   = (u16*)(ws + (216l << 20));     // 62.5 MiB
    float* bqkvS = (float*)(ws + (280l << 20));   // 48 KiB
    float* bqkvC = (float*)(ws + (280l << 20) + (64l << 10));  // 48 KiB
    const long WLAY = 16l * 1024 * 1024;          // u16 elems per layer block

    // ---- one-time prep (batched transposes: 4 dispatches total) ----
    {
      TPtrs32 pa{};
      for (int i = 0; i < kL; ++i) {
        u16* wqkvS = wbase + i * WLAY;
        u16* woS   = wqkvS + 3072 * 1024;
        u16* wqkvC = woS + 1024 * 1024;
        u16* woC   = wqkvC + 3072 * 1024;
        pa.in[i * 8 + 0] = Wq_s + i * DD; pa.out[i * 8 + 0] = wqkvS;
        pa.in[i * 8 + 1] = Wk_s + i * DD; pa.out[i * 8 + 1] = wqkvS + 1024 * 1024;
        pa.in[i * 8 + 2] = Wv_s + i * DD; pa.out[i * 8 + 2] = wqkvS + 2048 * 1024;
        pa.in[i * 8 + 3] = Wo_s + i * DD; pa.out[i * 8 + 3] = woS;
        pa.in[i * 8 + 4] = Wq_c + i * DD; pa.out[i * 8 + 4] = wqkvC;
        pa.in[i * 8 + 5] = Wk_c + i * DD; pa.out[i * 8 + 5] = wqkvC + 1024 * 1024;
        pa.in[i * 8 + 6] = Wv_c + i * DD; pa.out[i * 8 + 6] = wqkvC + 2048 * 1024;
        pa.in[i * 8 + 7] = Wo_c + i * DD; pa.out[i * 8 + 7] = woC;
      }
      transpose_wt_v4<<<dim3(16, 16, 32), blk256, 0, stream>>>(pa, 1024, 1024);
      TPtrs32 p1{};
      for (int i = 0; i < kL; ++i) {
        p1.in[i] = W1 + (long)i * kD * kF;
        p1.out[i] = wbase + i * WLAY + 8l * 1024 * 1024;  // w1t
      }
      transpose_wt_v4<<<dim3(64, 16, 4), blk256, 0, stream>>>(p1, 1024, 4096);
      TPtrs32 p2{};
      for (int i = 0; i < kL; ++i) {
        p2.in[i] = W2 + (long)i * kF * kD;
        p2.out[i] = wbase + i * WLAY + 12l * 1024 * 1024; // w2t
      }
      transpose_wt_v4<<<dim3(16, 64, 4), blk256, 0, stream>>>(p2, 4096, 1024);
      TPtrs32 po{}; po.in[0] = Wout; po.out[0] = woutT;
      transpose_wt_v4<<<dim3(500, 16, 1), blk256, 0, stream>>>(po, 1024, 32000);
    }
    concat_bias<<<dim3(48), blk256, 0, stream>>>(bqkvS, bq_s, bk_s, bv_s, 3);
    concat_bias<<<dim3(48), blk256, 0, stream>>>(bqkvC, bq_c, bk_c, bv_c, 3);
    cvt_bf16_v3<<<dim3(2048), blk256, 0, stream>>>(enc, encb, encb2);
    embed_v2<<<dim3(kM), blk256, 0, stream>>>(tgt, emb, x, xb);

    for (int i = 0; i < kL; ++i) {
      u16* wqkvS = wbase + i * WLAY;
      u16* woS   = wqkvS + 3072 * 1024;
      u16* wqkvC = woS + 1024 * 1024;
      u16* woC   = wqkvC + 3072 * 1024;
      u16* w1t   = woC + 1024 * 1024;
      u16* w2t   = w1t + (long)4096 * 1024;
      float* wSelf  = out + kLOG + (long)i * kBHTT;
      float* wCross = out + kLOG + (long)kL * kBHTT + (long)i * kBHTT;

      // -------- self attention --------
      gemm_bf<128, 128, 1, 1, 1, 1><<<dim3(16, 24, 1), blk256, 0, stream>>>(
          xb, wqkvS, bqkvS + i * 3072, Sqkv, vt, 1024, 1024, 1024, 3072,
          1, 0, 0, 0, 0, 0, 0, 1.0f, 0, 0);
      attn_fused<1><<<dim3(8, 64), dim3(512), 0, stream>>>(Sqkv, Sqkv + 1024, vt, wSelf, S3b);
      // O-proj: split-K x4 (K=256 each), single-buffer, bf16 partials
      gemm_bf<128, 128, 1, 0, 0, 1><<<dim3(16, 8, 4), blk256, 0, stream>>>(
          S3b, woS, bo_s + (long)i * kD, SpartB, nullptr, 256, 1024, 1024, 1024,
          1, 256, 0, 256, 0, kPART, 0, 1.0f, 0, 0);
      add_ln_v4<<<dim3(kM), blk256, 0, stream>>>(x, xb, SpartB, 4,
          ln1g + (long)i * kD, ln1b + (long)i * kD);

      // -------- cross attention (merged Q/K/V via z: xb|encb|encb2) --------
      gemm_bf<128, 128, 1, 1, 1, 1><<<dim3(16, 8, 3), blk256, 0, stream>>>(
          xb, wqkvC, bqkvC + i * 3072, Sqkv, vt, 1024, 1024, 1024, 3072,
          3, 0, (long)2048 * 1024, 0, (long)1024 * 1024, 0, 1024, 1.0f, 0, 1024);
      attn_fused<0><<<dim3(8, 64), dim3(512), 0, stream>>>(Sqkv, Sqkv + 1024, vt, wCross, S3b);
      gemm_bf<128, 128, 1, 0, 0, 1><<<dim3(16, 8, 4), blk256, 0, stream>>>(
          S3b, woC, bo_c + (long)i * kD, SpartB, nullptr, 256, 1024, 1024, 1024,
          1, 256, 0, 256, 0, kPART, 0, 1.0f, 0, 0);
      add_ln_v4<<<dim3(kM), blk256, 0, stream>>>(x, xb, SpartB, 4,
          ln2g + (long)i * kD, ln2b + (long)i * kD);

      // -------- FFN --------
      gemm_bf<128, 128, 1, 0, 1, 1><<<dim3(16, 32, 1), blk256, 0, stream>>>(
          xb, w1t, b1 + (long)i * kF, Hb, nullptr, 1024, 1024, 1024, 4096,
          1, 0, 0, 0, 0, 0, 0, 1.0f, 1, 0);
      // FFN2: split-K x4 (K=1024 each), single-buffer, bf16 partials
      gemm_bf<128, 128, 1, 0, 0, 1><<<dim3(16, 8, 4), blk256, 0, stream>>>(
          Hb, w2t, b2 + (long)i * kD, SpartB, nullptr, 1024, 4096, 4096, 1024,
          1, 1024, 0, 1024, 0, kPART, 0, 1.0f, 0, 0);
      add_ln_v4<<<dim3(kM), blk256, 0, stream>>>(x, xb, SpartB, 4,
          ln3g + (long)i * kD, ln3b + (long)i * kD);
    }

    // logits: BN=128 dbuf, M fastest (weight panel shared by co-resident blocks)
    gemm_bf<128, 128, 0, 0, 1, 1><<<dim3(16, 250, 1), blk256, 0, stream>>>(
        xb, woutT, bout, out, nullptr, 1024, 1024, 1024, 32000,
        1, 0, 0, 0, 0, 0, 0, 1.0f, 0, 0);
    return;
  }

  // =================== FALLBACK (Round-3 verified) ===================
  float* x = (float*)d_ws;
  char* sc = (char*)d_out;
  float* S0 = (float*)sc;
  float* S1 = (float*)(sc + (8l  << 20));
  float* S2 = (float*)(sc + (16l << 20));
  float* S3 = (float*)(sc + (24l << 20));
  float* S4 = (float*)(sc + (32l << 20));
  u16*   vt = (u16*)  (sc + (40l << 20));

  embed_kernel<<<dim3(kM), blk256, 0, stream>>>(tgt, emb, x);
  auto wgemm = [&](const float* A, const float* W, const float* bias, float* C) {
    gemm_kernel<128, 128, float, float, 1><<<dim3(kD / 128, kM / 128, 1), blk256, 0, stream>>>(
        A, W, bias, C, kD, kD, kD, kD, 1, 0, 0, 0, 0, 0, 0, 1.0f, 0);
  };
  for (int i = 0; i < kL; ++i) {
    const long wOff = (long)i * DD;
    float* wSelf  = out + kLOG + (long)i * kBHTT;
    float* wCross = out + kLOG + (long)kL * kBHTT + (long)i * kBHTT;
    wgemm(x, Wq_s + wOff, bq_s + (long)i * kD, S0);
    wgemm(x, Wk_s + wOff, bk_s + (long)i * kD, S1);
    wgemm(x, Wv_s + wOff, bv_s + (long)i * kD, S2);
    transpose_v_kernel<<<dim3(16, 2, 64), blkT, 0, stream>>>(S2, vt);
    gemm_kernel<128, 128, float, float, 0><<<dim3(4, 4, 64), blk256, 0, stream>>>(
        S0, S1, nullptr, wSelf, kDK, kD, kD, kT,
        kH, kTD, (long)kDK, kTD, (long)kDK, kHTT, kTT, 0.125f, 0);
    softmax_kernel<<<dim3(kB * kH * kT / 4), blk256, 0, stream>>>(wSelf, 1);
    gemm_kernel<128, 64, float, u16, 0><<<dim3(1, 4, 64), blk256, 0, stream>>>(
        wSelf, vt, nullptr, S3, kT, kT, kT, kD,
        kH, kHTT, kTT, (long)kH * kDK * kT, (long)kDK * kT, kTD, (long)kDK, 1.0f, 0);
    wgemm(S3, Wo_s + wOff, bo_s + (long)i * kD, S0);
    add_ln_kernel<<<dim3(kM), blk256, 0, stream>>>(x, S0, ln1g + (long)i * kD, ln1b + (long)i * kD);
    wgemm(x,   Wq_c + wOff, bq_c + (long)i * kD, S0);
    wgemm(enc, Wk_c + wOff, bk_c + (long)i * kD, S1);
    wgemm(enc, Wv_c + wOff, bv_c + (long)i * kD, S2);
    transpose_v_kernel<<<dim3(16, 2, 64), blkT, 0, stream>>>(S2, vt);
    gemm_kernel<128, 128, float, float, 0><<<dim3(4, 4, 64), blk256, 0, stream>>>(
        S0, S1, nullptr, wCross, kDK, kD, kD, kT,
        kH, kTD, (long)kDK, kTD, (long)kDK, kHTT, kTT, 0.125f, 0);
    softmax_kernel<<<dim3(kB * kH * kT / 4), blk256, 0, stream>>>(wCross, 0);
    gemm_kernel<128, 64, float, u16, 0><<<dim3(1, 4, 64), blk256, 0, stream>>>(
        wCross, vt, nullptr, S3, kT, kT, kT, kD,
        kH, kHTT, kTT, (long)kH * kDK * kT, (long)kDK * kT, kTD, (long)kDK, 1.0f, 0);
    wgemm(S3, Wo_c + wOff, bo_c + (long)i * kD, S0);
    add_ln_kernel<<<dim3(kM), blk256, 0, stream>>>(x, S0, ln2g + (long)i * kD, ln2b + (long)i * kD);
    gemm_kernel<128, 128, float, float, 1><<<dim3(kF / 128, kM / 128, 1), blk256, 0, stream>>>(
        x, W1 + (long)i * kD * kF, b1 + (long)i * kF, S0, kD, kD, kF, kF,
        1, 0, 0, 0, 0, 0, 0, 1.0f, 1);
    gemm_kernel<128, 128, float, float, 1><<<dim3(kD / 128, kM / 128, 1), blk256, 0, stream>>>(
        S0, W2 + (long)i * kF * kD, b2 + (long)i * kD, S4, kF, kF, kD, kD,
        1, 0, 0, 0, 0, 0, 0, 1.0f, 0);
    add_ln_kernel<<<dim3(kM), blk256, 0, stream>>>(x, S4, ln3g + (long)i * kD, ln3b + (long)i * kD);
  }
  gemm_kernel<128, 128, float, float, 1><<<dim3(kV / 128, kM / 128, 1), blk256, 0, stream>>>(
      x, Wout, bout, out, kD, kD, kV, kV,
      1, 0, 0, 0, 0, 0, 0, 1.0f, 0);
}

// Round 15
// 1352.076 us; speedup vs baseline: 1.1478x; 1.0189x over previous
//
#include <hip/hip_runtime.h>

// TransformerDecoder on MI355X. Round 15:
// - bf16 canonical residual stream: drop the f32 `x` buffer entirely.
//   add_ln_v5 reads/writes xb (bf16) in place; saves ~200 MB HBM per call
//   (16 MB per LN x 12). Precision: one extra bf16 rounding per LN output,
//   predicted absmax ~0.025 << 0.0709.
// Everything else = Round-14 passing code. Fallback = Round-3 proven.

typedef unsigned short u16;
typedef __bf16 v8bf __attribute__((ext_vector_type(8)));
typedef float v4f __attribute__((ext_vector_type(4)));

namespace {
constexpr int kB = 4, kT = 512, kD = 1024, kH = 16, kDK = 64, kF = 4096, kV = 32000, kL = 4;
constexpr int kM = kB * kT;
constexpr long kTD = (long)kT * kD;
constexpr long kTT = (long)kT * kT;
constexpr long kHTT = (long)kH * kTT;
constexpr long kBHTT = (long)kB * kHTT;
constexpr long kLOG = (long)kM * kV;
constexpr long kPART = (long)kM * kD;
}

__device__ __forceinline__ u16 f2bf(float f) {
  union { float f; unsigned u; } v; v.f = f;
  unsigned r = v.u + 0x7FFFu + ((v.u >> 16) & 1u);
  return (u16)(r >> 16);
}
__device__ __forceinline__ float bf2f(u16 h) {
  union { unsigned u; float f; } v; v.u = ((unsigned)h) << 16;
  return v.f;
}

typedef __attribute__((address_space(3))) void lds_void;
typedef const __attribute__((address_space(1))) void glob_void;
__device__ __forceinline__ void gl2lds16(const void* g, void* l) {
  __builtin_amdgcn_global_load_lds((glob_void*)g, (lds_void*)l, 16, 0, 0);
}

// ---------------------------------------------------------------------------
// bf16 GEMM, BK=64, swizzled LDS. DBUF=1: double-buffered (1 barrier/step).
// DBUF=0: single buffer. SWAP=1: blockIdx.x indexes M.
// C[m][n] = scale*sum A[m][k]*B[n][k] + bias[zh*bstride+n] (zb==0 only).
// VTR: cols>=2048 of a (.,3072) C also written transposed into vt (B,H,dk,T).
// ---------------------------------------------------------------------------
template <int BM, int BN, int OUTBF, int VTR, int DBUF, int SWAP>
__global__ __launch_bounds__(256)
void gemm_bf(const u16* __restrict__ A0, const u16* __restrict__ B0,
             const float* __restrict__ bias, void* __restrict__ Cv,
             u16* __restrict__ vtw,
             const int K, const int lda, const int ldb, const int ldc,
             const int nH, const long sAb, const long sAh,
             const long sBb, const long sBh, const long sCb, const long sCh,
             const float scale, const int relu, const int bstride) {
  static_assert(BM % 32 == 0 && BN % 32 == 0, "tiles");
  __shared__ u16 As[DBUF + 1][BM][64];
  __shared__ u16 Bs[DBUF + 1][BN][64];
  const int tid = threadIdx.x;
  const int lane = tid & 63;
  const int w = tid >> 6;
  const int byM = SWAP ? blockIdx.x : blockIdx.y;   // M tile index
  const int bxN = SWAP ? blockIdx.y : blockIdx.x;   // N tile index
  const int z = blockIdx.z;
  const int zb = z / nH, zh = z - zb * nH;
  const u16* A = A0 + zb * sAb + zh * sAh + (long)byM * BM * lda;
  const u16* B = B0 + zb * sBb + zh * sBh + (long)bxN * BN * ldb;
  const long offC = zb * sCb + zh * sCh;
  const int wm = w >> 1, wn = w & 1;
  constexpr int FM = BM / 32, FN = BN / 32;
  v4f acc[FM][FN];
  const v4f zero = {0.f, 0.f, 0.f, 0.f};
#pragma unroll
  for (int i = 0; i < FM; ++i)
#pragma unroll
    for (int j = 0; j < FN; ++j) acc[i][j] = zero;
  const int l15 = lane & 15, lk = lane >> 4;
  const int lr8 = lane >> 3;                       // row within 8-row stripe
  const int swz = ((lane & 7) ^ lr8) * 8;          // pre-swizzled source col
  const int l7 = l15 & 7;

  if constexpr (DBUF) {
    // prologue: stage tile 0 into buffer 0
#pragma unroll
    for (int s = 0; s < BM / 32; ++s)
      gl2lds16(A + (long)(w * (BM / 4) + s * 8 + lr8) * lda + swz,
               &As[0][w * (BM / 4) + s * 8][0]);
#pragma unroll
    for (int s = 0; s < BN / 32; ++s)
      gl2lds16(B + (long)(w * (BN / 4) + s * 8 + lr8) * ldb + swz,
               &Bs[0][w * (BN / 4) + s * 8][0]);

    const int NT = K >> 6;
    for (int kt = 0; kt < NT; ++kt) {
      const int cur = kt & 1;
      __syncthreads();   // drains prev stage + prev reads
      if (kt + 1 < NT) {
        const int k0 = (kt + 1) << 6;
#pragma unroll
        for (int s = 0; s < BM / 32; ++s)
          gl2lds16(A + (long)(w * (BM / 4) + s * 8 + lr8) * lda + k0 + swz,
                   &As[cur ^ 1][w * (BM / 4) + s * 8][0]);
#pragma unroll
        for (int s = 0; s < BN / 32; ++s)
          gl2lds16(B + (long)(w * (BN / 4) + s * 8 + lr8) * ldb + k0 + swz,
                   &Bs[cur ^ 1][w * (BN / 4) + s * 8][0]);
      }
#pragma unroll
      for (int t = 0; t < 2; ++t) {
        const int c0 = t * 4;
        v8bf af[FM], bfr[FN];
#pragma unroll
        for (int i = 0; i < FM; ++i)
          af[i] = *(const v8bf*)&As[cur][wm * (BM / 2) + i * 16 + l15][((c0 + lk) ^ l7) * 8];
#pragma unroll
        for (int j = 0; j < FN; ++j)
          bfr[j] = *(const v8bf*)&Bs[cur][wn * (BN / 2) + j * 16 + l15][((c0 + lk) ^ l7) * 8];
#pragma unroll
        for (int i = 0; i < FM; ++i)
#pragma unroll
          for (int j = 0; j < FN; ++j)
            acc[i][j] = __builtin_amdgcn_mfma_f32_16x16x32_bf16(af[i], bfr[j], acc[i][j], 0, 0, 0);
      }
    }
  } else {
    for (int k0 = 0; k0 < K; k0 += 64) {
      __syncthreads();
#pragma unroll
      for (int s = 0; s < BM / 32; ++s)
        gl2lds16(A + (long)(w * (BM / 4) + s * 8 + lr8) * lda + k0 + swz,
                 &As[0][w * (BM / 4) + s * 8][0]);
#pragma unroll
      for (int s = 0; s < BN / 32; ++s)
        gl2lds16(B + (long)(w * (BN / 4) + s * 8 + lr8) * ldb + k0 + swz,
                 &Bs[0][w * (BN / 4) + s * 8][0]);
      __syncthreads();
#pragma unroll
      for (int t = 0; t < 2; ++t) {
        const int c0 = t * 4;
        v8bf af[FM], bfr[FN];
#pragma unroll
        for (int i = 0; i < FM; ++i)
          af[i] = *(const v8bf*)&As[0][wm * (BM / 2) + i * 16 + l15][((c0 + lk) ^ l7) * 8];
#pragma unroll
        for (int j = 0; j < FN; ++j)
          bfr[j] = *(const v8bf*)&Bs[0][wn * (BN / 2) + j * 16 + l15][((c0 + lk) ^ l7) * 8];
#pragma unroll
        for (int i = 0; i < FM; ++i)
#pragma unroll
          for (int j = 0; j < FN; ++j)
            acc[i][j] = __builtin_amdgcn_mfma_f32_16x16x32_bf16(af[i], bfr[j], acc[i][j], 0, 0, 0);
      }
    }
  }

  const long m0 = (long)byM * BM + wm * (BM / 2);
  const int n0 = bxN * BN + wn * (BN / 2);
#pragma unroll
  for (int j = 0; j < FN; ++j) {
    const int col = n0 + j * 16 + l15;
    const float bv = (bias && zb == 0) ? bias[zh * bstride + col] : 0.0f;
#pragma unroll
    for (int i = 0; i < FM; ++i) {
      const long row = m0 + i * 16 + lk * 4;
#pragma unroll
      for (int r = 0; r < 4; ++r) {
        float v = acc[i][j][r] * scale + bv;
        if (relu) v = fmaxf(v, 0.0f);
        const long idx = offC + (row + r) * ldc + col;
        if (OUTBF) ((u16*)Cv)[idx] = f2bf(v);
        else       ((float*)Cv)[idx] = v;
        if (VTR) {
          const int colS = (int)(offC % 3072) + col;   // column within (.,3072)
          if (colS >= 2048) {
            const int hh = (colS - 2048) >> 6, dd = (colS - 2048) & 63;
            const int rowg = (int)(row + r);
            vtw[((long)((rowg >> 9) * 16 + hh)) * 32768 + dd * 512 + (rowg & 511)] = f2bf(v);
          }
        }
      }
    }
  }
}

// ---------------------------------------------------------------------------
// Fused attention, QBLK=64 (Round-13 proven). 512 threads = 8 waves.
// ---------------------------------------------------------------------------
template <int CAUSAL>
__global__ __launch_bounds__(512)
void attn_fused(const u16* __restrict__ Qb, const u16* __restrict__ Kb,
                const u16* __restrict__ vtp, float* __restrict__ wout,
                u16* __restrict__ oout) {
  __shared__ __align__(16) char lds[65536];
  u16 (*Ks)[64] = (u16 (*)[64])lds;                 // [512][64] = 64KB
  u16 (*Pl)[136] = (u16 (*)[136])lds;               // [64][136] (aliases Ks)
  u16 (*Vt)[136] = (u16 (*)[136])(lds + 17408);     // [64][136] (aliases Ks)
  __shared__ float redM[64][4];
  __shared__ float redS[64][4];
  const int tid = threadIdx.x, lane = tid & 63, w = tid >> 6;
  const int wm = w >> 2, wn = w & 3;
  const int l15 = lane & 15, lk = lane >> 4;
  const int lr8 = lane >> 3;
  const int swz = ((lane & 7) ^ lr8) * 8;
  const int l7 = l15 & 7;
  const int bx = blockIdx.x;                 // q tile 0..7 (64 rows each)
  const int z = blockIdx.y, zb = z >> 4, zh = z & 15;
  const u16* Q = Qb + (long)zb * 512 * 3072 + zh * 64 + (long)bx * 64 * 3072;
  const u16* Kp = Kb + (long)zb * 512 * 3072 + zh * 64;
  const u16* vtz = vtp + (long)((zb << 4) + zh) * 32768;
  const long obase = (long)zb * kHTT + (long)zh * kTT;
  const int qmax = bx * 64 + 63;

#pragma unroll
  for (int s = 0; s < 8; ++s) {
    const int r0 = w * 64 + s * 8;
    if (!CAUSAL || r0 <= qmax)
      gl2lds16(Kp + (long)(r0 + lr8) * 3072 + swz, &Ks[r0][0]);
  }
  __syncthreads();

  v4f acc[2][8];
  const v4f zero = {0.f, 0.f, 0.f, 0.f};
#pragma unroll
  for (int i = 0; i < 2; ++i)
#pragma unroll
    for (int j = 0; j < 8; ++j) acc[i][j] = zero;

#pragma unroll
  for (int t = 0; t < 2; ++t) {
    const int c0 = t * 4;
    v8bf aq[2], bk[8];
#pragma unroll
    for (int i = 0; i < 2; ++i)
      aq[i] = *(const v8bf*)(Q + (long)(wm * 32 + i * 16 + l15) * 3072 + (c0 + lk) * 8);
#pragma unroll
    for (int j = 0; j < 8; ++j)
      bk[j] = *(const v8bf*)&Ks[wn * 128 + j * 16 + l15][((c0 + lk) ^ l7) * 8];
#pragma unroll
    for (int i = 0; i < 2; ++i)
#pragma unroll
      for (int j = 0; j < 8; ++j)
        if (!(CAUSAL && wn * 128 + j * 16 > bx * 64 + wm * 32 + i * 16 + 15))
          acc[i][j] = __builtin_amdgcn_mfma_f32_16x16x32_bf16(aq[i], bk[j], acc[i][j], 0, 0, 0);
  }

  // row max
  float gmax[2][4];
#pragma unroll
  for (int i = 0; i < 2; ++i)
#pragma unroll
    for (int r = 0; r < 4; ++r) {
      const int q = bx * 64 + wm * 32 + i * 16 + lk * 4 + r;
      float m = -3.0e38f;
#pragma unroll
      for (int j = 0; j < 8; ++j) {
        const int col = wn * 128 + j * 16 + l15;
        if (!CAUSAL || col <= q) m = fmaxf(m, acc[i][j][r] * 0.125f);
      }
#pragma unroll
      for (int off = 1; off < 16; off <<= 1) m = fmaxf(m, __shfl_xor(m, off));
      if (l15 == 0) redM[wm * 32 + i * 16 + lk * 4 + r][wn] = m;
    }
  __syncthreads();
#pragma unroll
  for (int i = 0; i < 2; ++i)
#pragma unroll
    for (int r = 0; r < 4; ++r) {
      v4f mv = *(const v4f*)&redM[wm * 32 + i * 16 + lk * 4 + r][0];
      gmax[i][r] = fmaxf(fmaxf(mv[0], mv[1]), fmaxf(mv[2], mv[3]));
    }
  // exp + row sum
#pragma unroll
  for (int i = 0; i < 2; ++i)
#pragma unroll
    for (int r = 0; r < 4; ++r) {
      const int q = bx * 64 + wm * 32 + i * 16 + lk * 4 + r;
      float s = 0.0f;
#pragma unroll
      for (int j = 0; j < 8; ++j) {
        const int col = wn * 128 + j * 16 + l15;
        float e = (!CAUSAL || col <= q) ? __expf(acc[i][j][r] * 0.125f - gmax[i][r]) : 0.0f;
        acc[i][j][r] = e;
        s += e;
      }
#pragma unroll
      for (int off = 1; off < 16; off <<= 1) s += __shfl_xor(s, off);
      if (l15 == 0) redS[wm * 32 + i * 16 + lk * 4 + r][wn] = s;
    }
  __syncthreads();
  // normalize, write w (f32), keep normalized P in acc
#pragma unroll
  for (int i = 0; i < 2; ++i)
#pragma unroll
    for (int r = 0; r < 4; ++r) {
      v4f sv = *(const v4f*)&redS[wm * 32 + i * 16 + lk * 4 + r][0];
      const float inv = 1.0f / (sv[0] + sv[1] + sv[2] + sv[3]);
      const int q = bx * 64 + wm * 32 + i * 16 + lk * 4 + r;
      const long rowoff = obase + (long)q * 512;
#pragma unroll
      for (int j = 0; j < 8; ++j) {
        const int col = wn * 128 + j * 16 + l15;
        const float v = acc[i][j][r] * inv;
        acc[i][j][r] = v;
        wout[rowoff + col] = v;
      }
    }

  // ---- PV: O[64 q][64 d] = P @ V, chunked over k (128 per chunk) ----
  v4f acco[2];
#pragma unroll
  for (int i = 0; i < 2; ++i) acco[i] = zero;
  const int kcMax = CAUSAL ? (bx >> 1) : 3;
  for (int kc = 0; kc <= kcMax; ++kc) {
    __syncthreads();
    if (wn == kc) {       // this wave-group owns P cols [kc*128, kc*128+128)
#pragma unroll
      for (int i = 0; i < 2; ++i)
#pragma unroll
        for (int j = 0; j < 8; ++j) {
          const int colk = j * 16 + l15;
#pragma unroll
          for (int r = 0; r < 4; ++r)
            Pl[wm * 32 + i * 16 + lk * 4 + r][colk] = f2bf(acc[i][j][r]);
        }
    }
    // stage V^T chunk [64 d][128 k] into padded Vt
#pragma unroll
    for (int s = 0; s < 2; ++s) {
      const int c = tid * 2 + s;            // 0..1023 chunks of 8 u16
      const int d = c >> 4, off = (c & 15) * 8;
      uint4 vv = *(const uint4*)(vtz + (long)d * 512 + kc * 128 + off);
      *(uint4*)&Vt[d][off] = vv;
    }
    __syncthreads();
#pragma unroll
    for (int t = 0; t < 4; ++t) {
      v8bf bv = *(const v8bf*)&Vt[wn * 16 + l15][t * 32 + lk * 8];
#pragma unroll
      for (int i = 0; i < 2; ++i) {
        v8bf ap = *(const v8bf*)&Pl[wm * 32 + i * 16 + l15][t * 32 + lk * 8];
        acco[i] = __builtin_amdgcn_mfma_f32_16x16x32_bf16(ap, bv, acco[i], 0, 0, 0);
      }
    }
  }
  // write O bf16 into S3b (2048,1024) at column zh*64
#pragma unroll
  for (int i = 0; i < 2; ++i)
#pragma unroll
    for (int r = 0; r < 4; ++r) {
      const int row = bx * 64 + wm * 32 + i * 16 + lk * 4 + r;
      oout[(long)(zb * 512 + row) * 1024 + zh * 64 + wn * 16 + l15] = f2bf(acco[i][r]);
    }
}

// Weight transpose-convert: out(N,K) bf16 = in(K,N)^T f32; 64x64 tiles.
struct TPtrs32 { const float* in[32]; u16* out[32]; };

__global__ void transpose_wt_v4(TPtrs32 ps, int K, int N) {
  __shared__ float tile[64][65];
  const float* in = ps.in[blockIdx.z];
  u16* o = ps.out[blockIdx.z];
  const int n0 = blockIdx.x * 64, k0 = blockIdx.y * 64;
  const int tr = threadIdx.x >> 4;          // 0..15
  const int tc = (threadIdx.x & 15) * 4;    // 0,4,..,60
#pragma unroll
  for (int i = 0; i < 4; ++i) {
    float4 v = *(const float4*)(in + (long)(k0 + tr + 16 * i) * N + n0 + tc);
    tile[tr + 16 * i][tc + 0] = v.x;
    tile[tr + 16 * i][tc + 1] = v.y;
    tile[tr + 16 * i][tc + 2] = v.z;
    tile[tr + 16 * i][tc + 3] = v.w;
  }
  __syncthreads();
#pragma unroll
  for (int i = 0; i < 4; ++i) {
    const int rr = tr + 16 * i;             // n within tile
    u16 h[4];
#pragma unroll
    for (int j = 0; j < 4; ++j) h[j] = f2bf(tile[tc + j][rr]);
    *(uint2*)(o + (long)(n0 + rr) * K + k0 + tc) = *(const uint2*)h;
  }
}

__global__ void concat_bias(float* __restrict__ dst, const float* __restrict__ s0,
                            const float* __restrict__ s1, const float* __restrict__ s2,
                            const int nsrc) {
  const int idx = blockIdx.x * 256 + threadIdx.x;
  const int per = nsrc << 10;
  const int l = idx / per, rem = idx - l * per, s = rem >> 10, j = rem & 1023;
  const float* src = (s == 0) ? s0 : (s == 1 ? s1 : s2);
  dst[idx] = src[l * 1024 + j];
}

__global__ void cvt_bf16_v3(const float* __restrict__ in, u16* __restrict__ o1,
                            u16* __restrict__ o2) {
  const long i = ((long)blockIdx.x * 256 + threadIdx.x) * 4;
  float4 v = *(const float4*)(in + i);
  u16 h[4] = {f2bf(v.x), f2bf(v.y), f2bf(v.z), f2bf(v.w)};
  *(uint2*)(o1 + i) = *(const uint2*)h;
  *(uint2*)(o2 + i) = *(const uint2*)h;
}

// embed: writes bf16 residual xb only
__global__ void embed_v3(const int* __restrict__ tgt, const float* __restrict__ emb,
                         u16* __restrict__ xb) {
  const int row = blockIdx.x;
  const int t = row & (kT - 1);
  const int tok = tgt[row];
  const int c = threadIdx.x * 4;
  float4 e = *(const float4*)(emb + (long)tok * kD + c);
  const float nl = -9.210340371976184f / (float)kD;
  const float a0 = (float)t * expf((float)c * nl);
  const float a1 = (float)t * expf((float)(c + 2) * nl);
  float o0 = e.x * 32.0f + sinf(a0);
  float o1 = e.y * 32.0f + cosf(a0);
  float o2 = e.z * 32.0f + sinf(a1);
  float o3 = e.w * 32.0f + cosf(a1);
  u16 h[4] = {f2bf(o0), f2bf(o1), f2bf(o2), f2bf(o3)};
  *(uint2*)(xb + (long)row * kD + c) = *(const uint2*)h;
}

// xb = bf16(LN(xb + sum_{p<nres} resb[p])) — bf16 canonical residual stream
__global__ void add_ln_v5(u16* __restrict__ xb,
                          const u16* __restrict__ resb, const int nres,
                          const float* __restrict__ g, const float* __restrict__ b) {
  const int row = blockIdx.x;
  const int c = threadIdx.x * 4;
  uint2 xv = *(const uint2*)(xb + (long)row * kD + c);
  float v0 = bf2f((u16)(xv.x & 0xffffu));
  float v1 = bf2f((u16)(xv.x >> 16));
  float v2 = bf2f((u16)(xv.y & 0xffffu));
  float v3 = bf2f((u16)(xv.y >> 16));
  for (int p = 0; p < nres; ++p) {
    uint2 rv = *(const uint2*)(resb + p * kPART + (long)row * kD + c);
    v0 += bf2f((u16)(rv.x & 0xffffu));
    v1 += bf2f((u16)(rv.x >> 16));
    v2 += bf2f((u16)(rv.y & 0xffffu));
    v3 += bf2f((u16)(rv.y >> 16));
  }
  float s = v0 + v1 + v2 + v3;
  float ss = v0 * v0 + v1 * v1 + v2 * v2 + v3 * v3;
#pragma unroll
  for (int o = 32; o > 0; o >>= 1) { s += __shfl_xor(s, o); ss += __shfl_xor(ss, o); }
  __shared__ float red[4][2];
  const int wv = threadIdx.x >> 6;
  if ((threadIdx.x & 63) == 0) { red[wv][0] = s; red[wv][1] = ss; }
  __syncthreads();
  s  = red[0][0] + red[1][0] + red[2][0] + red[3][0];
  ss = red[0][1] + red[1][1] + red[2][1] + red[3][1];
  const float mean = s * (1.0f / kD);
  const float var = ss * (1.0f / kD) - mean * mean;
  const float rs = rsqrtf(var + 1e-5f);
  float4 gv = *(const float4*)(g + c);
  float4 bv = *(const float4*)(b + c);
  u16 h[4];
  h[0] = f2bf(gv.x * (v0 - mean) * rs + bv.x);
  h[1] = f2bf(gv.y * (v1 - mean) * rs + bv.y);
  h[2] = f2bf(gv.z * (v2 - mean) * rs + bv.z);
  h[3] = f2bf(gv.w * (v3 - mean) * rs + bv.w);
  *(uint2*)(xb + (long)row * kD + c) = *(const uint2*)h;
}

// ===========================================================================
// FALLBACK PATH (Round-3 proven)
// ===========================================================================
template <int BM, int BN, typename TA, typename TB, int BKN>
__global__ __launch_bounds__(256)
void gemm_kernel(const void* __restrict__ Av, const void* __restrict__ Bv,
                 const float* __restrict__ bias, float* __restrict__ Cv,
                 const int K, const int lda, const int ldb, const int ldc,
                 const int nH, const long sAb, const long sAh,
                 const long sBb, const long sBh, const long sCb, const long sCh,
                 const float scale, const int relu) {
  constexpr int LP = 40;
  __shared__ u16 As[BM][LP];
  __shared__ u16 Bs[BN][LP];
  const int tid = threadIdx.x;
  const int z = blockIdx.z;
  const int zb = z / nH, zh = z - zb * nH;
  const TA* A = (const TA*)Av + zb * sAb + zh * sAh + (long)blockIdx.y * BM * lda;
  const TB* Bp;
  if constexpr (BKN)
    Bp = (const TB*)Bv + zb * sBb + zh * sBh + (long)blockIdx.x * BN;
  else
    Bp = (const TB*)Bv + zb * sBb + zh * sBh + (long)blockIdx.x * BN * ldb;
  const long offC = zb * sCb + zh * sCh;
  const int lane = tid & 63;
  const int wm = (tid >> 7) & 1, wn = (tid >> 6) & 1;
  constexpr int FM = BM / 32, FN = BN / 32;
  v4f acc[FM][FN];
  const v4f zero = {0.f, 0.f, 0.f, 0.f};
#pragma unroll
  for (int i = 0; i < FM; ++i)
#pragma unroll
    for (int j = 0; j < FN; ++j) acc[i][j] = zero;
  const int l15 = lane & 15, lk = lane >> 4;

  for (int k0 = 0; k0 < K; k0 += 32) {
    __syncthreads();
    if constexpr (sizeof(TA) == 4) {
      const int r = tid >> 3, c = (tid & 7) * 4;
#pragma unroll
      for (int rr = 0; rr < BM; rr += 32) {
        float4 vv = *(const float4*)((const float*)A + (long)(rr + r) * lda + k0 + c);
        unsigned lo = (unsigned)f2bf(vv.x) | ((unsigned)f2bf(vv.y) << 16);
        unsigned hi = (unsigned)f2bf(vv.z) | ((unsigned)f2bf(vv.w) << 16);
        *(uint2*)&As[rr + r][c] = make_uint2(lo, hi);
      }
    } else {
      const int r = tid >> 2, c = (tid & 3) * 8;
#pragma unroll
      for (int rr = 0; rr < BM; rr += 64) {
        uint4 vv = *(const uint4*)((const u16*)A + (long)(rr + r) * lda + k0 + c);
        *(uint4*)&As[rr + r][c] = vv;
      }
    }
    if constexpr (BKN) {
      const int r = tid >> 3, c = (tid & 7) * 4;
#pragma unroll
      for (int nn = 0; nn < BN; nn += 32) {
        float4 vv = *(const float4*)((const float*)Bp + (long)(k0 + r) * ldb + nn + c);
        Bs[nn + c + 0][r] = f2bf(vv.x);
        Bs[nn + c + 1][r] = f2bf(vv.y);
        Bs[nn + c + 2][r] = f2bf(vv.z);
        Bs[nn + c + 3][r] = f2bf(vv.w);
      }
    } else if constexpr (sizeof(TB) == 4) {
      const int r = tid >> 3, c = (tid & 7) * 4;
#pragma unroll
      for (int rr = 0; rr < BN; rr += 32) {
        float4 vv = *(const float4*)((const float*)Bp + (long)(rr + r) * ldb + k0 + c);
        unsigned lo = (unsigned)f2bf(vv.x) | ((unsigned)f2bf(vv.y) << 16);
        unsigned hi = (unsigned)f2bf(vv.z) | ((unsigned)f2bf(vv.w) << 16);
        *(uint2*)&Bs[rr + r][c] = make_uint2(lo, hi);
      }
    } else {
      const int r = tid >> 2, c = (tid & 3) * 8;
#pragma unroll
      for (int rr = 0; rr < BN; rr += 64) {
        uint4 vv = *(const uint4*)((const u16*)Bp + (long)(rr + r) * ldb + k0 + c);
        *(uint4*)&Bs[rr + r][c] = vv;
      }
    }
    __syncthreads();
    v8bf af[FM], bfr[FN];
#pragma unroll
    for (int i = 0; i < FM; ++i)
      af[i] = *(const v8bf*)&As[wm * (BM / 2) + i * 16 + l15][lk * 8];
#pragma unroll
    for (int j = 0; j < FN; ++j)
      bfr[j] = *(const v8bf*)&Bs[wn * (BN / 2) + j * 16 + l15][lk * 8];
#pragma unroll
    for (int i = 0; i < FM; ++i)
#pragma unroll
      for (int j = 0; j < FN; ++j)
        acc[i][j] = __builtin_amdgcn_mfma_f32_16x16x32_bf16(af[i], bfr[j], acc[i][j], 0, 0, 0);
  }

  const long m0 = (long)blockIdx.y * BM + wm * (BM / 2);
  const int n0 = blockIdx.x * BN + wn * (BN / 2);
#pragma unroll
  for (int j = 0; j < FN; ++j) {
    const int col = n0 + j * 16 + l15;
    const float bv = bias ? bias[col] : 0.0f;
#pragma unroll
    for (int i = 0; i < FM; ++i) {
      const long row = m0 + i * 16 + lk * 4;
#pragma unroll
      for (int r = 0; r < 4; ++r) {
        float v = acc[i][j][r] * scale + bv;
        if (relu) v = fmaxf(v, 0.0f);
        Cv[offC + (row + r) * ldc + col] = v;
      }
    }
  }
}

__global__ void embed_kernel(const int* __restrict__ tgt, const float* __restrict__ emb,
                             float* __restrict__ x) {
  const int row = blockIdx.x;
  const int t = row & (kT - 1);
  const int tok = tgt[row];
  const int c = threadIdx.x * 4;
  float4 e = *(const float4*)(emb + (long)tok * kD + c);
  const float nl = -9.210340371976184f / (float)kD;
  const float a0 = (float)t * expf((float)c * nl);
  const float a1 = (float)t * expf((float)(c + 2) * nl);
  float4 o;
  o.x = e.x * 32.0f + sinf(a0);
  o.y = e.y * 32.0f + cosf(a0);
  o.z = e.z * 32.0f + sinf(a1);
  o.w = e.w * 32.0f + cosf(a1);
  *(float4*)(x + (long)row * kD + c) = o;
}

__global__ void transpose_v_kernel(const float* __restrict__ v, u16* __restrict__ vt) {
  __shared__ float tile[32][33];
  const int z = blockIdx.z;
  const int b = z >> 4, h = z & 15;
  const int t0 = blockIdx.x * 32, d0 = blockIdx.y * 32;
  const int tx = threadIdx.x, ty = threadIdx.y;
  const float* in = v + (long)b * kTD + (long)h * kDK;
#pragma unroll
  for (int i = 0; i < 4; ++i)
    tile[ty + 8 * i][tx] = in[(long)(t0 + ty + 8 * i) * kD + d0 + tx];
  __syncthreads();
  u16* o = vt + (long)z * kDK * kT;
#pragma unroll
  for (int i = 0; i < 4; ++i)
    o[(long)(d0 + ty + 8 * i) * kT + t0 + tx] = f2bf(tile[tx][ty + 8 * i]);
}

__global__ void softmax_kernel(float* __restrict__ w, const int causal) {
  const int rowg = blockIdx.x * 4 + (threadIdx.x >> 6);
  const int lane = threadIdx.x & 63;
  const int q = rowg & (kT - 1);
  float* p = w + (long)rowg * kT + lane * 8;
  float4 v0 = *(const float4*)p;
  float4 v1 = *(const float4*)(p + 4);
  float f[8] = {v0.x, v0.y, v0.z, v0.w, v1.x, v1.y, v1.z, v1.w};
  const int base = lane * 8;
  float mx = -3.0e38f;
#pragma unroll
  for (int j = 0; j < 8; ++j)
    if (!causal || base + j <= q) mx = fmaxf(mx, f[j]);
#pragma unroll
  for (int o = 32; o > 0; o >>= 1) mx = fmaxf(mx, __shfl_xor(mx, o));
  float s = 0.0f;
#pragma unroll
  for (int j = 0; j < 8; ++j) {
    float e = (!causal || base + j <= q) ? __expf(f[j] - mx) : 0.0f;
    f[j] = e; s += e;
  }
#pragma unroll
  for (int o = 32; o > 0; o >>= 1) s += __shfl_xor(s, o);
  const float inv = 1.0f / s;
  float4 o0 = {f[0] * inv, f[1] * inv, f[2] * inv, f[3] * inv};
  float4 o1 = {f[4] * inv, f[5] * inv, f[6] * inv, f[7] * inv};
  *(float4*)p = o0;
  *(float4*)(p + 4) = o1;
}

__global__ void add_ln_kernel(float* __restrict__ x, const float* __restrict__ res,
                              const float* __restrict__ g, const float* __restrict__ b) {
  const int row = blockIdx.x;
  const int c = threadIdx.x * 4;
  float4 xv = *(const float4*)(x + (long)row * kD + c);
  float4 rv = *(const float4*)(res + (long)row * kD + c);
  const float v0 = xv.x + rv.x, v1 = xv.y + rv.y, v2 = xv.z + rv.z, v3 = xv.w + rv.w;
  float s = v0 + v1 + v2 + v3;
  float ss = v0 * v0 + v1 * v1 + v2 * v2 + v3 * v3;
#pragma unroll
  for (int o = 32; o > 0; o >>= 1) { s += __shfl_xor(s, o); ss += __shfl_xor(ss, o); }
  __shared__ float red[4][2];
  const int wv = threadIdx.x >> 6;
  if ((threadIdx.x & 63) == 0) { red[wv][0] = s; red[wv][1] = ss; }
  __syncthreads();
  s  = red[0][0] + red[1][0] + red[2][0] + red[3][0];
  ss = red[0][1] + red[1][1] + red[2][1] + red[3][1];
  const float mean = s * (1.0f / kD);
  const float var = ss * (1.0f / kD) - mean * mean;
  const float rs = rsqrtf(var + 1e-5f);
  float4 gv = *(const float4*)(g + c);
  float4 bv = *(const float4*)(b + c);
  float4 o;
  o.x = gv.x * (v0 - mean) * rs + bv.x;
  o.y = gv.y * (v1 - mean) * rs + bv.y;
  o.z = gv.z * (v2 - mean) * rs + bv.z;
  o.w = gv.w * (v3 - mean) * rs + bv.w;
  *(float4*)(x + (long)row * kD + c) = o;
}

// ===========================================================================
extern "C" void kernel_launch(void* const* d_in, const int* in_sizes, int n_in,
                              void* d_out, int out_size, void* d_ws, size_t ws_size,
                              hipStream_t stream) {
  const int*   tgt  = (const int*)d_in[0];
  const float* enc  = (const float*)d_in[1];
  const float* emb  = (const float*)d_in[3];
  const float* Wout = (const float*)d_in[4];
  const float* bout = (const float*)d_in[5];
  const float* Wq_s = (const float*)d_in[6];
  const float* bq_s = (const float*)d_in[7];
  const float* Wk_s = (const float*)d_in[8];
  const float* bk_s = (const float*)d_in[9];
  const float* Wv_s = (const float*)d_in[10];
  const float* bv_s = (const float*)d_in[11];
  const float* Wo_s = (const float*)d_in[12];
  const float* bo_s = (const float*)d_in[13];
  const float* Wq_c = (const float*)d_in[14];
  const float* bq_c = (const float*)d_in[15];
  const float* Wk_c = (const float*)d_in[16];
  const float* bk_c = (const float*)d_in[17];
  const float* Wv_c = (const float*)d_in[18];
  const float* bv_c = (const float*)d_in[19];
  const float* Wo_c = (const float*)d_in[20];
  const float* bo_c = (const float*)d_in[21];
  const float* W1   = (const float*)d_in[22];
  const float* b1   = (const float*)d_in[23];
  const float* W2   = (const float*)d_in[24];
  const float* b2   = (const float*)d_in[25];
  const float* ln1g = (const float*)d_in[26];
  const float* ln1b = (const float*)d_in[27];
  const float* ln2g = (const float*)d_in[28];
  const float* ln2b = (const float*)d_in[29];
  const float* ln3g = (const float*)d_in[30];
  const float* ln3b = (const float*)d_in[31];

  float* out = (float*)d_out;
  const long DD = (long)kD * kD;
  const dim3 blk256(256), blkT(32, 8);

  if (ws_size >= (320ll << 20)) {
    // =================== FAST PATH ===================
    char* ws = (char*)d_ws;
    u16* xb      = (u16*)(ws + (8l << 20));       // 4 MiB bf16 canonical residual
    u16* encb    = (u16*)(ws + (12l << 20));      // 4 MiB (A source, merged cross)
    u16* encb2   = (u16*)(ws + (16l << 20));      // 4 MiB (second copy for V slice)
    u16* Sqkv    = (u16*)(ws + (20l << 20));      // 12 MiB (2048x3072)
    u16* vt      = (u16*)(ws + (32l << 20));      // 4 MiB (B,H,dk,T)
    u16* S3b     = (u16*)(ws + (36l << 20));      // 4 MiB
    u16* Hb      = (u16*)(ws + (40l << 20));      // 16 MiB (2048x4096)
    u16* SpartB  = (u16*)(ws + (56l << 20));      // 16 MiB (4 bf16 partials)
    u16* wbase   = (u16*)(ws + (88l << 20));      // 128 MiB
    u16* woutT   = (u16*)(ws + (216l << 20));     // 62.5 MiB
    float* bqkvS = (float*)(ws + (280l << 20));   // 48 KiB
    float* bqkvC = (float*)(ws + (280l << 20) + (64l << 10));  // 48 KiB
    const long WLAY = 16l * 1024 * 1024;          // u16 elems per layer block

    // ---- one-time prep (batched transposes: 4 dispatches total) ----
    {
      TPtrs32 pa{};
      for (int i = 0; i < kL; ++i) {
        u16* wqkvS = wbase + i * WLAY;
        u16* woS   = wqkvS + 3072 * 1024;
        u16* wqkvC = woS + 1024 * 1024;
        u16* woC   = wqkvC + 3072 * 1024;
        pa.in[i * 8 + 0] = Wq_s + i * DD; pa.out[i * 8 + 0] = wqkvS;
        pa.in[i * 8 + 1] = Wk_s + i * DD; pa.out[i * 8 + 1] = wqkvS + 1024 * 1024;
        pa.in[i * 8 + 2] = Wv_s + i * DD; pa.out[i * 8 + 2] = wqkvS + 2048 * 1024;
        pa.in[i * 8 + 3] = Wo_s + i * DD; pa.out[i * 8 + 3] = woS;
        pa.in[i * 8 + 4] = Wq_c + i * DD; pa.out[i * 8 + 4] = wqkvC;
        pa.in[i * 8 + 5] = Wk_c + i * DD; pa.out[i * 8 + 5] = wqkvC + 1024 * 1024;
        pa.in[i * 8 + 6] = Wv_c + i * DD; pa.out[i * 8 + 6] = wqkvC + 2048 * 1024;
        pa.in[i * 8 + 7] = Wo_c + i * DD; pa.out[i * 8 + 7] = woC;
      }
      transpose_wt_v4<<<dim3(16, 16, 32), blk256, 0, stream>>>(pa, 1024, 1024);
      TPtrs32 p1{};
      for (int i = 0; i < kL; ++i) {
        p1.in[i] = W1 + (long)i * kD * kF;
        p1.out[i] = wbase + i * WLAY + 8l * 1024 * 1024;  // w1t
      }
      transpose_wt_v4<<<dim3(64, 16, 4), blk256, 0, stream>>>(p1, 1024, 4096);
      TPtrs32 p2{};
      for (int i = 0; i < kL; ++i) {
        p2.in[i] = W2 + (long)i * kF * kD;
        p2.out[i] = wbase + i * WLAY + 12l * 1024 * 1024; // w2t
      }
      transpose_wt_v4<<<dim3(16, 64, 4), blk256, 0, stream>>>(p2, 4096, 1024);
      TPtrs32 po{}; po.in[0] = Wout; po.out[0] = woutT;
      transpose_wt_v4<<<dim3(500, 16, 1), blk256, 0, stream>>>(po, 1024, 32000);
    }
    concat_bias<<<dim3(48), blk256, 0, stream>>>(bqkvS, bq_s, bk_s, bv_s, 3);
    concat_bias<<<dim3(48), blk256, 0, stream>>>(bqkvC, bq_c, bk_c, bv_c, 3);
    cvt_bf16_v3<<<dim3(2048), blk256, 0, stream>>>(enc, encb, encb2);
    embed_v3<<<dim3(kM), blk256, 0, stream>>>(tgt, emb, xb);

    for (int i = 0; i < kL; ++i) {
      u16* wqkvS = wbase + i * WLAY;
      u16* woS   = wqkvS + 3072 * 1024;
      u16* wqkvC = woS + 1024 * 1024;
      u16* woC   = wqkvC + 3072 * 1024;
      u16* w1t   = woC + 1024 * 1024;
      u16* w2t   = w1t + (long)4096 * 1024;
      float* wSelf  = out + kLOG + (long)i * kBHTT;
      float* wCross = out + kLOG + (long)kL * kBHTT + (long)i * kBHTT;

      // -------- self attention --------
      gemm_bf<128, 128, 1, 1, 1, 1><<<dim3(16, 24, 1), blk256, 0, stream>>>(
          xb, wqkvS, bqkvS + i * 3072, Sqkv, vt, 1024, 1024, 1024, 3072,
          1, 0, 0, 0, 0, 0, 0, 1.0f, 0, 0);
      attn_fused<1><<<dim3(8, 64), dim3(512), 0, stream>>>(Sqkv, Sqkv + 1024, vt, wSelf, S3b);
      // O-proj: split-K x4 (K=256 each), single-buffer, bf16 partials
      gemm_bf<128, 128, 1, 0, 0, 1><<<dim3(16, 8, 4), blk256, 0, stream>>>(
          S3b, woS, bo_s + (long)i * kD, SpartB, nullptr, 256, 1024, 1024, 1024,
          1, 256, 0, 256, 0, kPART, 0, 1.0f, 0, 0);
      add_ln_v5<<<dim3(kM), blk256, 0, stream>>>(xb, SpartB, 4,
          ln1g + (long)i * kD, ln1b + (long)i * kD);

      // -------- cross attention (merged Q/K/V via z: xb|encb|encb2) --------
      gemm_bf<128, 128, 1, 1, 1, 1><<<dim3(16, 8, 3), blk256, 0, stream>>>(
          xb, wqkvC, bqkvC + i * 3072, Sqkv, vt, 1024, 1024, 1024, 3072,
          3, 0, (long)2048 * 1024, 0, (long)1024 * 1024, 0, 1024, 1.0f, 0, 1024);
      attn_fused<0><<<dim3(8, 64), dim3(512), 0, stream>>>(Sqkv, Sqkv + 1024, vt, wCross, S3b);
      gemm_bf<128, 128, 1, 0, 0, 1><<<dim3(16, 8, 4), blk256, 0, stream>>>(
          S3b, woC, bo_c + (long)i * kD, SpartB, nullptr, 256, 1024, 1024, 1024,
          1, 256, 0, 256, 0, kPART, 0, 1.0f, 0, 0);
      add_ln_v5<<<dim3(kM), blk256, 0, stream>>>(xb, SpartB, 4,
          ln2g + (long)i * kD, ln2b + (long)i * kD);

      // -------- FFN --------
      gemm_bf<128, 128, 1, 0, 1, 1><<<dim3(16, 32, 1), blk256, 0, stream>>>(
          xb, w1t, b1 + (long)i * kF, Hb, nullptr, 1024, 1024, 1024, 4096,
          1, 0, 0, 0, 0, 0, 0, 1.0f, 1, 0);
      // FFN2: split-K x4 (K=1024 each), single-buffer, bf16 partials
      gemm_bf<128, 128, 1, 0, 0, 1><<<dim3(16, 8, 4), blk256, 0, stream>>>(
          Hb, w2t, b2 + (long)i * kD, SpartB, nullptr, 1024, 4096, 4096, 1024,
          1, 1024, 0, 1024, 0, kPART, 0, 1.0f, 0, 0);
      add_ln_v5<<<dim3(kM), blk256, 0, stream>>>(xb, SpartB, 4,
          ln3g + (long)i * kD, ln3b + (long)i * kD);
    }

    // logits: BN=128 dbuf, M fastest
    gemm_bf<128, 128, 0, 0, 1, 1><<<dim3(16, 250, 1), blk256, 0, stream>>>(
        xb, woutT, bout, out, nullptr, 1024, 1024, 1024, 32000,
        1, 0, 0, 0, 0, 0, 0, 1.0f, 0, 0);
    return;
  }

  // =================== FALLBACK (Round-3 verified) ===================
  float* x = (float*)d_ws;
  char* sc = (char*)d_out;
  float* S0 = (float*)sc;
  float* S1 = (float*)(sc + (8l  << 20));
  float* S2 = (float*)(sc + (16l << 20));
  float* S3 = (float*)(sc + (24l << 20));
  float* S4 = (float*)(sc + (32l << 20));
  u16*   vt = (u16*)  (sc + (40l << 20));

  embed_kernel<<<dim3(kM), blk256, 0, stream>>>(tgt, emb, x);
  auto wgemm = [&](const float* A, const float* W, const float* bias, float* C) {
    gemm_kernel<128, 128, float, float, 1><<<dim3(kD / 128, kM / 128, 1), blk256, 0, stream>>>(
        A, W, bias, C, kD, kD, kD, kD, 1, 0, 0, 0, 0, 0, 0, 1.0f, 0);
  };
  for (int i = 0; i < kL; ++i) {
    const long wOff = (long)i * DD;
    float* wSelf  = out + kLOG + (long)i * kBHTT;
    float* wCross = out + kLOG + (long)kL * kBHTT + (long)i * kBHTT;
    wgemm(x, Wq_s + wOff, bq_s + (long)i * kD, S0);
    wgemm(x, Wk_s + wOff, bk_s + (long)i * kD, S1);
    wgemm(x, Wv_s + wOff, bv_s + (long)i * kD, S2);
    transpose_v_kernel<<<dim3(16, 2, 64), blkT, 0, stream>>>(S2, vt);
    gemm_kernel<128, 128, float, float, 0><<<dim3(4, 4, 64), blk256, 0, stream>>>(
        S0, S1, nullptr, wSelf, kDK, kD, kD, kT,
        kH, kTD, (long)kDK, kTD, (long)kDK, kHTT, kTT, 0.125f, 0);
    softmax_kernel<<<dim3(kB * kH * kT / 4), blk256, 0, stream>>>(wSelf, 1);
    gemm_kernel<128, 64, float, u16, 0><<<dim3(1, 4, 64), blk256, 0, stream>>>(
        wSelf, vt, nullptr, S3, kT, kT, kT, kD,
        kH, kHTT, kTT, (long)kH * kDK * kT, (long)kDK * kT, kTD, (long)kDK, 1.0f, 0);
    wgemm(S3, Wo_s + wOff, bo_s + (long)i * kD, S0);
    add_ln_kernel<<<dim3(kM), blk256, 0, stream>>>(x, S0, ln1g + (long)i * kD, ln1b + (long)i * kD);
    wgemm(x,   Wq_c + wOff, bq_c + (long)i * kD, S0);
    wgemm(enc, Wk_c + wOff, bk_c + (long)i * kD, S1);
    wgemm(enc, Wv_c + wOff, bv_c + (long)i * kD, S2);
    transpose_v_kernel<<<dim3(16, 2, 64), blkT, 0, stream>>>(S2, vt);
    gemm_kernel<128, 128, float, float, 0><<<dim3(4, 4, 64), blk256, 0, stream>>>(
        S0, S1, nullptr, wCross, kDK, kD, kD, kT,
        kH, kTD, (long)kDK, kTD, (long)kDK, kHTT, kTT, 0.125f, 0);
    softmax_kernel<<<dim3(kB * kH * kT / 4), blk256, 0, stream>>>(wCross, 0);
    gemm_kernel<128, 64, float, u16, 0><<<dim3(1, 4, 64), blk256, 0, stream>>>(
        wCross, vt, nullptr, S3, kT, kT, kT, kD,
        kH, kHTT, kTT, (long)kH * kDK * kT, (long)kDK * kT, kTD, (long)kDK, 1.0f, 0);
    wgemm(S3, Wo_c + wOff, bo_c + (long)i * kD, S0);
    add_ln_kernel<<<dim3(kM), blk256, 0, stream>>>(x, S0, ln2g + (long)i * kD, ln2b + (long)i * kD);
    gemm_kernel<128, 128, float, float, 1><<<dim3(kF / 128, kM / 128, 1), blk256, 0, stream>>>(
        x, W1 + (long)i * kD * kF, b1 + (long)i * kF, S0, kD, kD, kF, kF,
        1, 0, 0, 0, 0, 0, 0, 1.0f, 1);
    gemm_kernel<128, 128, float, float, 1><<<dim3(kD / 128, kM / 128, 1), blk256, 0, stream>>>(
        S0, W2 + (long)i * kF * kD, b2 + (long)i * kD, S4, kF, kF, kD, kD,
        1, 0, 0, 0, 0, 0, 0, 1.0f, 0);
    add_ln_kernel<<<dim3(kM), blk256, 0, stream>>>(x, S4, ln3g + (long)i * kD, ln3b + (long)i * kD);
  }
  gemm_kernel<128, 128, float, float, 1><<<dim3(kV / 128, kM / 128, 1), blk256, 0, stream>>>(
      x, Wout, bout, out, kD, kD, kV, kV,
      1, 0, 0, 0, 0, 0, 0, 1.0f, 0);
}